// Round 2
// baseline (5520.615 us; speedup 1.0000x reference)
//
#include <hip/hip_runtime.h>
#include <math.h>

#define NZc     64
#define EMBEDc  256
#define DMc     256
#define NHc     16
#define HDc     16
#define DFFc    1024
#define NLc     6
#define E1Dc    32
#define PDIMc   64
#define PMAXLc  24
#define NBINSc  49
#define NB      8
#define Lc      512
#define NTOK    (NB * Lc)        // 4096
#define UMDIM   (EMBEDc + E1Dc)  // 288

typedef __attribute__((ext_vector_type(4))) float f4;
typedef __attribute__((ext_vector_type(8))) short bf8;   // 8 bf16 in 4 VGPRs

#define MFMA(a, b, c) __builtin_amdgcn_mfma_f32_16x16x32_bf16((a), (b), (c), 0, 0, 0)

__device__ __forceinline__ short f2bf(float f) {
    unsigned u = __float_as_uint(f);
    u += 0x7FFFu + ((u >> 16) & 1u);   // round-to-nearest-even
    return (short)(u >> 16);
}
__device__ __forceinline__ float bf2f(short s) {
    return __uint_as_float(((unsigned)(unsigned short)s) << 16);
}

// ---------------------------------------------------------------------------
// weight conversion: fp32 -> bf16 hi/lo with per-layer dest strides
__global__ void k_cvt(const float* __restrict__ src, short* __restrict__ hi,
                      short* __restrict__ lo, int per_layer, int dst_stride,
                      int dst_off, float scale, int total) {
    for (int i = blockIdx.x * blockDim.x + threadIdx.x; i < total;
         i += gridDim.x * blockDim.x) {
        int l = i / per_layer, rels = i - l * per_layer;
        size_t di = (size_t)l * dst_stride + dst_off + rels;
        float v = src[i] * scale;
        short h = f2bf(v);
        hi[di] = h;
        lo[di] = f2bf(v - bf2f(h));
    }
}

// ---------------------------------------------------------------------------
// bias bins: bb[l][h][bin] = dot(pos_emb[bin], W2d[l][h]) + b2d[l][h]
__global__ void k_biasbins(const float* __restrict__ pos_emb,
                           const float* __restrict__ W2d,
                           const float* __restrict__ b2d,
                           float* __restrict__ bb) {
    int idx = blockIdx.x * blockDim.x + threadIdx.x;
    if (idx >= NLc * NHc * NBINSc) return;
    int bin = idx % NBINSc;
    int tmp = idx / NBINSc;
    int hh = tmp % NHc;
    int l  = tmp / NHc;
    float s = b2d[l * NHc + hh];
    const float* pe = pos_emb + bin * PDIMc;
    const float* w  = W2d + (l * NHc + hh) * PDIMc;
    for (int p = 0; p < PDIMc; ++p) s += pe[p] * w[p];
    bb[idx] = s;
}

// ---------------------------------------------------------------------------
// e_aa -> um cols 256..287 (bf16 hi/lo)
__global__ void k_eaa(const float* __restrict__ x,
                      const float* __restrict__ aa_emb,
                      short* __restrict__ umhi, short* __restrict__ umlo) {
    int tok = blockIdx.x * blockDim.x + threadIdx.x;
    if (tok >= NTOK) return;
    int n = tok / Lc, l = tok % Lc;
    const float* xp = x + (size_t)n * 20 * Lc + l;
    float best = xp[0];
    int bi = 0;
    for (int c = 1; c < 20; ++c) {
        float v = xp[c * Lc];
        if (v > best) { best = v; bi = c; }
    }
    const float* e = aa_emb + bi * E1Dc;
    for (int c = 0; c < E1Dc; ++c) {
        float v = e[c];
        short h = f2bf(v);
        umhi[(size_t)tok * UMDIM + EMBEDc + c] = h;
        umlo[(size_t)tok * UMDIM + EMBEDc + c] = f2bf(v - bf2f(h));
    }
}

// ---------------------------------------------------------------------------
// embed: h = relu(z^T W1^T + b1) W2^T + b2 ; writes h fp32 + um hi/lo
__global__ __launch_bounds__(256) void k_embed(const float* __restrict__ z,
                                               const float* __restrict__ w1,
                                               const float* __restrict__ b1,
                                               const float* __restrict__ w2,
                                               const float* __restrict__ b2,
                                               float* __restrict__ h,
                                               short* __restrict__ umhi,
                                               short* __restrict__ umlo) {
    int tok = blockIdx.x;
    int t = threadIdx.x;
    int n = tok / Lc, l = tok % Lc;
    __shared__ float zs[NZc];
    __shared__ float hid[EMBEDc];
    if (t < NZc) zs[t] = z[((size_t)n * NZc + t) * Lc + l];
    __syncthreads();
    float s = b1[t];
    const float* w = w1 + t * NZc;
    for (int c = 0; c < NZc; ++c) s += zs[c] * w[c];
    hid[t] = fmaxf(s, 0.0f);
    __syncthreads();
    s = b2[t];
    const float* wr = w2 + t * EMBEDc;
    for (int c = 0; c < EMBEDc; ++c) s += hid[c] * wr[c];
    h[(size_t)tok * EMBEDc + t] = s;
    short hv = f2bf(s);
    umhi[(size_t)tok * UMDIM + t] = hv;
    umlo[(size_t)tok * UMDIM + t] = f2bf(s - bf2f(hv));
}

// ---------------------------------------------------------------------------
// MFMA GEMM: C[M x N] = A @ W^T, A/W in bf16 hi/lo, 3-term compensated.
// block = 256 thr (4 waves), tile 64(M) x 64(N), wave w owns rows [16w,16w+16)
// EPI 0: store fp32 to outf (ldo).  EPI 1: relu(acc + bias[n]) -> bf16 hi/lo.
template <int EPI>
__global__ __launch_bounds__(256) void k_gemm(
    const short* __restrict__ Ahi, const short* __restrict__ Alo, int lda,
    const short* __restrict__ Bhi, const short* __restrict__ Blo, int ldb,
    int K, float* __restrict__ outf, int ldo, short* __restrict__ ohi,
    short* __restrict__ olo, const float* __restrict__ bias) {
    int wv = threadIdx.x >> 6, l = threadIdx.x & 63;
    int lr = l & 15, lk = l >> 4;
    int m0 = blockIdx.y * 64 + wv * 16;
    int n0 = blockIdx.x * 64;
    const short* ap_h = Ahi + (size_t)(m0 + lr) * lda + lk * 8;
    const short* ap_l = Alo + (size_t)(m0 + lr) * lda + lk * 8;
    const short* bp_h = Bhi + (size_t)(n0 + lr) * ldb + lk * 8;
    const short* bp_l = Blo + (size_t)(n0 + lr) * ldb + lk * 8;
    f4 acc[4];
#pragma unroll
    for (int nf = 0; nf < 4; ++nf) acc[nf] = (f4){0.f, 0.f, 0.f, 0.f};
    for (int ks = 0; ks < K; ks += 32) {
        bf8 ah = *(const bf8*)(ap_h + ks);
        bf8 al = *(const bf8*)(ap_l + ks);
#pragma unroll
        for (int nf = 0; nf < 4; ++nf) {
            bf8 bh = *(const bf8*)(bp_h + nf * 16 * ldb + ks);
            bf8 bl = *(const bf8*)(bp_l + nf * 16 * ldb + ks);
            acc[nf] = MFMA(ah, bh, acc[nf]);
            acc[nf] = MFMA(ah, bl, acc[nf]);
            acc[nf] = MFMA(al, bh, acc[nf]);
        }
    }
#pragma unroll
    for (int nf = 0; nf < 4; ++nf) {
        int n = n0 + nf * 16 + lr;
        if (EPI == 0) {
#pragma unroll
            for (int r = 0; r < 4; ++r)
                outf[(size_t)(m0 + lk * 4 + r) * ldo + n] = acc[nf][r];
        } else {
            float bv = bias[n];
#pragma unroll
            for (int r = 0; r < 4; ++r) {
                float y = fmaxf(acc[nf][r] + bv, 0.f);
                short hv = f2bf(y);
                size_t oi = (size_t)(m0 + lk * 4 + r) * ldo + n;
                ohi[oi] = hv;
                olo[oi] = f2bf(y - bf2f(hv));
            }
        }
    }
}

// ---------------------------------------------------------------------------
// attention: fp32 math, conflict-free transposed LDS tiles, f4 vector ops.
// qkv layout [tok][768]: q 0..255, k 256..511, v 512..767. o out: bf16 hi/lo.
__global__ __launch_bounds__(256) void k_attn(const float* __restrict__ qkv,
                                              const float* __restrict__ bb,
                                              short* __restrict__ ohi,
                                              short* __restrict__ olo) {
    int blk = blockIdx.x;
    int it = blk & 31, head = (blk >> 5) & 15, n = blk >> 9;
    int t = threadIdx.x;
    int rr = t >> 4, c = t & 15;
    int i = it * 16 + rr;

    __shared__ __align__(16) float sc[16][520];
    __shared__ __align__(16) float tt[2][16][68];
    __shared__ float biasr[64];
    if (t < NBINSc) biasr[t] = bb[head * NBINSc + t];

    const float* qrow = qkv + ((size_t)n * Lc + i) * 768 + head * 16;
    f4 qf[4];
    qf[0] = *(const f4*)qrow;
    qf[1] = *(const f4*)(qrow + 4);
    qf[2] = *(const f4*)(qrow + 8);
    qf[3] = *(const f4*)(qrow + 12);

#define STAGE(bufi, jt, OFF)                                                   \
    for (int u = t; u < 1024; u += 256) {                                      \
        int jj = u >> 4, dd = u & 15;                                          \
        tt[bufi][dd][jj] =                                                     \
            qkv[((size_t)n * Lc + (jt) * 64 + jj) * 768 + (OFF) + head * 16 + dd]; \
    }

    STAGE(0, 0, 256);
    __syncthreads();
    int buf = 0;
    for (int jt = 0; jt < 8; ++jt) {
        if (jt < 7) { STAGE(buf ^ 1, jt + 1, 256); }
        f4 s4 = (f4){0.f, 0.f, 0.f, 0.f};
#pragma unroll
        for (int dd = 0; dd < 16; ++dd) {
            f4 t4 = *(const f4*)&tt[buf][dd][4 * c];
            s4 += t4 * qf[dd >> 2][dd & 3];
        }
        int jb = jt * 64 + 4 * c;
#pragma unroll
        for (int qq = 0; qq < 4; ++qq) {
            int rel = jb + qq - i;
            rel = rel < -PMAXLc ? -PMAXLc : (rel > PMAXLc ? PMAXLc : rel);
            s4[qq] += biasr[rel + PMAXLc];
        }
        *(f4*)&sc[rr][jb] = s4;
        __syncthreads();
        buf ^= 1;
    }

    // softmax over row rr (16 lanes c)
    float m = -1e30f;
#pragma unroll
    for (int s = 0; s < 8; ++s) {
        f4 v = *(const f4*)&sc[rr][s * 64 + 4 * c];
        m = fmaxf(m, fmaxf(fmaxf(v[0], v[1]), fmaxf(v[2], v[3])));
    }
#pragma unroll
    for (int off = 8; off; off >>= 1) m = fmaxf(m, __shfl_xor(m, off, 16));
    float sum = 0.f;
#pragma unroll
    for (int s = 0; s < 8; ++s) {
        f4 v = *(const f4*)&sc[rr][s * 64 + 4 * c];
        v[0] = __expf(v[0] - m);
        v[1] = __expf(v[1] - m);
        v[2] = __expf(v[2] - m);
        v[3] = __expf(v[3] - m);
        sum += v[0] + v[1] + v[2] + v[3];
        *(f4*)&sc[rr][s * 64 + 4 * c] = v;
    }
#pragma unroll
    for (int off = 8; off; off >>= 1) sum += __shfl_xor(sum, off, 16);
    float inv = 1.0f / sum;

    // PV
    STAGE(0, 0, 512);
    __syncthreads();
    buf = 0;
    float oa = 0.f;
    for (int jt = 0; jt < 8; ++jt) {
        if (jt < 7) { STAGE(buf ^ 1, jt + 1, 512); }
#pragma unroll
        for (int j4 = 0; j4 < 16; ++j4) {
            f4 p = *(const f4*)&sc[rr][jt * 64 + 4 * j4];
            f4 vv = *(const f4*)&tt[buf][c][4 * j4];
            oa += p[0] * vv[0] + p[1] * vv[1] + p[2] * vv[2] + p[3] * vv[3];
        }
        __syncthreads();
        buf ^= 1;
    }
    float y = oa * inv;
    size_t oi = ((size_t)n * Lc + i) * DMc + head * 16 + c;
    short hv = f2bf(y);
    ohi[oi] = hv;
    olo[oi] = f2bf(y - bf2f(hv));
#undef STAGE
}

// ---------------------------------------------------------------------------
// LN: h = LN(h + s2 + sbias) ; writes h fp32 + um hi/lo (cols 0..255)
__global__ __launch_bounds__(256) void k_ln(const float* __restrict__ s2,
                                            const float* __restrict__ sbias,
                                            const float* __restrict__ g,
                                            const float* __restrict__ bta,
                                            float* __restrict__ h,
                                            short* __restrict__ umhi,
                                            short* __restrict__ umlo) {
    int tile = blockIdx.x;
    int t = threadIdx.x;
    int tok = t >> 4, j = t & 15;
    size_t gtok = (size_t)tile * 16 + tok;
    float sum = 0.f, ssq = 0.f;
    float vals[16];
#pragma unroll
    for (int d0 = 0; d0 < 16; ++d0) {
        int d = j + d0 * 16;
        float vv = h[gtok * EMBEDc + d] + s2[gtok * EMBEDc + d] + sbias[d];
        vals[d0] = vv;
        sum += vv;
        ssq += vv * vv;
    }
#pragma unroll
    for (int off = 8; off; off >>= 1) {
        sum += __shfl_xor(sum, off, 16);
        ssq += __shfl_xor(ssq, off, 16);
    }
    float mean = sum * (1.f / EMBEDc);
    float var = ssq * (1.f / EMBEDc) - mean * mean;
    float inv = rsqrtf(var + 1e-5f);
#pragma unroll
    for (int d0 = 0; d0 < 16; ++d0) {
        int d = j + d0 * 16;
        float y = (vals[d0] - mean) * inv * g[d] + bta[d];
        h[gtok * EMBEDc + d] = y;
        short hv = f2bf(y);
        umhi[gtok * UMDIM + d] = hv;
        umlo[gtok * UMDIM + d] = f2bf(y - bf2f(hv));
    }
}

// ---------------------------------------------------------------------------
// final MLP -> r (N,L,3)
__global__ __launch_bounds__(256) void k_final(const float* __restrict__ h,
                                               const float* __restrict__ w1,
                                               const float* __restrict__ b1,
                                               const float* __restrict__ w2,
                                               const float* __restrict__ b2,
                                               float* __restrict__ r) {
    int tok = blockIdx.x;
    int t = threadIdx.x;
    __shared__ float hs[EMBEDc];
    __shared__ float hid[EMBEDc];
    hs[t] = h[(size_t)tok * EMBEDc + t];
    __syncthreads();
    float s = b1[t];
    const float* w = w1 + (size_t)t * EMBEDc;
    for (int c = 0; c < EMBEDc; ++c) s += hs[c] * w[c];
    hid[t] = fmaxf(s, 0.f);
    __syncthreads();
    if (t < 3) {
        float o = b2[t];
        const float* wr = w2 + (size_t)t * EMBEDc;
        for (int c = 0; c < EMBEDc; ++c) o += hid[c] * wr[c];
        r[(size_t)tok * 3 + t] = o;
    }
}

// ---------------------------------------------------------------------------
__global__ __launch_bounds__(256) void k_dmap(const float* __restrict__ r,
                                              float* __restrict__ d) {
    int b = blockIdx.x;
    int n = b / Lc;
    float xi = r[(size_t)b * 3], yi = r[(size_t)b * 3 + 1], zi = r[(size_t)b * 3 + 2];
    const float* rn = r + (size_t)n * Lc * 3;
    for (int j = threadIdx.x; j < Lc; j += 256) {
        float dx = xi - rn[j * 3];
        float dy = yi - rn[j * 3 + 1];
        float dz = zi - rn[j * 3 + 2];
        d[(size_t)b * Lc + j] = sqrtf(dx * dx + dy * dy + dz * dz + 1e-12f);
    }
}

// ---------------------------------------------------------------------------
extern "C" void kernel_launch(void* const* d_in, const int* in_sizes, int n_in,
                              void* d_out, int out_size, void* d_ws, size_t ws_size,
                              hipStream_t stream) {
    const float* z       = (const float*)d_in[0];
    const float* x       = (const float*)d_in[1];
    const float* pos_emb = (const float*)d_in[2];
    const float* aa_emb  = (const float*)d_in[3];
    const float* ex_w1   = (const float*)d_in[4];
    const float* ex_b1   = (const float*)d_in[5];
    const float* ex_w2   = (const float*)d_in[6];
    const float* ex_b2   = (const float*)d_in[7];
    const float* Wq      = (const float*)d_in[8];
    const float* Wk      = (const float*)d_in[9];
    const float* Wv      = (const float*)d_in[10];
    const float* Wo      = (const float*)d_in[11];
    const float* bo      = (const float*)d_in[12];
    const float* W2d     = (const float*)d_in[13];
    const float* b2d     = (const float*)d_in[14];
    const float* Wf1     = (const float*)d_in[15];
    const float* bf1     = (const float*)d_in[16];
    const float* Wf2     = (const float*)d_in[17];
    const float* bf2     = (const float*)d_in[18];
    const float* ln1_g   = (const float*)d_in[19];
    const float* ln1_b   = (const float*)d_in[20];
    const float* ln2_g   = (const float*)d_in[21];
    const float* ln2_b   = (const float*)d_in[22];
    const float* o_w1    = (const float*)d_in[23];
    const float* o_b1    = (const float*)d_in[24];
    const float* o_w2    = (const float*)d_in[25];
    const float* o_b2    = (const float*)d_in[26];

    // workspace carve-up (~66 MB total)
    float* h    = (float*)d_ws;                    // 4096*256
    float* s2   = h + (size_t)NTOK * EMBEDc;       // 4096*256
    float* qkv  = s2 + (size_t)NTOK * EMBEDc;      // 4096*768
    float* bbuf = qkv + (size_t)NTOK * 768;        // 6*16*49
    float* r    = bbuf + NLc * NHc * NBINSc;       // 4096*3 (pad to 12288)
    short* um_hi = (short*)(r + 12288);            // 4096*288
    short* um_lo = um_hi + (size_t)NTOK * UMDIM;
    short* o_hi  = um_lo + (size_t)NTOK * UMDIM;   // 4096*256
    short* o_lo  = o_hi + (size_t)NTOK * EMBEDc;
    short* f1_hi = o_lo + (size_t)NTOK * EMBEDc;   // 4096*1024
    short* f1_lo = f1_hi + (size_t)NTOK * DFFc;
    short* wqkv_hi = f1_lo + (size_t)NTOK * DFFc;  // 6*768*256
    short* wqkv_lo = wqkv_hi + (size_t)NLc * 768 * EMBEDc;
    short* wo_hi   = wqkv_lo + (size_t)NLc * 768 * EMBEDc;   // 6*256*256
    short* wo_lo   = wo_hi + (size_t)NLc * EMBEDc * DMc;
    short* wf1_hi  = wo_lo + (size_t)NLc * EMBEDc * DMc;     // 6*1024*288
    short* wf1_lo  = wf1_hi + (size_t)NLc * DFFc * UMDIM;
    short* wf2_hi  = wf1_lo + (size_t)NLc * DFFc * UMDIM;    // 6*256*1024
    short* wf2_lo  = wf2_hi + (size_t)NLc * EMBEDc * DFFc;

    // weight conversions (w_t folded into Wq)
    k_cvt<<<512, 256, 0, stream>>>(Wq, wqkv_hi, wqkv_lo, DMc * EMBEDc, 768 * EMBEDc, 0, 0.0625f, NLc * DMc * EMBEDc);
    k_cvt<<<512, 256, 0, stream>>>(Wk, wqkv_hi, wqkv_lo, DMc * EMBEDc, 768 * EMBEDc, EMBEDc * EMBEDc, 1.f, NLc * DMc * EMBEDc);
    k_cvt<<<512, 256, 0, stream>>>(Wv, wqkv_hi, wqkv_lo, DMc * EMBEDc, 768 * EMBEDc, 2 * EMBEDc * EMBEDc, 1.f, NLc * DMc * EMBEDc);
    k_cvt<<<512, 256, 0, stream>>>(Wo, wo_hi, wo_lo, EMBEDc * DMc, EMBEDc * DMc, 0, 1.f, NLc * EMBEDc * DMc);
    k_cvt<<<512, 256, 0, stream>>>(Wf1, wf1_hi, wf1_lo, DFFc * UMDIM, DFFc * UMDIM, 0, 1.f, NLc * DFFc * UMDIM);
    k_cvt<<<512, 256, 0, stream>>>(Wf2, wf2_hi, wf2_lo, EMBEDc * DFFc, EMBEDc * DFFc, 0, 1.f, NLc * EMBEDc * DFFc);

    k_biasbins<<<(NLc * NHc * NBINSc + 255) / 256, 256, 0, stream>>>(pos_emb, W2d, b2d, bbuf);
    k_eaa<<<NTOK / 256, 256, 0, stream>>>(x, aa_emb, um_hi, um_lo);
    k_embed<<<NTOK, 256, 0, stream>>>(z, ex_w1, ex_b1, ex_w2, ex_b2, h, um_hi, um_lo);

    for (int l = 0; l < NLc; ++l) {
        // qkv: [4096,768] = um[:, :256] @ Wqkv^T   (scale folded into Wq)
        k_gemm<0><<<dim3(768 / 64, NTOK / 64), 256, 0, stream>>>(
            um_hi, um_lo, UMDIM,
            wqkv_hi + (size_t)l * 768 * EMBEDc, wqkv_lo + (size_t)l * 768 * EMBEDc, EMBEDc,
            EMBEDc, qkv, 768, nullptr, nullptr, nullptr);
        k_attn<<<NB * NHc * (Lc / 16), 256, 0, stream>>>(qkv, bbuf + (size_t)l * NHc * NBINSc, o_hi, o_lo);
        // oproj: s2 = o @ Wo^T (bias added in LN)
        k_gemm<0><<<dim3(EMBEDc / 64, NTOK / 64), 256, 0, stream>>>(
            o_hi, o_lo, EMBEDc,
            wo_hi + (size_t)l * EMBEDc * DMc, wo_lo + (size_t)l * EMBEDc * DMc, DMc,
            DMc, s2, EMBEDc, nullptr, nullptr, nullptr);
        k_ln<<<NTOK / 16, 256, 0, stream>>>(s2, bo + (size_t)l * EMBEDc,
                                            ln1_g + (size_t)l * EMBEDc, ln1_b + (size_t)l * EMBEDc,
                                            h, um_hi, um_lo);
        // ffn1: f1 = relu(um @ Wf1^T + bf1) -> bf16 hi/lo
        k_gemm<1><<<dim3(DFFc / 64, NTOK / 64), 256, 0, stream>>>(
            um_hi, um_lo, UMDIM,
            wf1_hi + (size_t)l * DFFc * UMDIM, wf1_lo + (size_t)l * DFFc * UMDIM, UMDIM,
            UMDIM, nullptr, DFFc, f1_hi, f1_lo, bf1 + (size_t)l * DFFc);
        // ffn2: s2 = f1 @ Wf2^T (bias bf2 added in LN)
        k_gemm<0><<<dim3(EMBEDc / 64, NTOK / 64), 256, 0, stream>>>(
            f1_hi, f1_lo, DFFc,
            wf2_hi + (size_t)l * EMBEDc * DFFc, wf2_lo + (size_t)l * EMBEDc * DFFc, DFFc,
            DFFc, s2, EMBEDc, nullptr, nullptr, nullptr);
        k_ln<<<NTOK / 16, 256, 0, stream>>>(s2, bf2 + (size_t)l * EMBEDc,
                                            ln2_g + (size_t)l * EMBEDc, ln2_b + (size_t)l * EMBEDc,
                                            h, um_hi, um_lo);
    }

    k_final<<<NTOK, 256, 0, stream>>>(h, o_w1, o_b1, o_w2, o_b2, r);
    k_dmap<<<NB * Lc, 256, 0, stream>>>(r, (float*)d_out);
}

// Round 3
// 1394.739 us; speedup vs baseline: 3.9582x; 3.9582x over previous
//
#include <hip/hip_runtime.h>
#include <math.h>

#define NZc     64
#define EMBEDc  256
#define DMc     256
#define NHc     16
#define HDc     16
#define DFFc    1024
#define NLc     6
#define E1Dc    32
#define PDIMc   64
#define PMAXLc  24
#define NBINSc  49
#define NB      8
#define Lc      512
#define NTOK    (NB * Lc)        // 4096
#define UMDIM   (EMBEDc + E1Dc)  // 288

typedef __attribute__((ext_vector_type(4))) float f4;
typedef __attribute__((ext_vector_type(8))) short bf8;   // 8 bf16 in 4 VGPRs

#define MFMA(a, b, c) __builtin_amdgcn_mfma_f32_16x16x32_bf16((a), (b), (c), 0, 0, 0)

__device__ __forceinline__ short f2bf(float f) {
    unsigned u = __float_as_uint(f);
    u += 0x7FFFu + ((u >> 16) & 1u);   // round-to-nearest-even
    return (short)(u >> 16);
}
__device__ __forceinline__ float bf2f(short s) {
    return __uint_as_float(((unsigned)(unsigned short)s) << 16);
}

// ---------------------------------------------------------------------------
// weight conversion: fp32 -> bf16 hi/lo with per-layer dest strides
__global__ void k_cvt(const float* __restrict__ src, short* __restrict__ hi,
                      short* __restrict__ lo, int per_layer, int dst_stride,
                      int dst_off, float scale, int total) {
    for (int i = blockIdx.x * blockDim.x + threadIdx.x; i < total;
         i += gridDim.x * blockDim.x) {
        int l = i / per_layer, rels = i - l * per_layer;
        size_t di = (size_t)l * dst_stride + dst_off + rels;
        float v = src[i] * scale;
        short h = f2bf(v);
        hi[di] = h;
        lo[di] = f2bf(v - bf2f(h));
    }
}

// ---------------------------------------------------------------------------
__global__ void k_biasbins(const float* __restrict__ pos_emb,
                           const float* __restrict__ W2d,
                           const float* __restrict__ b2d,
                           float* __restrict__ bb) {
    int idx = blockIdx.x * blockDim.x + threadIdx.x;
    if (idx >= NLc * NHc * NBINSc) return;
    int bin = idx % NBINSc;
    int tmp = idx / NBINSc;
    int hh = tmp % NHc;
    int l  = tmp / NHc;
    float s = b2d[l * NHc + hh];
    const float* pe = pos_emb + bin * PDIMc;
    const float* w  = W2d + (l * NHc + hh) * PDIMc;
    for (int p = 0; p < PDIMc; ++p) s += pe[p] * w[p];
    bb[idx] = s;
}

// ---------------------------------------------------------------------------
__global__ void k_eaa(const float* __restrict__ x,
                      const float* __restrict__ aa_emb,
                      short* __restrict__ umhi, short* __restrict__ umlo) {
    int tok = blockIdx.x * blockDim.x + threadIdx.x;
    if (tok >= NTOK) return;
    int n = tok / Lc, l = tok % Lc;
    const float* xp = x + (size_t)n * 20 * Lc + l;
    float best = xp[0];
    int bi = 0;
    for (int c = 1; c < 20; ++c) {
        float v = xp[c * Lc];
        if (v > best) { best = v; bi = c; }
    }
    const float* e = aa_emb + bi * E1Dc;
    for (int c = 0; c < E1Dc; ++c) {
        float v = e[c];
        short h = f2bf(v);
        umhi[(size_t)tok * UMDIM + EMBEDc + c] = h;
        umlo[(size_t)tok * UMDIM + EMBEDc + c] = f2bf(v - bf2f(h));
    }
}

// ---------------------------------------------------------------------------
__global__ __launch_bounds__(256) void k_embed(const float* __restrict__ z,
                                               const float* __restrict__ w1,
                                               const float* __restrict__ b1,
                                               const float* __restrict__ w2,
                                               const float* __restrict__ b2,
                                               float* __restrict__ h,
                                               short* __restrict__ umhi,
                                               short* __restrict__ umlo) {
    int tok = blockIdx.x;
    int t = threadIdx.x;
    int n = tok / Lc, l = tok % Lc;
    __shared__ float zs[NZc];
    __shared__ float hid[EMBEDc];
    if (t < NZc) zs[t] = z[((size_t)n * NZc + t) * Lc + l];
    __syncthreads();
    float s = b1[t];
    const float* w = w1 + t * NZc;
    for (int c = 0; c < NZc; ++c) s += zs[c] * w[c];
    hid[t] = fmaxf(s, 0.0f);
    __syncthreads();
    s = b2[t];
    const float* wr = w2 + t * EMBEDc;
    for (int c = 0; c < EMBEDc; ++c) s += hid[c] * wr[c];
    h[(size_t)tok * EMBEDc + t] = s;
    short hv = f2bf(s);
    umhi[(size_t)tok * UMDIM + t] = hv;
    umlo[(size_t)tok * UMDIM + t] = f2bf(s - bf2f(hv));
}

// ---------------------------------------------------------------------------
// MFMA GEMM: C[M x N] = A @ W^T, 3-term compensated bf16.
// EPI 0: fp32 out. EPI 1: relu(acc+bias) -> bf16 hi/lo. EPI 2: acc -> bf16 hi/lo.
template <int EPI>
__global__ __launch_bounds__(256) void k_gemm(
    const short* __restrict__ Ahi, const short* __restrict__ Alo, int lda,
    const short* __restrict__ Bhi, const short* __restrict__ Blo, int ldb,
    int K, float* __restrict__ outf, int ldo, short* __restrict__ ohi,
    short* __restrict__ olo, const float* __restrict__ bias) {
    int wv = threadIdx.x >> 6, l = threadIdx.x & 63;
    int lr = l & 15, lk = l >> 4;
    int m0 = blockIdx.y * 64 + wv * 16;
    int n0 = blockIdx.x * 64;
    const short* ap_h = Ahi + (size_t)(m0 + lr) * lda + lk * 8;
    const short* ap_l = Alo + (size_t)(m0 + lr) * lda + lk * 8;
    const short* bp_h = Bhi + (size_t)(n0 + lr) * ldb + lk * 8;
    const short* bp_l = Blo + (size_t)(n0 + lr) * ldb + lk * 8;
    f4 acc[4];
#pragma unroll
    for (int nf = 0; nf < 4; ++nf) acc[nf] = (f4){0.f, 0.f, 0.f, 0.f};
    for (int ks = 0; ks < K; ks += 32) {
        bf8 ah = *(const bf8*)(ap_h + ks);
        bf8 al = *(const bf8*)(ap_l + ks);
#pragma unroll
        for (int nf = 0; nf < 4; ++nf) {
            bf8 bh = *(const bf8*)(bp_h + nf * 16 * ldb + ks);
            bf8 bl = *(const bf8*)(bp_l + nf * 16 * ldb + ks);
            acc[nf] = MFMA(ah, bh, acc[nf]);
            acc[nf] = MFMA(ah, bl, acc[nf]);
            acc[nf] = MFMA(al, bh, acc[nf]);
        }
    }
#pragma unroll
    for (int nf = 0; nf < 4; ++nf) {
        int n = n0 + nf * 16 + lr;
        if (EPI == 0) {
#pragma unroll
            for (int r = 0; r < 4; ++r)
                outf[(size_t)(m0 + lk * 4 + r) * ldo + n] = acc[nf][r];
        } else if (EPI == 1) {
            float bv = bias[n];
#pragma unroll
            for (int r = 0; r < 4; ++r) {
                float y = fmaxf(acc[nf][r] + bv, 0.f);
                short hv = f2bf(y);
                size_t oi = (size_t)(m0 + lk * 4 + r) * ldo + n;
                ohi[oi] = hv;
                olo[oi] = f2bf(y - bf2f(hv));
            }
        } else {
#pragma unroll
            for (int r = 0; r < 4; ++r) {
                float y = acc[nf][r];
                short hv = f2bf(y);
                size_t oi = (size_t)(m0 + lk * 4 + r) * ldo + n;
                ohi[oi] = hv;
                olo[oi] = f2bf(y - bf2f(hv));
            }
        }
    }
}

// ---------------------------------------------------------------------------
// MFMA flash attention. qkvh/qkvl: [4096][768] bf16 hi/lo (q|k|v).
// Block: (n, head, qquarter of 128 rows). 4 waves; wave = 2 q-tiles of 16.
// Swapped QK^T: S^T = mfma(K, Q^T); lane holds q=lane&15, keys=(lane>>4)*4+r.
// hi/lo packed along MFMA K-dim: A=[Kh|Kl], B1=[Qh|Qh], B2=[Ql|0] -> 2 MFMA
// give KhQh+KlQh+KhQl. Same for PV. P fragment == S^T fragment layout.
__global__ __launch_bounds__(256) void k_attn(const short* __restrict__ qh,
                                              const short* __restrict__ ql,
                                              const float* __restrict__ bb,
                                              short* __restrict__ ohi,
                                              short* __restrict__ olo) {
    int bx = blockIdx.x;
    int qt = bx & 3, head = (bx >> 2) & 15, n = bx >> 6;
    int t = threadIdx.x;
    int w = t >> 6, l = t & 63;
    int lq = l & 15, lk = l >> 4;

    __shared__ __align__(16) short khl[512][40];   // [key][hi0-15|lo16-31|pad]
    __shared__ __align__(16) short vth[16][536];   // V^T hi: [d][key]
    __shared__ __align__(16) short vtl[16][536];   // V^T lo
    __shared__ float biasr[64];

    if (t < NBINSc) biasr[t] = bb[head * NBINSc + t];

    size_t base = (size_t)n * Lc * 768 + head * 16;
    // stage K (hi+lo packed per row)
    for (int u = t; u < 2048; u += 256) {
        int key = u >> 2, seg = u & 3;   // 0:h0-7 1:h8-15 2:l0-7 3:l8-15
        const short* src = (seg < 2 ? qh : ql) + base + 256 + (size_t)key * 768 + (seg & 1) * 8;
        *(bf8*)&khl[key][seg * 8] = *(const bf8*)src;
    }
    // stage V transposed
    for (int u = t; u < 1024; u += 256) {
        int key = u >> 1, half = u & 1;
        bf8 v8h = *(const bf8*)(qh + base + 512 + (size_t)key * 768 + half * 8);
        bf8 v8l = *(const bf8*)(ql + base + 512 + (size_t)key * 768 + half * 8);
#pragma unroll
        for (int i = 0; i < 8; ++i) {
            vth[half * 8 + i][key] = v8h[i];
            vtl[half * 8 + i][key] = v8l[i];
        }
    }
    __syncthreads();

    for (int qi = 0; qi < 2; ++qi) {
        int qg = qt * 128 + w * 32 + qi * 16 + lq;   // this lane's q column
        size_t qrow = ((size_t)n * Lc + qg) * 768 + head * 16;
        bf8 B1 = *(const bf8*)(qh + qrow + (lk & 1) * 8);   // [Qh|Qh]
        bf8 B2;
        if (lk < 2) B2 = *(const bf8*)(ql + qrow + lk * 8);  // [Ql|0]
        else {
#pragma unroll
            for (int i = 0; i < 8; ++i) B2[i] = 0;
        }

        f4 acc = (f4){0.f, 0.f, 0.f, 0.f};
        float m = -1e30f, lsum = 0.f;

        for (int kt = 0; kt < 32; ++kt) {
            bf8 A1 = *(const bf8*)&khl[kt * 16 + lq][lk * 8];  // [Kh|Kl]
            f4 s = (f4){0.f, 0.f, 0.f, 0.f};
            s = MFMA(A1, B1, s);      // KhQh + KlQh
            s = MFMA(A1, B2, s);      // KhQl
            int kb = kt * 16 + lk * 4;
#pragma unroll
            for (int r = 0; r < 4; ++r) {
                int rel = kb + r - qg;
                rel = rel < -PMAXLc ? -PMAXLc : (rel > PMAXLc ? PMAXLc : rel);
                s[r] += biasr[rel + PMAXLc];
            }
            float mt = fmaxf(fmaxf(s[0], s[1]), fmaxf(s[2], s[3]));
            mt = fmaxf(mt, __shfl_xor(mt, 16));
            mt = fmaxf(mt, __shfl_xor(mt, 32));
            float mn = fmaxf(m, mt);
            float alpha = __expf(m - mn);
            m = mn;
            f4 p;
#pragma unroll
            for (int r = 0; r < 4; ++r) p[r] = __expf(s[r] - mn);
            lsum = lsum * alpha + (p[0] + p[1] + p[2] + p[3]);
            // rescale O (O reg r is q = lk*4+r; alpha lives at lane q)
#pragma unroll
            for (int r = 0; r < 4; ++r) acc[r] *= __shfl(alpha, lk * 4 + r);
            // gather this lane's 8 P values (keys (lk&1)*8 .. +8 of row lq)
            int src0 = (lk & 1) * 32 + lq;
            int src1 = src0 + 16;
            float g[8];
#pragma unroll
            for (int j = 0; j < 4; ++j) {
                g[j]     = __shfl(p[j], src0);
                g[j + 4] = __shfl(p[j], src1);
            }
            bf8 PA;
#pragma unroll
            for (int j = 0; j < 8; ++j) {
                short hv = f2bf(g[j]);
                PA[j] = (lk < 2) ? hv : f2bf(g[j] - bf2f(hv));  // [Ph|Pl]
            }
            bf8 VB1 = *(const bf8*)&vth[lq][kt * 16 + (lk & 1) * 8];  // [Vh|Vh]
            bf8 VB2;
            if (lk < 2) VB2 = *(const bf8*)&vtl[lq][kt * 16 + lk * 8];  // [Vl|0]
            else {
#pragma unroll
                for (int i = 0; i < 8; ++i) VB2[i] = 0;
            }
            acc = MFMA(PA, VB1, acc);   // PhVh + PlVh
            acc = MFMA(PA, VB2, acc);   // PhVl
        }

        float lr = lsum + __shfl_xor(lsum, 16);
        lr += __shfl_xor(lr, 32);
        float inv = 1.0f / lr;
#pragma unroll
        for (int r = 0; r < 4; ++r) {
            float iq = __shfl(inv, lk * 4 + r);
            float y = acc[r] * iq;
            int qo = qt * 128 + w * 32 + qi * 16 + lk * 4 + r;
            size_t oi = ((size_t)n * Lc + qo) * DMc + head * 16 + lq;
            short hv = f2bf(y);
            ohi[oi] = hv;
            olo[oi] = f2bf(y - bf2f(hv));
        }
    }
}

// ---------------------------------------------------------------------------
__global__ __launch_bounds__(256) void k_ln(const float* __restrict__ s2,
                                            const float* __restrict__ sbias,
                                            const float* __restrict__ g,
                                            const float* __restrict__ bta,
                                            float* __restrict__ h,
                                            short* __restrict__ umhi,
                                            short* __restrict__ umlo) {
    int tile = blockIdx.x;
    int t = threadIdx.x;
    int tok = t >> 4, j = t & 15;
    size_t gtok = (size_t)tile * 16 + tok;
    float sum = 0.f, ssq = 0.f;
    float vals[16];
#pragma unroll
    for (int d0 = 0; d0 < 16; ++d0) {
        int d = j + d0 * 16;
        float vv = h[gtok * EMBEDc + d] + s2[gtok * EMBEDc + d] + sbias[d];
        vals[d0] = vv;
        sum += vv;
        ssq += vv * vv;
    }
#pragma unroll
    for (int off = 8; off; off >>= 1) {
        sum += __shfl_xor(sum, off, 16);
        ssq += __shfl_xor(ssq, off, 16);
    }
    float mean = sum * (1.f / EMBEDc);
    float var = ssq * (1.f / EMBEDc) - mean * mean;
    float inv = rsqrtf(var + 1e-5f);
#pragma unroll
    for (int d0 = 0; d0 < 16; ++d0) {
        int d = j + d0 * 16;
        float y = (vals[d0] - mean) * inv * g[d] + bta[d];
        h[gtok * EMBEDc + d] = y;
        short hv = f2bf(y);
        umhi[gtok * UMDIM + d] = hv;
        umlo[gtok * UMDIM + d] = f2bf(y - bf2f(hv));
    }
}

// ---------------------------------------------------------------------------
__global__ __launch_bounds__(256) void k_final(const float* __restrict__ h,
                                               const float* __restrict__ w1,
                                               const float* __restrict__ b1,
                                               const float* __restrict__ w2,
                                               const float* __restrict__ b2,
                                               float* __restrict__ r) {
    int tok = blockIdx.x;
    int t = threadIdx.x;
    __shared__ float hs[EMBEDc];
    __shared__ float hid[EMBEDc];
    hs[t] = h[(size_t)tok * EMBEDc + t];
    __syncthreads();
    float s = b1[t];
    const float* w = w1 + (size_t)t * EMBEDc;
    for (int c = 0; c < EMBEDc; ++c) s += hs[c] * w[c];
    hid[t] = fmaxf(s, 0.f);
    __syncthreads();
    if (t < 3) {
        float o = b2[t];
        const float* wr = w2 + (size_t)t * EMBEDc;
        for (int c = 0; c < EMBEDc; ++c) o += hid[c] * wr[c];
        r[(size_t)tok * 3 + t] = o;
    }
}

// ---------------------------------------------------------------------------
__global__ __launch_bounds__(256) void k_dmap(const float* __restrict__ r,
                                              float* __restrict__ d) {
    int b = blockIdx.x;
    int n = b / Lc;
    float xi = r[(size_t)b * 3], yi = r[(size_t)b * 3 + 1], zi = r[(size_t)b * 3 + 2];
    const float* rn = r + (size_t)n * Lc * 3;
    for (int j = threadIdx.x; j < Lc; j += 256) {
        float dx = xi - rn[j * 3];
        float dy = yi - rn[j * 3 + 1];
        float dz = zi - rn[j * 3 + 2];
        d[(size_t)b * Lc + j] = sqrtf(dx * dx + dy * dy + dz * dz + 1e-12f);
    }
}

// ---------------------------------------------------------------------------
extern "C" void kernel_launch(void* const* d_in, const int* in_sizes, int n_in,
                              void* d_out, int out_size, void* d_ws, size_t ws_size,
                              hipStream_t stream) {
    const float* z       = (const float*)d_in[0];
    const float* x       = (const float*)d_in[1];
    const float* pos_emb = (const float*)d_in[2];
    const float* aa_emb  = (const float*)d_in[3];
    const float* ex_w1   = (const float*)d_in[4];
    const float* ex_b1   = (const float*)d_in[5];
    const float* ex_w2   = (const float*)d_in[6];
    const float* ex_b2   = (const float*)d_in[7];
    const float* Wq      = (const float*)d_in[8];
    const float* Wk      = (const float*)d_in[9];
    const float* Wv      = (const float*)d_in[10];
    const float* Wo      = (const float*)d_in[11];
    const float* bo      = (const float*)d_in[12];
    const float* W2d     = (const float*)d_in[13];
    const float* b2d     = (const float*)d_in[14];
    const float* Wf1     = (const float*)d_in[15];
    const float* bf1     = (const float*)d_in[16];
    const float* Wf2     = (const float*)d_in[17];
    const float* bf2     = (const float*)d_in[18];
    const float* ln1_g   = (const float*)d_in[19];
    const float* ln1_b   = (const float*)d_in[20];
    const float* ln2_g   = (const float*)d_in[21];
    const float* ln2_b   = (const float*)d_in[22];
    const float* o_w1    = (const float*)d_in[23];
    const float* o_b1    = (const float*)d_in[24];
    const float* o_w2    = (const float*)d_in[25];
    const float* o_b2    = (const float*)d_in[26];

    float* h    = (float*)d_ws;                    // 4096*256
    float* s2   = h + (size_t)NTOK * EMBEDc;       // 4096*256
    float* bbuf = s2 + (size_t)NTOK * EMBEDc;      // 6*16*49 (pad 8192)
    float* r    = bbuf + 8192;                     // 4096*3 (pad 16384)
    short* qkvh = (short*)(r + 16384);             // 4096*768
    short* qkvl = qkvh + (size_t)NTOK * 768;
    short* um_hi = qkvl + (size_t)NTOK * 768;      // 4096*288
    short* um_lo = um_hi + (size_t)NTOK * UMDIM;
    short* o_hi  = um_lo + (size_t)NTOK * UMDIM;   // 4096*256
    short* o_lo  = o_hi + (size_t)NTOK * EMBEDc;
    short* f1_hi = o_lo + (size_t)NTOK * EMBEDc;   // 4096*1024
    short* f1_lo = f1_hi + (size_t)NTOK * DFFc;
    short* wqkv_hi = f1_lo + (size_t)NTOK * DFFc;  // 6*768*256
    short* wqkv_lo = wqkv_hi + (size_t)NLc * 768 * EMBEDc;
    short* wo_hi   = wqkv_lo + (size_t)NLc * 768 * EMBEDc;   // 6*256*256
    short* wo_lo   = wo_hi + (size_t)NLc * EMBEDc * DMc;
    short* wf1_hi  = wo_lo + (size_t)NLc * EMBEDc * DMc;     // 6*1024*288
    short* wf1_lo  = wf1_hi + (size_t)NLc * DFFc * UMDIM;
    short* wf2_hi  = wf1_lo + (size_t)NLc * DFFc * UMDIM;    // 6*256*1024
    short* wf2_lo  = wf2_hi + (size_t)NLc * EMBEDc * DFFc;

    k_cvt<<<512, 256, 0, stream>>>(Wq, wqkv_hi, wqkv_lo, DMc * EMBEDc, 768 * EMBEDc, 0, 0.0625f, NLc * DMc * EMBEDc);
    k_cvt<<<512, 256, 0, stream>>>(Wk, wqkv_hi, wqkv_lo, DMc * EMBEDc, 768 * EMBEDc, EMBEDc * EMBEDc, 1.f, NLc * DMc * EMBEDc);
    k_cvt<<<512, 256, 0, stream>>>(Wv, wqkv_hi, wqkv_lo, DMc * EMBEDc, 768 * EMBEDc, 2 * EMBEDc * EMBEDc, 1.f, NLc * DMc * EMBEDc);
    k_cvt<<<512, 256, 0, stream>>>(Wo, wo_hi, wo_lo, EMBEDc * DMc, EMBEDc * DMc, 0, 1.f, NLc * EMBEDc * DMc);
    k_cvt<<<512, 256, 0, stream>>>(Wf1, wf1_hi, wf1_lo, DFFc * UMDIM, DFFc * UMDIM, 0, 1.f, NLc * DFFc * UMDIM);
    k_cvt<<<512, 256, 0, stream>>>(Wf2, wf2_hi, wf2_lo, EMBEDc * DFFc, EMBEDc * DFFc, 0, 1.f, NLc * EMBEDc * DFFc);

    k_biasbins<<<(NLc * NHc * NBINSc + 255) / 256, 256, 0, stream>>>(pos_emb, W2d, b2d, bbuf);
    k_eaa<<<NTOK / 256, 256, 0, stream>>>(x, aa_emb, um_hi, um_lo);
    k_embed<<<NTOK, 256, 0, stream>>>(z, ex_w1, ex_b1, ex_w2, ex_b2, h, um_hi, um_lo);

    for (int l = 0; l < NLc; ++l) {
        // qkv: [4096,768] bf16 hi/lo (w_t folded into Wq)
        k_gemm<2><<<dim3(768 / 64, NTOK / 64), 256, 0, stream>>>(
            um_hi, um_lo, UMDIM,
            wqkv_hi + (size_t)l * 768 * EMBEDc, wqkv_lo + (size_t)l * 768 * EMBEDc, EMBEDc,
            EMBEDc, nullptr, 768, qkvh, qkvl, nullptr);
        k_attn<<<NB * NHc * 4, 256, 0, stream>>>(qkvh, qkvl, bbuf + (size_t)l * NHc * NBINSc, o_hi, o_lo);
        k_gemm<0><<<dim3(EMBEDc / 64, NTOK / 64), 256, 0, stream>>>(
            o_hi, o_lo, EMBEDc,
            wo_hi + (size_t)l * EMBEDc * DMc, wo_lo + (size_t)l * EMBEDc * DMc, DMc,
            DMc, s2, EMBEDc, nullptr, nullptr, nullptr);
        k_ln<<<NTOK / 16, 256, 0, stream>>>(s2, bo + (size_t)l * EMBEDc,
                                            ln1_g + (size_t)l * EMBEDc, ln1_b + (size_t)l * EMBEDc,
                                            h, um_hi, um_lo);
        k_gemm<1><<<dim3(DFFc / 64, NTOK / 64), 256, 0, stream>>>(
            um_hi, um_lo, UMDIM,
            wf1_hi + (size_t)l * DFFc * UMDIM, wf1_lo + (size_t)l * DFFc * UMDIM, UMDIM,
            UMDIM, nullptr, DFFc, f1_hi, f1_lo, bf1 + (size_t)l * DFFc);
        k_gemm<0><<<dim3(EMBEDc / 64, NTOK / 64), 256, 0, stream>>>(
            f1_hi, f1_lo, DFFc,
            wf2_hi + (size_t)l * EMBEDc * DFFc, wf2_lo + (size_t)l * EMBEDc * DFFc, DFFc,
            DFFc, s2, EMBEDc, nullptr, nullptr, nullptr);
        k_ln<<<NTOK / 16, 256, 0, stream>>>(s2, bf2 + (size_t)l * EMBEDc,
                                            ln2_g + (size_t)l * EMBEDc, ln2_b + (size_t)l * EMBEDc,
                                            h, um_hi, um_lo);
    }

    k_final<<<NTOK, 256, 0, stream>>>(h, o_w1, o_b1, o_w2, o_b2, r);
    k_dmap<<<NB * Lc, 256, 0, stream>>>(r, (float*)d_out);
}

// Round 4
// 1298.455 us; speedup vs baseline: 4.2517x; 1.0742x over previous
//
#include <hip/hip_runtime.h>
#include <math.h>

#define NZc     64
#define EMBEDc  256
#define DMc     256
#define NHc     16
#define HDc     16
#define DFFc    1024
#define NLc     6
#define E1Dc    32
#define PDIMc   64
#define PMAXLc  24
#define NBINSc  49
#define NB      8
#define Lc      512
#define NTOK    (NB * Lc)        // 4096
#define UMDIM   (EMBEDc + E1Dc)  // 288

typedef __attribute__((ext_vector_type(4))) float f4;
typedef __attribute__((ext_vector_type(8))) short bf8;   // 8 bf16 in 4 VGPRs

#define MFMA(a, b, c) __builtin_amdgcn_mfma_f32_16x16x32_bf16((a), (b), (c), 0, 0, 0)

__device__ __forceinline__ short f2bf(float f) {
    unsigned u = __float_as_uint(f);
    u += 0x7FFFu + ((u >> 16) & 1u);   // round-to-nearest-even
    return (short)(u >> 16);
}
__device__ __forceinline__ float bf2f(short s) {
    return __uint_as_float(((unsigned)(unsigned short)s) << 16);
}

// ---------------------------------------------------------------------------
// weight conversion: fp32 -> bf16 hi/lo with per-layer dest strides
__global__ void k_cvt(const float* __restrict__ src, short* __restrict__ hi,
                      short* __restrict__ lo, int per_layer, int dst_stride,
                      int dst_off, float scale, int total) {
    for (int i = blockIdx.x * blockDim.x + threadIdx.x; i < total;
         i += gridDim.x * blockDim.x) {
        int l = i / per_layer, rels = i - l * per_layer;
        size_t di = (size_t)l * dst_stride + dst_off + rels;
        float v = src[i] * scale;
        short h = f2bf(v);
        hi[di] = h;
        lo[di] = f2bf(v - bf2f(h));
    }
}

// ---------------------------------------------------------------------------
__global__ void k_biasbins(const float* __restrict__ pos_emb,
                           const float* __restrict__ W2d,
                           const float* __restrict__ b2d,
                           float* __restrict__ bb) {
    int idx = blockIdx.x * blockDim.x + threadIdx.x;
    if (idx >= NLc * NHc * NBINSc) return;
    int bin = idx % NBINSc;
    int tmp = idx / NBINSc;
    int hh = tmp % NHc;
    int l  = tmp / NHc;
    float s = b2d[l * NHc + hh];
    const float* pe = pos_emb + bin * PDIMc;
    const float* w  = W2d + (l * NHc + hh) * PDIMc;
    for (int p = 0; p < PDIMc; ++p) s += pe[p] * w[p];
    bb[idx] = s;
}

// ---------------------------------------------------------------------------
__global__ void k_eaa(const float* __restrict__ x,
                      const float* __restrict__ aa_emb,
                      short* __restrict__ umhi, short* __restrict__ umlo) {
    int tok = blockIdx.x * blockDim.x + threadIdx.x;
    if (tok >= NTOK) return;
    int n = tok / Lc, l = tok % Lc;
    const float* xp = x + (size_t)n * 20 * Lc + l;
    float best = xp[0];
    int bi = 0;
    for (int c = 1; c < 20; ++c) {
        float v = xp[c * Lc];
        if (v > best) { best = v; bi = c; }
    }
    const float* e = aa_emb + bi * E1Dc;
    for (int c = 0; c < E1Dc; ++c) {
        float v = e[c];
        short h = f2bf(v);
        umhi[(size_t)tok * UMDIM + EMBEDc + c] = h;
        umlo[(size_t)tok * UMDIM + EMBEDc + c] = f2bf(v - bf2f(h));
    }
}

// ---------------------------------------------------------------------------
// transpose z (N,NZ,L) -> zt (tok, NZ) bf16 hi/lo. reads coalesced over l.
__global__ __launch_bounds__(256) void k_zt(const float* __restrict__ z,
                                            short* __restrict__ zth,
                                            short* __restrict__ ztl) {
    int tok = blockIdx.x * blockDim.x + threadIdx.x;
    int n = tok >> 9, l = tok & 511;
    for (int c = 0; c < NZc; ++c) {
        float v = z[((size_t)n * NZc + c) * Lc + l];
        short hv = f2bf(v);
        zth[(size_t)tok * NZc + c] = hv;
        ztl[(size_t)tok * NZc + c] = f2bf(v - bf2f(hv));
    }
}

// ---------------------------------------------------------------------------
// MFMA GEMM: C[M x N] = A @ W^T, 3-term compensated bf16.
// 4 waves, wave = 16 rows x (16*NF) cols. grid = (N/(16*NF), M/64).
// EPI 0: fp32 out(ldo). EPI 1: relu(acc+bias)->hi/lo(ldh).
// EPI 2: acc->hi/lo(ldh). EPI 3: acc+bias->fp32 out(ldo) AND hi/lo(ldh).
template <int EPI, int NF>
__global__ __launch_bounds__(256) void k_gemm(
    const short* __restrict__ Ahi, const short* __restrict__ Alo, int lda,
    const short* __restrict__ Bhi, const short* __restrict__ Blo, int ldb,
    int K, float* __restrict__ outf, int ldo, short* __restrict__ ohi,
    short* __restrict__ olo, int ldh, const float* __restrict__ bias) {
    int wv = threadIdx.x >> 6, l = threadIdx.x & 63;
    int lr = l & 15, lk = l >> 4;
    int m0 = blockIdx.y * 64 + wv * 16;
    int n0 = blockIdx.x * 16 * NF;
    const short* ap_h = Ahi + (size_t)(m0 + lr) * lda + lk * 8;
    const short* ap_l = Alo + (size_t)(m0 + lr) * lda + lk * 8;
    const short* bp_h = Bhi + (size_t)(n0 + lr) * ldb + lk * 8;
    const short* bp_l = Blo + (size_t)(n0 + lr) * ldb + lk * 8;
    f4 acc[NF];
#pragma unroll
    for (int nf = 0; nf < NF; ++nf) acc[nf] = (f4){0.f, 0.f, 0.f, 0.f};
    for (int ks = 0; ks < K; ks += 32) {
        bf8 ah = *(const bf8*)(ap_h + ks);
        bf8 al = *(const bf8*)(ap_l + ks);
#pragma unroll
        for (int nf = 0; nf < NF; ++nf) {
            bf8 bh = *(const bf8*)(bp_h + nf * 16 * ldb + ks);
            bf8 bl = *(const bf8*)(bp_l + nf * 16 * ldb + ks);
            acc[nf] = MFMA(ah, bh, acc[nf]);
            acc[nf] = MFMA(ah, bl, acc[nf]);
            acc[nf] = MFMA(al, bh, acc[nf]);
        }
    }
#pragma unroll
    for (int nf = 0; nf < NF; ++nf) {
        int n = n0 + nf * 16 + lr;
        if (EPI == 0) {
#pragma unroll
            for (int r = 0; r < 4; ++r)
                outf[(size_t)(m0 + lk * 4 + r) * ldo + n] = acc[nf][r];
        } else if (EPI == 1) {
            float bv = bias[n];
#pragma unroll
            for (int r = 0; r < 4; ++r) {
                float y = fmaxf(acc[nf][r] + bv, 0.f);
                short hv = f2bf(y);
                size_t oi = (size_t)(m0 + lk * 4 + r) * ldh + n;
                ohi[oi] = hv;
                olo[oi] = f2bf(y - bf2f(hv));
            }
        } else if (EPI == 2) {
#pragma unroll
            for (int r = 0; r < 4; ++r) {
                float y = acc[nf][r];
                short hv = f2bf(y);
                size_t oi = (size_t)(m0 + lk * 4 + r) * ldh + n;
                ohi[oi] = hv;
                olo[oi] = f2bf(y - bf2f(hv));
            }
        } else {
            float bv = bias[n];
#pragma unroll
            for (int r = 0; r < 4; ++r) {
                float y = acc[nf][r] + bv;
                outf[(size_t)(m0 + lk * 4 + r) * ldo + n] = y;
                short hv = f2bf(y);
                size_t oi = (size_t)(m0 + lk * 4 + r) * ldh + n;
                ohi[oi] = hv;
                olo[oi] = f2bf(y - bf2f(hv));
            }
        }
    }
}

// ---------------------------------------------------------------------------
// MFMA flash attention (validated round 3). qkvh/l: [4096][768] bf16 hi/lo.
__global__ __launch_bounds__(256) void k_attn(const short* __restrict__ qh,
                                              const short* __restrict__ ql,
                                              const float* __restrict__ bb,
                                              short* __restrict__ ohi,
                                              short* __restrict__ olo) {
    int bx = blockIdx.x;
    int qt = bx & 3, head = (bx >> 2) & 15, n = bx >> 6;
    int t = threadIdx.x;
    int w = t >> 6, l = t & 63;
    int lq = l & 15, lk = l >> 4;

    __shared__ __align__(16) short khl[512][40];
    __shared__ __align__(16) short vth[16][536];
    __shared__ __align__(16) short vtl[16][536];
    __shared__ float biasr[64];

    if (t < NBINSc) biasr[t] = bb[head * NBINSc + t];

    size_t base = (size_t)n * Lc * 768 + head * 16;
    for (int u = t; u < 2048; u += 256) {
        int key = u >> 2, seg = u & 3;
        const short* src = (seg < 2 ? qh : ql) + base + 256 + (size_t)key * 768 + (seg & 1) * 8;
        *(bf8*)&khl[key][seg * 8] = *(const bf8*)src;
    }
    for (int u = t; u < 1024; u += 256) {
        int key = u >> 1, half = u & 1;
        bf8 v8h = *(const bf8*)(qh + base + 512 + (size_t)key * 768 + half * 8);
        bf8 v8l = *(const bf8*)(ql + base + 512 + (size_t)key * 768 + half * 8);
#pragma unroll
        for (int i = 0; i < 8; ++i) {
            vth[half * 8 + i][key] = v8h[i];
            vtl[half * 8 + i][key] = v8l[i];
        }
    }
    __syncthreads();

    for (int qi = 0; qi < 2; ++qi) {
        int qg = qt * 128 + w * 32 + qi * 16 + lq;
        size_t qrow = ((size_t)n * Lc + qg) * 768 + head * 16;
        bf8 B1 = *(const bf8*)(qh + qrow + (lk & 1) * 8);
        bf8 B2;
        if (lk < 2) B2 = *(const bf8*)(ql + qrow + lk * 8);
        else {
#pragma unroll
            for (int i = 0; i < 8; ++i) B2[i] = 0;
        }

        f4 acc = (f4){0.f, 0.f, 0.f, 0.f};
        float m = -1e30f, lsum = 0.f;

        for (int kt = 0; kt < 32; ++kt) {
            bf8 A1 = *(const bf8*)&khl[kt * 16 + lq][lk * 8];
            f4 s = (f4){0.f, 0.f, 0.f, 0.f};
            s = MFMA(A1, B1, s);
            s = MFMA(A1, B2, s);
            int kb = kt * 16 + lk * 4;
#pragma unroll
            for (int r = 0; r < 4; ++r) {
                int rel = kb + r - qg;
                rel = rel < -PMAXLc ? -PMAXLc : (rel > PMAXLc ? PMAXLc : rel);
                s[r] += biasr[rel + PMAXLc];
            }
            float mt = fmaxf(fmaxf(s[0], s[1]), fmaxf(s[2], s[3]));
            mt = fmaxf(mt, __shfl_xor(mt, 16));
            mt = fmaxf(mt, __shfl_xor(mt, 32));
            float mn = fmaxf(m, mt);
            float alpha = __expf(m - mn);
            m = mn;
            f4 p;
#pragma unroll
            for (int r = 0; r < 4; ++r) p[r] = __expf(s[r] - mn);
            lsum = lsum * alpha + (p[0] + p[1] + p[2] + p[3]);
#pragma unroll
            for (int r = 0; r < 4; ++r) acc[r] *= __shfl(alpha, lk * 4 + r);
            int src0 = (lk & 1) * 32 + lq;
            int src1 = src0 + 16;
            float g[8];
#pragma unroll
            for (int j = 0; j < 4; ++j) {
                g[j]     = __shfl(p[j], src0);
                g[j + 4] = __shfl(p[j], src1);
            }
            bf8 PA;
#pragma unroll
            for (int j = 0; j < 8; ++j) {
                short hv = f2bf(g[j]);
                PA[j] = (lk < 2) ? hv : f2bf(g[j] - bf2f(hv));
            }
            bf8 VB1 = *(const bf8*)&vth[lq][kt * 16 + (lk & 1) * 8];
            bf8 VB2;
            if (lk < 2) VB2 = *(const bf8*)&vtl[lq][kt * 16 + lk * 8];
            else {
#pragma unroll
                for (int i = 0; i < 8; ++i) VB2[i] = 0;
            }
            acc = MFMA(PA, VB1, acc);
            acc = MFMA(PA, VB2, acc);
        }

        float lr = lsum + __shfl_xor(lsum, 16);
        lr += __shfl_xor(lr, 32);
        float inv = 1.0f / lr;
#pragma unroll
        for (int r = 0; r < 4; ++r) {
            float iq = __shfl(inv, lk * 4 + r);
            float y = acc[r] * iq;
            int qo = qt * 128 + w * 32 + qi * 16 + lk * 4 + r;
            size_t oi = ((size_t)n * Lc + qo) * DMc + head * 16 + lq;
            short hv = f2bf(y);
            ohi[oi] = hv;
            olo[oi] = f2bf(y - bf2f(hv));
        }
    }
}

// ---------------------------------------------------------------------------
__global__ __launch_bounds__(256) void k_ln(const float* __restrict__ s2,
                                            const float* __restrict__ sbias,
                                            const float* __restrict__ g,
                                            const float* __restrict__ bta,
                                            float* __restrict__ h,
                                            short* __restrict__ umhi,
                                            short* __restrict__ umlo) {
    int tile = blockIdx.x;
    int t = threadIdx.x;
    int tok = t >> 4, j = t & 15;
    size_t gtok = (size_t)tile * 16 + tok;
    float sum = 0.f, ssq = 0.f;
    float vals[16];
#pragma unroll
    for (int d0 = 0; d0 < 16; ++d0) {
        int d = j + d0 * 16;
        float vv = h[gtok * EMBEDc + d] + s2[gtok * EMBEDc + d] + sbias[d];
        vals[d0] = vv;
        sum += vv;
        ssq += vv * vv;
    }
#pragma unroll
    for (int off = 8; off; off >>= 1) {
        sum += __shfl_xor(sum, off, 16);
        ssq += __shfl_xor(ssq, off, 16);
    }
    float mean = sum * (1.f / EMBEDc);
    float var = ssq * (1.f / EMBEDc) - mean * mean;
    float inv = rsqrtf(var + 1e-5f);
#pragma unroll
    for (int d0 = 0; d0 < 16; ++d0) {
        int d = j + d0 * 16;
        float y = (vals[d0] - mean) * inv * g[d] + bta[d];
        h[gtok * EMBEDc + d] = y;
        short hv = f2bf(y);
        umhi[gtok * UMDIM + d] = hv;
        umlo[gtok * UMDIM + d] = f2bf(y - bf2f(hv));
    }
}

// ---------------------------------------------------------------------------
// r = f @ o_w2^T + o_b2  (N=3). f: bf16 hi/lo [4096][256]. 64 tokens/block.
__global__ __launch_bounds__(256) void k_r(const short* __restrict__ fh,
                                           const short* __restrict__ fl,
                                           const float* __restrict__ w2,
                                           const float* __restrict__ b2,
                                           float* __restrict__ r) {
    __shared__ float w[3][EMBEDc];
    int t = threadIdx.x;
    for (int u = t; u < 3 * EMBEDc; u += 256) w[u >> 8][u & 255] = w2[u];
    __syncthreads();
    int tok = blockIdx.x * 64 + (t >> 2), o = t & 3;
    if (o < 3) {
        const short* ph = fh + (size_t)tok * EMBEDc;
        const short* pl = fl + (size_t)tok * EMBEDc;
        float s = b2[o];
        for (int c8 = 0; c8 < EMBEDc / 8; ++c8) {
            bf8 vh = *(const bf8*)(ph + c8 * 8);
            bf8 vl = *(const bf8*)(pl + c8 * 8);
#pragma unroll
            for (int j = 0; j < 8; ++j)
                s += (bf2f(vh[j]) + bf2f(vl[j])) * w[o][c8 * 8 + j];
        }
        r[(size_t)tok * 3 + o] = s;
    }
}

// ---------------------------------------------------------------------------
__global__ __launch_bounds__(256) void k_dmap(const float* __restrict__ r,
                                              float* __restrict__ d) {
    int b = blockIdx.x;
    int n = b / Lc;
    float xi = r[(size_t)b * 3], yi = r[(size_t)b * 3 + 1], zi = r[(size_t)b * 3 + 2];
    const float* rn = r + (size_t)n * Lc * 3;
    for (int j = threadIdx.x; j < Lc; j += 256) {
        float dx = xi - rn[j * 3];
        float dy = yi - rn[j * 3 + 1];
        float dz = zi - rn[j * 3 + 2];
        d[(size_t)b * Lc + j] = sqrtf(dx * dx + dy * dy + dz * dz + 1e-12f);
    }
}

// ---------------------------------------------------------------------------
extern "C" void kernel_launch(void* const* d_in, const int* in_sizes, int n_in,
                              void* d_out, int out_size, void* d_ws, size_t ws_size,
                              hipStream_t stream) {
    const float* z       = (const float*)d_in[0];
    const float* x       = (const float*)d_in[1];
    const float* pos_emb = (const float*)d_in[2];
    const float* aa_emb  = (const float*)d_in[3];
    const float* ex_w1   = (const float*)d_in[4];
    const float* ex_b1   = (const float*)d_in[5];
    const float* ex_w2   = (const float*)d_in[6];
    const float* ex_b2   = (const float*)d_in[7];
    const float* Wq      = (const float*)d_in[8];
    const float* Wk      = (const float*)d_in[9];
    const float* Wv      = (const float*)d_in[10];
    const float* Wo      = (const float*)d_in[11];
    const float* bo      = (const float*)d_in[12];
    const float* W2d     = (const float*)d_in[13];
    const float* b2d     = (const float*)d_in[14];
    const float* Wf1     = (const float*)d_in[15];
    const float* bf1     = (const float*)d_in[16];
    const float* Wf2     = (const float*)d_in[17];
    const float* bf2     = (const float*)d_in[18];
    const float* ln1_g   = (const float*)d_in[19];
    const float* ln1_b   = (const float*)d_in[20];
    const float* ln2_g   = (const float*)d_in[21];
    const float* ln2_b   = (const float*)d_in[22];
    const float* o_w1    = (const float*)d_in[23];
    const float* o_b1    = (const float*)d_in[24];
    const float* o_w2    = (const float*)d_in[25];
    const float* o_b2    = (const float*)d_in[26];

    float* h    = (float*)d_ws;                    // 4096*256
    float* s2   = h + (size_t)NTOK * EMBEDc;
    float* bbuf = s2 + (size_t)NTOK * EMBEDc;      // pad 8192
    float* r    = bbuf + 8192;                     // pad 16384
    short* qkvh = (short*)(r + 16384);             // 4096*768
    short* qkvl = qkvh + (size_t)NTOK * 768;
    short* um_hi = qkvl + (size_t)NTOK * 768;      // 4096*288
    short* um_lo = um_hi + (size_t)NTOK * UMDIM;
    short* o_hi  = um_lo + (size_t)NTOK * UMDIM;   // 4096*256
    short* o_lo  = o_hi + (size_t)NTOK * EMBEDc;
    short* f1_hi = o_lo + (size_t)NTOK * EMBEDc;   // 4096*1024
    short* f1_lo = f1_hi + (size_t)NTOK * DFFc;
    short* wqkv_hi = f1_lo + (size_t)NTOK * DFFc;  // 6*768*256
    short* wqkv_lo = wqkv_hi + (size_t)NLc * 768 * EMBEDc;
    short* wo_hi   = wqkv_lo + (size_t)NLc * 768 * EMBEDc;   // 6*256*256
    short* wo_lo   = wo_hi + (size_t)NLc * EMBEDc * DMc;
    short* wf1_hi  = wo_lo + (size_t)NLc * EMBEDc * DMc;     // 6*1024*288
    short* wf1_lo  = wf1_hi + (size_t)NLc * DFFc * UMDIM;
    short* wf2_hi  = wf1_lo + (size_t)NLc * DFFc * UMDIM;    // 6*256*1024
    short* wf2_lo  = wf2_hi + (size_t)NLc * EMBEDc * DFFc;
    short* wex1_hi = wf2_lo + (size_t)NLc * EMBEDc * DFFc;   // 256*64
    short* wex1_lo = wex1_hi + EMBEDc * NZc;
    short* wex2_hi = wex1_lo + EMBEDc * NZc;                 // 256*256
    short* wex2_lo = wex2_hi + EMBEDc * EMBEDc;
    short* wo1_hi  = wex2_lo + EMBEDc * EMBEDc;              // 256*256
    short* wo1_lo  = wo1_hi + EMBEDc * EMBEDc;
    // zt aliases the o buffer (only used in preamble, before k_attn writes o)
    short* zt_hi = o_hi;
    short* zt_lo = o_lo;

    k_cvt<<<512, 256, 0, stream>>>(Wq, wqkv_hi, wqkv_lo, DMc * EMBEDc, 768 * EMBEDc, 0, 0.0625f, NLc * DMc * EMBEDc);
    k_cvt<<<512, 256, 0, stream>>>(Wk, wqkv_hi, wqkv_lo, DMc * EMBEDc, 768 * EMBEDc, EMBEDc * EMBEDc, 1.f, NLc * DMc * EMBEDc);
    k_cvt<<<512, 256, 0, stream>>>(Wv, wqkv_hi, wqkv_lo, DMc * EMBEDc, 768 * EMBEDc, 2 * EMBEDc * EMBEDc, 1.f, NLc * DMc * EMBEDc);
    k_cvt<<<512, 256, 0, stream>>>(Wo, wo_hi, wo_lo, EMBEDc * DMc, EMBEDc * DMc, 0, 1.f, NLc * EMBEDc * DMc);
    k_cvt<<<512, 256, 0, stream>>>(Wf1, wf1_hi, wf1_lo, DFFc * UMDIM, DFFc * UMDIM, 0, 1.f, NLc * DFFc * UMDIM);
    k_cvt<<<512, 256, 0, stream>>>(Wf2, wf2_hi, wf2_lo, EMBEDc * DFFc, EMBEDc * DFFc, 0, 1.f, NLc * EMBEDc * DFFc);
    k_cvt<<<64, 256, 0, stream>>>(ex_w1, wex1_hi, wex1_lo, EMBEDc * NZc, EMBEDc * NZc, 0, 1.f, EMBEDc * NZc);
    k_cvt<<<256, 256, 0, stream>>>(ex_w2, wex2_hi, wex2_lo, EMBEDc * EMBEDc, EMBEDc * EMBEDc, 0, 1.f, EMBEDc * EMBEDc);
    k_cvt<<<256, 256, 0, stream>>>(o_w1, wo1_hi, wo1_lo, EMBEDc * EMBEDc, EMBEDc * EMBEDc, 0, 1.f, EMBEDc * EMBEDc);

    k_biasbins<<<(NLc * NHc * NBINSc + 255) / 256, 256, 0, stream>>>(pos_emb, W2d, b2d, bbuf);
    k_eaa<<<NTOK / 256, 256, 0, stream>>>(x, aa_emb, um_hi, um_lo);

    // embed: zt -> relu GEMM -> GEMM (fp32 h + bf16 um)
    k_zt<<<NTOK / 256, 256, 0, stream>>>(z, zt_hi, zt_lo);
    k_gemm<1, 1><<<dim3(16, 64), 256, 0, stream>>>(
        zt_hi, zt_lo, NZc, wex1_hi, wex1_lo, NZc, NZc,
        nullptr, 0, f1_hi, f1_lo, EMBEDc, ex_b1);
    k_gemm<3, 1><<<dim3(16, 64), 256, 0, stream>>>(
        f1_hi, f1_lo, EMBEDc, wex2_hi, wex2_lo, EMBEDc, EMBEDc,
        h, EMBEDc, um_hi, um_lo, UMDIM, ex_b2);

    for (int l = 0; l < NLc; ++l) {
        k_gemm<2, 4><<<dim3(12, 64), 256, 0, stream>>>(
            um_hi, um_lo, UMDIM,
            wqkv_hi + (size_t)l * 768 * EMBEDc, wqkv_lo + (size_t)l * 768 * EMBEDc, EMBEDc,
            EMBEDc, nullptr, 0, qkvh, qkvl, 768, nullptr);
        k_attn<<<NB * NHc * 4, 256, 0, stream>>>(qkvh, qkvl, bbuf + (size_t)l * NHc * NBINSc, o_hi, o_lo);
        k_gemm<0, 1><<<dim3(16, 64), 256, 0, stream>>>(
            o_hi, o_lo, EMBEDc,
            wo_hi + (size_t)l * EMBEDc * DMc, wo_lo + (size_t)l * EMBEDc * DMc, DMc,
            DMc, s2, EMBEDc, nullptr, nullptr, 0, nullptr);
        k_ln<<<NTOK / 16, 256, 0, stream>>>(s2, bo + (size_t)l * EMBEDc,
                                            ln1_g + (size_t)l * EMBEDc, ln1_b + (size_t)l * EMBEDc,
                                            h, um_hi, um_lo);
        k_gemm<1, 4><<<dim3(16, 64), 256, 0, stream>>>(
            um_hi, um_lo, UMDIM,
            wf1_hi + (size_t)l * DFFc * UMDIM, wf1_lo + (size_t)l * DFFc * UMDIM, UMDIM,
            UMDIM, nullptr, 0, f1_hi, f1_lo, DFFc, bf1 + (size_t)l * DFFc);
        k_gemm<0, 1><<<dim3(16, 64), 256, 0, stream>>>(
            f1_hi, f1_lo, DFFc,
            wf2_hi + (size_t)l * EMBEDc * DFFc, wf2_lo + (size_t)l * EMBEDc * DFFc, DFFc,
            DFFc, s2, EMBEDc, nullptr, nullptr, 0, nullptr);
        k_ln<<<NTOK / 16, 256, 0, stream>>>(s2, bf2 + (size_t)l * EMBEDc,
                                            ln2_g + (size_t)l * EMBEDc, ln2_b + (size_t)l * EMBEDc,
                                            h, um_hi, um_lo);
    }

    // final: f = relu(um @ o_w1^T + o_b1) (um cols 0..255 hold h in bf16)
    k_gemm<1, 1><<<dim3(16, 64), 256, 0, stream>>>(
        um_hi, um_lo, UMDIM, wo1_hi, wo1_lo, EMBEDc, EMBEDc,
        nullptr, 0, f1_hi, f1_lo, EMBEDc, o_b1);
    k_r<<<NTOK / 64, 256, 0, stream>>>(f1_hi, f1_lo, o_w2, o_b2, r);
    k_dmap<<<NB * Lc, 256, 0, stream>>>(r, (float*)d_out);
}

// Round 5
// 880.725 us; speedup vs baseline: 6.2683x; 1.4743x over previous
//
#include <hip/hip_runtime.h>
#include <math.h>

#define NZc     64
#define EMBEDc  256
#define DMc     256
#define NHc     16
#define HDc     16
#define DFFc    1024
#define NLc     6
#define E1Dc    32
#define PDIMc   64
#define PMAXLc  24
#define NBINSc  49
#define NB      8
#define Lc      512
#define NTOK    (NB * Lc)        // 4096
#define UMDIM   (EMBEDc + E1Dc)  // 288

typedef __attribute__((ext_vector_type(4))) float f4;
typedef __attribute__((ext_vector_type(8))) short bf8;   // 8 bf16 in 4 VGPRs

#define MFMA(a, b, c) __builtin_amdgcn_mfma_f32_16x16x32_bf16((a), (b), (c), 0, 0, 0)

__device__ __forceinline__ short f2bf(float f) {
    unsigned u = __float_as_uint(f);
    u += 0x7FFFu + ((u >> 16) & 1u);   // round-to-nearest-even
    return (short)(u >> 16);
}
__device__ __forceinline__ float bf2f(short s) {
    return __uint_as_float(((unsigned)(unsigned short)s) << 16);
}

// ---------------------------------------------------------------------------
// weight conversion: fp32 -> bf16 hi/lo with per-layer dest strides
__global__ void k_cvt(const float* __restrict__ src, short* __restrict__ hi,
                      short* __restrict__ lo, int per_layer, int dst_stride,
                      int dst_off, float scale, int total) {
    for (int i = blockIdx.x * blockDim.x + threadIdx.x; i < total;
         i += gridDim.x * blockDim.x) {
        int l = i / per_layer, rels = i - l * per_layer;
        size_t di = (size_t)l * dst_stride + dst_off + rels;
        float v = src[i] * scale;
        short h = f2bf(v);
        hi[di] = h;
        lo[di] = f2bf(v - bf2f(h));
    }
}

// ---------------------------------------------------------------------------
__global__ void k_biasbins(const float* __restrict__ pos_emb,
                           const float* __restrict__ W2d,
                           const float* __restrict__ b2d,
                           float* __restrict__ bb) {
    int idx = blockIdx.x * blockDim.x + threadIdx.x;
    if (idx >= NLc * NHc * NBINSc) return;
    int bin = idx % NBINSc;
    int tmp = idx / NBINSc;
    int hh = tmp % NHc;
    int l  = tmp / NHc;
    float s = b2d[l * NHc + hh];
    const float* pe = pos_emb + bin * PDIMc;
    const float* w  = W2d + (l * NHc + hh) * PDIMc;
    for (int p = 0; p < PDIMc; ++p) s += pe[p] * w[p];
    bb[idx] = s;
}

// ---------------------------------------------------------------------------
__global__ void k_eaa(const float* __restrict__ x,
                      const float* __restrict__ aa_emb,
                      short* __restrict__ umhi, short* __restrict__ umlo) {
    int tok = blockIdx.x * blockDim.x + threadIdx.x;
    if (tok >= NTOK) return;
    int n = tok / Lc, l = tok % Lc;
    const float* xp = x + (size_t)n * 20 * Lc + l;
    float best = xp[0];
    int bi = 0;
    for (int c = 1; c < 20; ++c) {
        float v = xp[c * Lc];
        if (v > best) { best = v; bi = c; }
    }
    const float* e = aa_emb + bi * E1Dc;
    for (int c = 0; c < E1Dc; ++c) {
        float v = e[c];
        short h = f2bf(v);
        umhi[(size_t)tok * UMDIM + EMBEDc + c] = h;
        umlo[(size_t)tok * UMDIM + EMBEDc + c] = f2bf(v - bf2f(h));
    }
}

// ---------------------------------------------------------------------------
// transpose z (N,NZ,L) -> zt (tok, NZ) bf16 hi/lo. reads coalesced over l.
__global__ __launch_bounds__(256) void k_zt(const float* __restrict__ z,
                                            short* __restrict__ zth,
                                            short* __restrict__ ztl) {
    int tok = blockIdx.x * blockDim.x + threadIdx.x;
    int n = tok >> 9, l = tok & 511;
    for (int c = 0; c < NZc; ++c) {
        float v = z[((size_t)n * NZc + c) * Lc + l];
        short hv = f2bf(v);
        zth[(size_t)tok * NZc + c] = hv;
        ztl[(size_t)tok * NZc + c] = f2bf(v - bf2f(hv));
    }
}

// ---------------------------------------------------------------------------
// LDS-staged MFMA GEMM: C[M x N] = A @ W^T, 3-term compensated bf16.
// Tile 128M x 64N, BK=32, 256 thr (4 waves). Wave w owns rows w*32..w*32+32
// (Mf=2) x all 64 N (Nf=4): 24 MFMA vs 12 ds_read_b128 per K-step.
// Staging: coalesced 16B row-segments, register-prefetched one step ahead.
// LDS linear [rows][32] shorts (64B rows): fragment reads self-distribute
// over all 32 banks (16 rows x 64B = 1KB; inherent 8 cyc, even spread).
// EPI 0: fp32 out(ldo). EPI 1: relu(acc+bias)->hi/lo(ldh).
// EPI 2: acc->hi/lo(ldh). EPI 3: acc+bias->fp32 out(ldo) AND hi/lo(ldh).
template <int EPI>
__global__ __launch_bounds__(256) void k_gemm2(
    const short* __restrict__ Ahi, const short* __restrict__ Alo, int lda,
    const short* __restrict__ Bhi, const short* __restrict__ Blo, int ldb,
    int K, float* __restrict__ outf, int ldo, short* __restrict__ ohi,
    short* __restrict__ olo, int ldh, const float* __restrict__ bias) {
    __shared__ __align__(16) short Ah[128][32];
    __shared__ __align__(16) short Al[128][32];
    __shared__ __align__(16) short Bh[64][32];
    __shared__ __align__(16) short Bl[64][32];

    int t = threadIdx.x;
    int w = t >> 6, l = t & 63, lr = l & 15, lk = l >> 4;
    int m0 = blockIdx.y * 128;
    int n0 = blockIdx.x * 64;

    // staging coords: thread t -> row t>>2, 16B segment (t&3)
    int srow = t >> 2, scol = (t & 3) * 8;
    const short* gah0 = Ahi + (size_t)(m0 + srow) * lda + scol;
    const short* gah1 = Ahi + (size_t)(m0 + 64 + srow) * lda + scol;
    const short* gal0 = Alo + (size_t)(m0 + srow) * lda + scol;
    const short* gal1 = Alo + (size_t)(m0 + 64 + srow) * lda + scol;
    const short* gbh  = Bhi + (size_t)(n0 + srow) * ldb + scol;
    const short* gbl  = Blo + (size_t)(n0 + srow) * ldb + scol;

    bf8 ra0 = *(const bf8*)gah0;
    bf8 ra1 = *(const bf8*)gah1;
    bf8 rla0 = *(const bf8*)gal0;
    bf8 rla1 = *(const bf8*)gal1;
    bf8 rb = *(const bf8*)gbh;
    bf8 rlb = *(const bf8*)gbl;

    f4 acc[2][4];
#pragma unroll
    for (int mf = 0; mf < 2; ++mf)
#pragma unroll
        for (int nf = 0; nf < 4; ++nf) acc[mf][nf] = (f4){0.f, 0.f, 0.f, 0.f};

    for (int ks = 0; ks < K; ks += 32) {
        __syncthreads();   // all waves done reading previous LDS contents
        *(bf8*)&Ah[srow][scol] = ra0;
        *(bf8*)&Ah[64 + srow][scol] = ra1;
        *(bf8*)&Al[srow][scol] = rla0;
        *(bf8*)&Al[64 + srow][scol] = rla1;
        *(bf8*)&Bh[srow][scol] = rb;
        *(bf8*)&Bl[srow][scol] = rlb;
        __syncthreads();
        if (ks + 32 < K) {   // prefetch next K-step while computing this one
            ra0 = *(const bf8*)(gah0 + ks + 32);
            ra1 = *(const bf8*)(gah1 + ks + 32);
            rla0 = *(const bf8*)(gal0 + ks + 32);
            rla1 = *(const bf8*)(gal1 + ks + 32);
            rb = *(const bf8*)(gbh + ks + 32);
            rlb = *(const bf8*)(gbl + ks + 32);
        }
        bf8 bhf[4], blf[4];
#pragma unroll
        for (int nf = 0; nf < 4; ++nf) {
            bhf[nf] = *(const bf8*)&Bh[nf * 16 + lr][lk * 8];
            blf[nf] = *(const bf8*)&Bl[nf * 16 + lr][lk * 8];
        }
#pragma unroll
        for (int mf = 0; mf < 2; ++mf) {
            bf8 ah = *(const bf8*)&Ah[w * 32 + mf * 16 + lr][lk * 8];
            bf8 al = *(const bf8*)&Al[w * 32 + mf * 16 + lr][lk * 8];
#pragma unroll
            for (int nf = 0; nf < 4; ++nf) {
                acc[mf][nf] = MFMA(ah, bhf[nf], acc[mf][nf]);
                acc[mf][nf] = MFMA(ah, blf[nf], acc[mf][nf]);
                acc[mf][nf] = MFMA(al, bhf[nf], acc[mf][nf]);
            }
        }
    }

#pragma unroll
    for (int mf = 0; mf < 2; ++mf) {
#pragma unroll
        for (int nf = 0; nf < 4; ++nf) {
            int n = n0 + nf * 16 + lr;
            int mbase = m0 + w * 32 + mf * 16 + lk * 4;
            if (EPI == 0) {
#pragma unroll
                for (int r = 0; r < 4; ++r)
                    outf[(size_t)(mbase + r) * ldo + n] = acc[mf][nf][r];
            } else if (EPI == 1) {
                float bv = bias[n];
#pragma unroll
                for (int r = 0; r < 4; ++r) {
                    float y = fmaxf(acc[mf][nf][r] + bv, 0.f);
                    short hv = f2bf(y);
                    size_t oi = (size_t)(mbase + r) * ldh + n;
                    ohi[oi] = hv;
                    olo[oi] = f2bf(y - bf2f(hv));
                }
            } else if (EPI == 2) {
#pragma unroll
                for (int r = 0; r < 4; ++r) {
                    float y = acc[mf][nf][r];
                    short hv = f2bf(y);
                    size_t oi = (size_t)(mbase + r) * ldh + n;
                    ohi[oi] = hv;
                    olo[oi] = f2bf(y - bf2f(hv));
                }
            } else {
                float bv = bias[n];
#pragma unroll
                for (int r = 0; r < 4; ++r) {
                    float y = acc[mf][nf][r] + bv;
                    outf[(size_t)(mbase + r) * ldo + n] = y;
                    short hv = f2bf(y);
                    size_t oi = (size_t)(mbase + r) * ldh + n;
                    ohi[oi] = hv;
                    olo[oi] = f2bf(y - bf2f(hv));
                }
            }
        }
    }
}

// ---------------------------------------------------------------------------
// MFMA flash attention (validated round 3). qkvh/l: [4096][768] bf16 hi/lo.
__global__ __launch_bounds__(256) void k_attn(const short* __restrict__ qh,
                                              const short* __restrict__ ql,
                                              const float* __restrict__ bb,
                                              short* __restrict__ ohi,
                                              short* __restrict__ olo) {
    int bx = blockIdx.x;
    int qt = bx & 3, head = (bx >> 2) & 15, n = bx >> 6;
    int t = threadIdx.x;
    int w = t >> 6, l = t & 63;
    int lq = l & 15, lk = l >> 4;

    __shared__ __align__(16) short khl[512][40];
    __shared__ __align__(16) short vth[16][536];
    __shared__ __align__(16) short vtl[16][536];
    __shared__ float biasr[64];

    if (t < NBINSc) biasr[t] = bb[head * NBINSc + t];

    size_t base = (size_t)n * Lc * 768 + head * 16;
    for (int u = t; u < 2048; u += 256) {
        int key = u >> 2, seg = u & 3;
        const short* src = (seg < 2 ? qh : ql) + base + 256 + (size_t)key * 768 + (seg & 1) * 8;
        *(bf8*)&khl[key][seg * 8] = *(const bf8*)src;
    }
    for (int u = t; u < 1024; u += 256) {
        int key = u >> 1, half = u & 1;
        bf8 v8h = *(const bf8*)(qh + base + 512 + (size_t)key * 768 + half * 8);
        bf8 v8l = *(const bf8*)(ql + base + 512 + (size_t)key * 768 + half * 8);
#pragma unroll
        for (int i = 0; i < 8; ++i) {
            vth[half * 8 + i][key] = v8h[i];
            vtl[half * 8 + i][key] = v8l[i];
        }
    }
    __syncthreads();

    for (int qi = 0; qi < 2; ++qi) {
        int qg = qt * 128 + w * 32 + qi * 16 + lq;
        size_t qrow = ((size_t)n * Lc + qg) * 768 + head * 16;
        bf8 B1 = *(const bf8*)(qh + qrow + (lk & 1) * 8);
        bf8 B2;
        if (lk < 2) B2 = *(const bf8*)(ql + qrow + lk * 8);
        else {
#pragma unroll
            for (int i = 0; i < 8; ++i) B2[i] = 0;
        }

        f4 acc = (f4){0.f, 0.f, 0.f, 0.f};
        float m = -1e30f, lsum = 0.f;

        for (int kt = 0; kt < 32; ++kt) {
            bf8 A1 = *(const bf8*)&khl[kt * 16 + lq][lk * 8];
            f4 s = (f4){0.f, 0.f, 0.f, 0.f};
            s = MFMA(A1, B1, s);
            s = MFMA(A1, B2, s);
            int kb = kt * 16 + lk * 4;
#pragma unroll
            for (int r = 0; r < 4; ++r) {
                int rel = kb + r - qg;
                rel = rel < -PMAXLc ? -PMAXLc : (rel > PMAXLc ? PMAXLc : rel);
                s[r] += biasr[rel + PMAXLc];
            }
            float mt = fmaxf(fmaxf(s[0], s[1]), fmaxf(s[2], s[3]));
            mt = fmaxf(mt, __shfl_xor(mt, 16));
            mt = fmaxf(mt, __shfl_xor(mt, 32));
            float mn = fmaxf(m, mt);
            float alpha = __expf(m - mn);
            m = mn;
            f4 p;
#pragma unroll
            for (int r = 0; r < 4; ++r) p[r] = __expf(s[r] - mn);
            lsum = lsum * alpha + (p[0] + p[1] + p[2] + p[3]);
#pragma unroll
            for (int r = 0; r < 4; ++r) acc[r] *= __shfl(alpha, lk * 4 + r);
            int src0 = (lk & 1) * 32 + lq;
            int src1 = src0 + 16;
            float g[8];
#pragma unroll
            for (int j = 0; j < 4; ++j) {
                g[j]     = __shfl(p[j], src0);
                g[j + 4] = __shfl(p[j], src1);
            }
            bf8 PA;
#pragma unroll
            for (int j = 0; j < 8; ++j) {
                short hv = f2bf(g[j]);
                PA[j] = (lk < 2) ? hv : f2bf(g[j] - bf2f(hv));
            }
            bf8 VB1 = *(const bf8*)&vth[lq][kt * 16 + (lk & 1) * 8];
            bf8 VB2;
            if (lk < 2) VB2 = *(const bf8*)&vtl[lq][kt * 16 + lk * 8];
            else {
#pragma unroll
                for (int i = 0; i < 8; ++i) VB2[i] = 0;
            }
            acc = MFMA(PA, VB1, acc);
            acc = MFMA(PA, VB2, acc);
        }

        float lr = lsum + __shfl_xor(lsum, 16);
        lr += __shfl_xor(lr, 32);
        float inv = 1.0f / lr;
#pragma unroll
        for (int r = 0; r < 4; ++r) {
            float iq = __shfl(inv, lk * 4 + r);
            float y = acc[r] * iq;
            int qo = qt * 128 + w * 32 + qi * 16 + lk * 4 + r;
            size_t oi = ((size_t)n * Lc + qo) * DMc + head * 16 + lq;
            short hv = f2bf(y);
            ohi[oi] = hv;
            olo[oi] = f2bf(y - bf2f(hv));
        }
    }
}

// ---------------------------------------------------------------------------
__global__ __launch_bounds__(256) void k_ln(const float* __restrict__ s2,
                                            const float* __restrict__ sbias,
                                            const float* __restrict__ g,
                                            const float* __restrict__ bta,
                                            float* __restrict__ h,
                                            short* __restrict__ umhi,
                                            short* __restrict__ umlo) {
    int tile = blockIdx.x;
    int t = threadIdx.x;
    int tok = t >> 4, j = t & 15;
    size_t gtok = (size_t)tile * 16 + tok;
    float sum = 0.f, ssq = 0.f;
    float vals[16];
#pragma unroll
    for (int d0 = 0; d0 < 16; ++d0) {
        int d = j + d0 * 16;
        float vv = h[gtok * EMBEDc + d] + s2[gtok * EMBEDc + d] + sbias[d];
        vals[d0] = vv;
        sum += vv;
        ssq += vv * vv;
    }
#pragma unroll
    for (int off = 8; off; off >>= 1) {
        sum += __shfl_xor(sum, off, 16);
        ssq += __shfl_xor(ssq, off, 16);
    }
    float mean = sum * (1.f / EMBEDc);
    float var = ssq * (1.f / EMBEDc) - mean * mean;
    float inv = rsqrtf(var + 1e-5f);
#pragma unroll
    for (int d0 = 0; d0 < 16; ++d0) {
        int d = j + d0 * 16;
        float y = (vals[d0] - mean) * inv * g[d] + bta[d];
        h[gtok * EMBEDc + d] = y;
        short hv = f2bf(y);
        umhi[gtok * UMDIM + d] = hv;
        umlo[gtok * UMDIM + d] = f2bf(y - bf2f(hv));
    }
}

// ---------------------------------------------------------------------------
// r = f @ o_w2^T + o_b2  (N=3). f: bf16 hi/lo [4096][256]. 64 tokens/block.
__global__ __launch_bounds__(256) void k_r(const short* __restrict__ fh,
                                           const short* __restrict__ fl,
                                           const float* __restrict__ w2,
                                           const float* __restrict__ b2,
                                           float* __restrict__ r) {
    __shared__ float w[3][EMBEDc];
    int t = threadIdx.x;
    for (int u = t; u < 3 * EMBEDc; u += 256) w[u >> 8][u & 255] = w2[u];
    __syncthreads();
    int tok = blockIdx.x * 64 + (t >> 2), o = t & 3;
    if (o < 3) {
        const short* ph = fh + (size_t)tok * EMBEDc;
        const short* pl = fl + (size_t)tok * EMBEDc;
        float s = b2[o];
        for (int c8 = 0; c8 < EMBEDc / 8; ++c8) {
            bf8 vh = *(const bf8*)(ph + c8 * 8);
            bf8 vl = *(const bf8*)(pl + c8 * 8);
#pragma unroll
            for (int j = 0; j < 8; ++j)
                s += (bf2f(vh[j]) + bf2f(vl[j])) * w[o][c8 * 8 + j];
        }
        r[(size_t)tok * 3 + o] = s;
    }
}

// ---------------------------------------------------------------------------
__global__ __launch_bounds__(256) void k_dmap(const float* __restrict__ r,
                                              float* __restrict__ d) {
    int b = blockIdx.x;
    int n = b / Lc;
    float xi = r[(size_t)b * 3], yi = r[(size_t)b * 3 + 1], zi = r[(size_t)b * 3 + 2];
    const float* rn = r + (size_t)n * Lc * 3;
    for (int j = threadIdx.x; j < Lc; j += 256) {
        float dx = xi - rn[j * 3];
        float dy = yi - rn[j * 3 + 1];
        float dz = zi - rn[j * 3 + 2];
        d[(size_t)b * Lc + j] = sqrtf(dx * dx + dy * dy + dz * dz + 1e-12f);
    }
}

// ---------------------------------------------------------------------------
extern "C" void kernel_launch(void* const* d_in, const int* in_sizes, int n_in,
                              void* d_out, int out_size, void* d_ws, size_t ws_size,
                              hipStream_t stream) {
    const float* z       = (const float*)d_in[0];
    const float* x       = (const float*)d_in[1];
    const float* pos_emb = (const float*)d_in[2];
    const float* aa_emb  = (const float*)d_in[3];
    const float* ex_w1   = (const float*)d_in[4];
    const float* ex_b1   = (const float*)d_in[5];
    const float* ex_w2   = (const float*)d_in[6];
    const float* ex_b2   = (const float*)d_in[7];
    const float* Wq      = (const float*)d_in[8];
    const float* Wk      = (const float*)d_in[9];
    const float* Wv      = (const float*)d_in[10];
    const float* Wo      = (const float*)d_in[11];
    const float* bo      = (const float*)d_in[12];
    const float* W2d     = (const float*)d_in[13];
    const float* b2d     = (const float*)d_in[14];
    const float* Wf1     = (const float*)d_in[15];
    const float* bf1     = (const float*)d_in[16];
    const float* Wf2     = (const float*)d_in[17];
    const float* bf2     = (const float*)d_in[18];
    const float* ln1_g   = (const float*)d_in[19];
    const float* ln1_b   = (const float*)d_in[20];
    const float* ln2_g   = (const float*)d_in[21];
    const float* ln2_b   = (const float*)d_in[22];
    const float* o_w1    = (const float*)d_in[23];
    const float* o_b1    = (const float*)d_in[24];
    const float* o_w2    = (const float*)d_in[25];
    const float* o_b2    = (const float*)d_in[26];

    float* h    = (float*)d_ws;                    // 4096*256
    float* s2   = h + (size_t)NTOK * EMBEDc;
    float* bbuf = s2 + (size_t)NTOK * EMBEDc;      // pad 8192
    float* r    = bbuf + 8192;                     // pad 16384
    short* qkvh = (short*)(r + 16384);             // 4096*768
    short* qkvl = qkvh + (size_t)NTOK * 768;
    short* um_hi = qkvl + (size_t)NTOK * 768;      // 4096*288
    short* um_lo = um_hi + (size_t)NTOK * UMDIM;
    short* o_hi  = um_lo + (size_t)NTOK * UMDIM;   // 4096*256
    short* o_lo  = o_hi + (size_t)NTOK * EMBEDc;
    short* f1_hi = o_lo + (size_t)NTOK * EMBEDc;   // 4096*1024
    short* f1_lo = f1_hi + (size_t)NTOK * DFFc;
    short* wqkv_hi = f1_lo + (size_t)NTOK * DFFc;  // 6*768*256
    short* wqkv_lo = wqkv_hi + (size_t)NLc * 768 * EMBEDc;
    short* wo_hi   = wqkv_lo + (size_t)NLc * 768 * EMBEDc;   // 6*256*256
    short* wo_lo   = wo_hi + (size_t)NLc * EMBEDc * DMc;
    short* wf1_hi  = wo_lo + (size_t)NLc * EMBEDc * DMc;     // 6*1024*288
    short* wf1_lo  = wf1_hi + (size_t)NLc * DFFc * UMDIM;
    short* wf2_hi  = wf1_lo + (size_t)NLc * DFFc * UMDIM;    // 6*256*1024
    short* wf2_lo  = wf2_hi + (size_t)NLc * EMBEDc * DFFc;
    short* wex1_hi = wf2_lo + (size_t)NLc * EMBEDc * DFFc;   // 256*64
    short* wex1_lo = wex1_hi + EMBEDc * NZc;
    short* wex2_hi = wex1_lo + EMBEDc * NZc;                 // 256*256
    short* wex2_lo = wex2_hi + EMBEDc * EMBEDc;
    short* wo1_hi  = wex2_lo + EMBEDc * EMBEDc;              // 256*256
    short* wo1_lo  = wo1_hi + EMBEDc * EMBEDc;
    // zt aliases the o buffer (only used in preamble, before k_attn writes o)
    short* zt_hi = o_hi;
    short* zt_lo = o_lo;

    k_cvt<<<512, 256, 0, stream>>>(Wq, wqkv_hi, wqkv_lo, DMc * EMBEDc, 768 * EMBEDc, 0, 0.0625f, NLc * DMc * EMBEDc);
    k_cvt<<<512, 256, 0, stream>>>(Wk, wqkv_hi, wqkv_lo, DMc * EMBEDc, 768 * EMBEDc, EMBEDc * EMBEDc, 1.f, NLc * DMc * EMBEDc);
    k_cvt<<<512, 256, 0, stream>>>(Wv, wqkv_hi, wqkv_lo, DMc * EMBEDc, 768 * EMBEDc, 2 * EMBEDc * EMBEDc, 1.f, NLc * DMc * EMBEDc);
    k_cvt<<<512, 256, 0, stream>>>(Wo, wo_hi, wo_lo, EMBEDc * DMc, EMBEDc * DMc, 0, 1.f, NLc * EMBEDc * DMc);
    k_cvt<<<512, 256, 0, stream>>>(Wf1, wf1_hi, wf1_lo, DFFc * UMDIM, DFFc * UMDIM, 0, 1.f, NLc * DFFc * UMDIM);
    k_cvt<<<512, 256, 0, stream>>>(Wf2, wf2_hi, wf2_lo, EMBEDc * DFFc, EMBEDc * DFFc, 0, 1.f, NLc * EMBEDc * DFFc);
    k_cvt<<<64, 256, 0, stream>>>(ex_w1, wex1_hi, wex1_lo, EMBEDc * NZc, EMBEDc * NZc, 0, 1.f, EMBEDc * NZc);
    k_cvt<<<256, 256, 0, stream>>>(ex_w2, wex2_hi, wex2_lo, EMBEDc * EMBEDc, EMBEDc * EMBEDc, 0, 1.f, EMBEDc * EMBEDc);
    k_cvt<<<256, 256, 0, stream>>>(o_w1, wo1_hi, wo1_lo, EMBEDc * EMBEDc, EMBEDc * EMBEDc, 0, 1.f, EMBEDc * EMBEDc);

    k_biasbins<<<(NLc * NHc * NBINSc + 255) / 256, 256, 0, stream>>>(pos_emb, W2d, b2d, bbuf);
    k_eaa<<<NTOK / 256, 256, 0, stream>>>(x, aa_emb, um_hi, um_lo);

    // embed: zt -> relu GEMM -> GEMM (fp32 h + bf16 um)
    k_zt<<<NTOK / 256, 256, 0, stream>>>(z, zt_hi, zt_lo);
    k_gemm2<1><<<dim3(4, 32), 256, 0, stream>>>(
        zt_hi, zt_lo, NZc, wex1_hi, wex1_lo, NZc, NZc,
        nullptr, 0, f1_hi, f1_lo, EMBEDc, ex_b1);
    k_gemm2<3><<<dim3(4, 32), 256, 0, stream>>>(
        f1_hi, f1_lo, EMBEDc, wex2_hi, wex2_lo, EMBEDc, EMBEDc,
        h, EMBEDc, um_hi, um_lo, UMDIM, ex_b2);

    for (int l = 0; l < NLc; ++l) {
        k_gemm2<2><<<dim3(12, 32), 256, 0, stream>>>(
            um_hi, um_lo, UMDIM,
            wqkv_hi + (size_t)l * 768 * EMBEDc, wqkv_lo + (size_t)l * 768 * EMBEDc, EMBEDc,
            EMBEDc, nullptr, 0, qkvh, qkvl, 768, nullptr);
        k_attn<<<NB * NHc * 4, 256, 0, stream>>>(qkvh, qkvl, bbuf + (size_t)l * NHc * NBINSc, o_hi, o_lo);
        k_gemm2<0><<<dim3(4, 32), 256, 0, stream>>>(
            o_hi, o_lo, EMBEDc,
            wo_hi + (size_t)l * EMBEDc * DMc, wo_lo + (size_t)l * EMBEDc * DMc, DMc,
            DMc, s2, EMBEDc, nullptr, nullptr, 0, nullptr);
        k_ln<<<NTOK / 16, 256, 0, stream>>>(s2, bo + (size_t)l * EMBEDc,
                                            ln1_g + (size_t)l * EMBEDc, ln1_b + (size_t)l * EMBEDc,
                                            h, um_hi, um_lo);
        k_gemm2<1><<<dim3(16, 32), 256, 0, stream>>>(
            um_hi, um_lo, UMDIM,
            wf1_hi + (size_t)l * DFFc * UMDIM, wf1_lo + (size_t)l * DFFc * UMDIM, UMDIM,
            UMDIM, nullptr, 0, f1_hi, f1_lo, DFFc, bf1 + (size_t)l * DFFc);
        k_gemm2<0><<<dim3(4, 32), 256, 0, stream>>>(
            f1_hi, f1_lo, DFFc,
            wf2_hi + (size_t)l * EMBEDc * DFFc, wf2_lo + (size_t)l * EMBEDc * DFFc, DFFc,
            DFFc, s2, EMBEDc, nullptr, nullptr, 0, nullptr);
        k_ln<<<NTOK / 16, 256, 0, stream>>>(s2, bf2 + (size_t)l * EMBEDc,
                                            ln2_g + (size_t)l * EMBEDc, ln2_b + (size_t)l * EMBEDc,
                                            h, um_hi, um_lo);
    }

    // final: f = relu(um @ o_w1^T + o_b1) (um cols 0..255 hold h in bf16)
    k_gemm2<1><<<dim3(4, 32), 256, 0, stream>>>(
        um_hi, um_lo, UMDIM, wo1_hi, wo1_lo, EMBEDc, EMBEDc,
        nullptr, 0, f1_hi, f1_lo, EMBEDc, o_b1);
    k_r<<<NTOK / 64, 256, 0, stream>>>(f1_hi, f1_lo, o_w2, o_b2, r);
    k_dmap<<<NB * Lc, 256, 0, stream>>>(r, (float*)d_out);
}

// Round 6
// 835.408 us; speedup vs baseline: 6.6083x; 1.0542x over previous
//
#include <hip/hip_runtime.h>
#include <math.h>

#define NZc     64
#define EMBEDc  256
#define DMc     256
#define NHc     16
#define HDc     16
#define DFFc    1024
#define NLc     6
#define E1Dc    32
#define PDIMc   64
#define PMAXLc  24
#define NBINSc  49
#define NB      8
#define Lc      512
#define NTOK    (NB * Lc)        // 4096
#define UMDIM   (EMBEDc + E1Dc)  // 288

typedef __attribute__((ext_vector_type(4))) float f4;
typedef __attribute__((ext_vector_type(8))) short bf8;   // 8 bf16 in 4 VGPRs

#define MFMA(a, b, c) __builtin_amdgcn_mfma_f32_16x16x32_bf16((a), (b), (c), 0, 0, 0)

__device__ __forceinline__ short f2bf(float f) {
    unsigned u = __float_as_uint(f);
    u += 0x7FFFu + ((u >> 16) & 1u);   // round-to-nearest-even
    return (short)(u >> 16);
}
__device__ __forceinline__ float bf2f(short s) {
    return __uint_as_float(((unsigned)(unsigned short)s) << 16);
}

// ---------------------------------------------------------------------------
// weight conversion: fp32 -> bf16 hi/lo with per-layer dest strides
__global__ void k_cvt(const float* __restrict__ src, short* __restrict__ hi,
                      short* __restrict__ lo, int per_layer, int dst_stride,
                      int dst_off, float scale, int total) {
    for (int i = blockIdx.x * blockDim.x + threadIdx.x; i < total;
         i += gridDim.x * blockDim.x) {
        int l = i / per_layer, rels = i - l * per_layer;
        size_t di = (size_t)l * dst_stride + dst_off + rels;
        float v = src[i] * scale;
        short h = f2bf(v);
        hi[di] = h;
        lo[di] = f2bf(v - bf2f(h));
    }
}

// ---------------------------------------------------------------------------
__global__ void k_biasbins(const float* __restrict__ pos_emb,
                           const float* __restrict__ W2d,
                           const float* __restrict__ b2d,
                           float* __restrict__ bb) {
    int idx = blockIdx.x * blockDim.x + threadIdx.x;
    if (idx >= NLc * NHc * NBINSc) return;
    int bin = idx % NBINSc;
    int tmp = idx / NBINSc;
    int hh = tmp % NHc;
    int l  = tmp / NHc;
    float s = b2d[l * NHc + hh];
    const float* pe = pos_emb + bin * PDIMc;
    const float* w  = W2d + (l * NHc + hh) * PDIMc;
    for (int p = 0; p < PDIMc; ++p) s += pe[p] * w[p];
    bb[idx] = s;
}

// ---------------------------------------------------------------------------
__global__ void k_eaa(const float* __restrict__ x,
                      const float* __restrict__ aa_emb,
                      short* __restrict__ umhi, short* __restrict__ umlo) {
    int tok = blockIdx.x * blockDim.x + threadIdx.x;
    if (tok >= NTOK) return;
    int n = tok / Lc, l = tok % Lc;
    const float* xp = x + (size_t)n * 20 * Lc + l;
    float best = xp[0];
    int bi = 0;
    for (int c = 1; c < 20; ++c) {
        float v = xp[c * Lc];
        if (v > best) { best = v; bi = c; }
    }
    const float* e = aa_emb + bi * E1Dc;
    for (int c = 0; c < E1Dc; ++c) {
        float v = e[c];
        short h = f2bf(v);
        umhi[(size_t)tok * UMDIM + EMBEDc + c] = h;
        umlo[(size_t)tok * UMDIM + EMBEDc + c] = f2bf(v - bf2f(h));
    }
}

// ---------------------------------------------------------------------------
// transpose z (N,NZ,L) -> zt (tok, NZ) bf16 hi/lo. reads coalesced over l.
__global__ __launch_bounds__(256) void k_zt(const float* __restrict__ z,
                                            short* __restrict__ zth,
                                            short* __restrict__ ztl) {
    int tok = blockIdx.x * blockDim.x + threadIdx.x;
    int n = tok >> 9, l = tok & 511;
    for (int c = 0; c < NZc; ++c) {
        float v = z[((size_t)n * NZc + c) * Lc + l];
        short hv = f2bf(v);
        zth[(size_t)tok * NZc + c] = hv;
        ztl[(size_t)tok * NZc + c] = f2bf(v - bf2f(hv));
    }
}

// ---------------------------------------------------------------------------
// LDS-staged MFMA GEMM: C[M x N] = A @ W^T, 3-term compensated bf16.
// Tile 128M x 64N, BK=32, 256 thr (4 waves). (validated round 5)
template <int EPI>
__global__ __launch_bounds__(256) void k_gemm2(
    const short* __restrict__ Ahi, const short* __restrict__ Alo, int lda,
    const short* __restrict__ Bhi, const short* __restrict__ Blo, int ldb,
    int K, float* __restrict__ outf, int ldo, short* __restrict__ ohi,
    short* __restrict__ olo, int ldh, const float* __restrict__ bias) {
    __shared__ __align__(16) short Ah[128][32];
    __shared__ __align__(16) short Al[128][32];
    __shared__ __align__(16) short Bh[64][32];
    __shared__ __align__(16) short Bl[64][32];

    int t = threadIdx.x;
    int w = t >> 6, l = t & 63, lr = l & 15, lk = l >> 4;
    int m0 = blockIdx.y * 128;
    int n0 = blockIdx.x * 64;

    int srow = t >> 2, scol = (t & 3) * 8;
    const short* gah0 = Ahi + (size_t)(m0 + srow) * lda + scol;
    const short* gah1 = Ahi + (size_t)(m0 + 64 + srow) * lda + scol;
    const short* gal0 = Alo + (size_t)(m0 + srow) * lda + scol;
    const short* gal1 = Alo + (size_t)(m0 + 64 + srow) * lda + scol;
    const short* gbh  = Bhi + (size_t)(n0 + srow) * ldb + scol;
    const short* gbl  = Blo + (size_t)(n0 + srow) * ldb + scol;

    bf8 ra0 = *(const bf8*)gah0;
    bf8 ra1 = *(const bf8*)gah1;
    bf8 rla0 = *(const bf8*)gal0;
    bf8 rla1 = *(const bf8*)gal1;
    bf8 rb = *(const bf8*)gbh;
    bf8 rlb = *(const bf8*)gbl;

    f4 acc[2][4];
#pragma unroll
    for (int mf = 0; mf < 2; ++mf)
#pragma unroll
        for (int nf = 0; nf < 4; ++nf) acc[mf][nf] = (f4){0.f, 0.f, 0.f, 0.f};

    for (int ks = 0; ks < K; ks += 32) {
        __syncthreads();
        *(bf8*)&Ah[srow][scol] = ra0;
        *(bf8*)&Ah[64 + srow][scol] = ra1;
        *(bf8*)&Al[srow][scol] = rla0;
        *(bf8*)&Al[64 + srow][scol] = rla1;
        *(bf8*)&Bh[srow][scol] = rb;
        *(bf8*)&Bl[srow][scol] = rlb;
        __syncthreads();
        if (ks + 32 < K) {
            ra0 = *(const bf8*)(gah0 + ks + 32);
            ra1 = *(const bf8*)(gah1 + ks + 32);
            rla0 = *(const bf8*)(gal0 + ks + 32);
            rla1 = *(const bf8*)(gal1 + ks + 32);
            rb = *(const bf8*)(gbh + ks + 32);
            rlb = *(const bf8*)(gbl + ks + 32);
        }
        bf8 bhf[4], blf[4];
#pragma unroll
        for (int nf = 0; nf < 4; ++nf) {
            bhf[nf] = *(const bf8*)&Bh[nf * 16 + lr][lk * 8];
            blf[nf] = *(const bf8*)&Bl[nf * 16 + lr][lk * 8];
        }
#pragma unroll
        for (int mf = 0; mf < 2; ++mf) {
            bf8 ah = *(const bf8*)&Ah[w * 32 + mf * 16 + lr][lk * 8];
            bf8 al = *(const bf8*)&Al[w * 32 + mf * 16 + lr][lk * 8];
#pragma unroll
            for (int nf = 0; nf < 4; ++nf) {
                acc[mf][nf] = MFMA(ah, bhf[nf], acc[mf][nf]);
                acc[mf][nf] = MFMA(ah, blf[nf], acc[mf][nf]);
                acc[mf][nf] = MFMA(al, bhf[nf], acc[mf][nf]);
            }
        }
    }

#pragma unroll
    for (int mf = 0; mf < 2; ++mf) {
#pragma unroll
        for (int nf = 0; nf < 4; ++nf) {
            int n = n0 + nf * 16 + lr;
            int mbase = m0 + w * 32 + mf * 16 + lk * 4;
            if (EPI == 0) {
#pragma unroll
                for (int r = 0; r < 4; ++r)
                    outf[(size_t)(mbase + r) * ldo + n] = acc[mf][nf][r];
            } else if (EPI == 1) {
                float bv = bias[n];
#pragma unroll
                for (int r = 0; r < 4; ++r) {
                    float y = fmaxf(acc[mf][nf][r] + bv, 0.f);
                    short hv = f2bf(y);
                    size_t oi = (size_t)(mbase + r) * ldh + n;
                    ohi[oi] = hv;
                    olo[oi] = f2bf(y - bf2f(hv));
                }
            } else if (EPI == 2) {
#pragma unroll
                for (int r = 0; r < 4; ++r) {
                    float y = acc[mf][nf][r];
                    short hv = f2bf(y);
                    size_t oi = (size_t)(mbase + r) * ldh + n;
                    ohi[oi] = hv;
                    olo[oi] = f2bf(y - bf2f(hv));
                }
            } else {
                float bv = bias[n];
#pragma unroll
                for (int r = 0; r < 4; ++r) {
                    float y = acc[mf][nf][r] + bv;
                    outf[(size_t)(mbase + r) * ldo + n] = y;
                    short hv = f2bf(y);
                    size_t oi = (size_t)(mbase + r) * ldh + n;
                    ohi[oi] = hv;
                    olo[oi] = f2bf(y - bf2f(hv));
                }
            }
        }
    }
}

// ---------------------------------------------------------------------------
// MFMA flash attention. qt-slow block order (XCD K/V reuse); bias fast-path;
// defer-max (THR=8); trunc-split P; pair-packed V staging; setprio on MFMA.
__global__ __launch_bounds__(256) void k_attn(const short* __restrict__ qh,
                                              const short* __restrict__ ql,
                                              const float* __restrict__ bb,
                                              short* __restrict__ ohi,
                                              short* __restrict__ olo) {
    int bx = blockIdx.x;
    int qt = bx >> 7;            // slow: blocks sharing (n,head) are 128 apart
    int head = bx & 15;
    int n = (bx >> 4) & 7;
    int t = threadIdx.x;
    int w = t >> 6, l = t & 63;
    int lq = l & 15, lk = l >> 4;

    __shared__ __align__(16) short khl[512][40];   // [key][hi0-15|lo16-31|pad]
    __shared__ __align__(16) short vth[16][536];   // V^T hi: [d][key]
    __shared__ __align__(16) short vtl[16][536];   // V^T lo
    __shared__ float biasr[64];

    if (t < NBINSc) biasr[t] = bb[head * NBINSc + t];
    float bL = bb[head * NBINSc];              // bias at rel = -24 (clamped low)
    float bR = bb[head * NBINSc + 48];         // bias at rel = +24 (clamped high)

    size_t base = (size_t)n * Lc * 768 + head * 16;
    // stage K (hi+lo packed per row)
    for (int u = t; u < 2048; u += 256) {
        int key = u >> 2, seg = u & 3;
        const short* src = (seg < 2 ? qh : ql) + base + 256 + (size_t)key * 768 + (seg & 1) * 8;
        *(bf8*)&khl[key][seg * 8] = *(const bf8*)src;
    }
    // stage V transposed, pair-packed b32 writes (conflict-free)
    {
        int u = t;                       // pair index 0..255 -> keys 2u, 2u+1
        const short* vsh = qh + base + 512 + (size_t)(u * 2) * 768;
        const short* vsl = ql + base + 512 + (size_t)(u * 2) * 768;
        bf8 h0  = *(const bf8*)vsh;
        bf8 h0b = *(const bf8*)(vsh + 8);
        bf8 h1  = *(const bf8*)(vsh + 768);
        bf8 h1b = *(const bf8*)(vsh + 768 + 8);
        bf8 l0  = *(const bf8*)vsl;
        bf8 l0b = *(const bf8*)(vsl + 8);
        bf8 l1  = *(const bf8*)(vsl + 768);
        bf8 l1b = *(const bf8*)(vsl + 768 + 8);
        unsigned* vthw = (unsigned*)&vth[0][0];   // row stride 268 words
        unsigned* vtlw = (unsigned*)&vtl[0][0];
#pragma unroll
        for (int i = 0; i < 8; ++i) {
            vthw[i * 268 + u]       = (unsigned)(unsigned short)h0[i]  | ((unsigned)(unsigned short)h1[i] << 16);
            vthw[(8 + i) * 268 + u] = (unsigned)(unsigned short)h0b[i] | ((unsigned)(unsigned short)h1b[i] << 16);
            vtlw[i * 268 + u]       = (unsigned)(unsigned short)l0[i]  | ((unsigned)(unsigned short)l1[i] << 16);
            vtlw[(8 + i) * 268 + u] = (unsigned)(unsigned short)l0b[i] | ((unsigned)(unsigned short)l1b[i] << 16);
        }
    }
    __syncthreads();

    for (int qi = 0; qi < 2; ++qi) {
        int qg = qt * 128 + w * 32 + qi * 16 + lq;   // this lane's q column
        size_t qrow = ((size_t)n * Lc + qg) * 768 + head * 16;
        bf8 B1 = *(const bf8*)(qh + qrow + (lk & 1) * 8);   // [Qh|Qh]
        bf8 B2;
        if (lk < 2) B2 = *(const bf8*)(ql + qrow + lk * 8);  // [Ql|0]
        else {
#pragma unroll
            for (int i = 0; i < 8; ++i) B2[i] = 0;
        }

        f4 acc = (f4){0.f, 0.f, 0.f, 0.f};
        float m = -1e30f, lsum = 0.f;
        int rel0 = lk * 4 - qg;      // rel of s[0] at kt=0; += 16 per tile

        for (int kt = 0; kt < 32; ++kt, rel0 += 16) {
            bf8 A1 = *(const bf8*)&khl[kt * 16 + lq][lk * 8];  // [Kh|Kl]
            f4 s = (f4){0.f, 0.f, 0.f, 0.f};
            __builtin_amdgcn_s_setprio(1);
            s = MFMA(A1, B1, s);      // KhQh + KlQh
            s = MFMA(A1, B2, s);      // KhQl
            __builtin_amdgcn_s_setprio(0);
            // bias: fast path outside the +/-24 window
            if (rel0 >= PMAXLc) {
                s[0] += bR; s[1] += bR; s[2] += bR; s[3] += bR;
            } else if (rel0 + 3 <= -PMAXLc) {
                s[0] += bL; s[1] += bL; s[2] += bL; s[3] += bL;
            } else {
#pragma unroll
                for (int r = 0; r < 4; ++r) {
                    int rel = rel0 + r;
                    rel = rel < -PMAXLc ? -PMAXLc : (rel > PMAXLc ? PMAXLc : rel);
                    s[r] += biasr[rel + PMAXLc];
                }
            }
            float mt = fmaxf(fmaxf(s[0], s[1]), fmaxf(s[2], s[3]));
            mt = fmaxf(mt, __shfl_xor(mt, 16));
            mt = fmaxf(mt, __shfl_xor(mt, 32));
            // defer-max: rescale only when the running max grows materially
            if (__any(mt > m + 8.0f)) {
                float mn = fmaxf(m, mt);
                float alpha = __expf(m - mn);
                m = mn;
                lsum *= alpha;
#pragma unroll
                for (int r = 0; r < 4; ++r) acc[r] *= __shfl(alpha, lk * 4 + r);
            }
            f4 p;
#pragma unroll
            for (int r = 0; r < 4; ++r) p[r] = __expf(s[r] - m);
            lsum += p[0] + p[1] + p[2] + p[3];
            // gather this lane's 8 P values (keys (lk&1)*8 .. +8 of row lq)
            int src0 = (lk & 1) * 32 + lq;
            int src1 = src0 + 16;
            float g[8];
#pragma unroll
            for (int j = 0; j < 4; ++j) {
                g[j]     = __shfl(p[j], src0);
                g[j + 4] = __shfl(p[j], src1);
            }
            // trunc-split: hi = top16 bits (lanes 0-31), lo = bf16(residual)
            bf8 PA;
            if (lk < 2) {
#pragma unroll
                for (int j = 0; j < 8; ++j)
                    PA[j] = (short)(__float_as_uint(g[j]) >> 16);
            } else {
#pragma unroll
                for (int j = 0; j < 8; ++j) {
                    unsigned hu = __float_as_uint(g[j]) & 0xFFFF0000u;
                    float res = g[j] - __uint_as_float(hu);
                    PA[j] = (short)(__float_as_uint(res) >> 16);
                }
            }
            bf8 VB1 = *(const bf8*)&vth[lq][kt * 16 + (lk & 1) * 8];  // [Vh|Vh]
            bf8 VB2;
            if (lk < 2) VB2 = *(const bf8*)&vtl[lq][kt * 16 + lk * 8];  // [Vl|0]
            else {
#pragma unroll
                for (int i = 0; i < 8; ++i) VB2[i] = 0;
            }
            __builtin_amdgcn_s_setprio(1);
            acc = MFMA(PA, VB1, acc);   // PhVh + PlVh
            acc = MFMA(PA, VB2, acc);   // PhVl
            __builtin_amdgcn_s_setprio(0);
        }

        float lred = lsum + __shfl_xor(lsum, 16);
        lred += __shfl_xor(lred, 32);
        float inv = 1.0f / lred;
#pragma unroll
        for (int r = 0; r < 4; ++r) {
            float iq = __shfl(inv, lk * 4 + r);
            float y = acc[r] * iq;
            int qo = qt * 128 + w * 32 + qi * 16 + lk * 4 + r;
            size_t oi = ((size_t)n * Lc + qo) * DMc + head * 16 + lq;
            unsigned hu = __float_as_uint(y) & 0xFFFF0000u;
            ohi[oi] = (short)(hu >> 16);
            float res = y - __uint_as_float(hu);
            olo[oi] = (short)(__float_as_uint(res) >> 16);
        }
    }
}

// ---------------------------------------------------------------------------
__global__ __launch_bounds__(256) void k_ln(const float* __restrict__ s2,
                                            const float* __restrict__ sbias,
                                            const float* __restrict__ g,
                                            const float* __restrict__ bta,
                                            float* __restrict__ h,
                                            short* __restrict__ umhi,
                                            short* __restrict__ umlo) {
    int tile = blockIdx.x;
    int t = threadIdx.x;
    int tok = t >> 4, j = t & 15;
    size_t gtok = (size_t)tile * 16 + tok;
    float sum = 0.f, ssq = 0.f;
    float vals[16];
#pragma unroll
    for (int d0 = 0; d0 < 16; ++d0) {
        int d = j + d0 * 16;
        float vv = h[gtok * EMBEDc + d] + s2[gtok * EMBEDc + d] + sbias[d];
        vals[d0] = vv;
        sum += vv;
        ssq += vv * vv;
    }
#pragma unroll
    for (int off = 8; off; off >>= 1) {
        sum += __shfl_xor(sum, off, 16);
        ssq += __shfl_xor(ssq, off, 16);
    }
    float mean = sum * (1.f / EMBEDc);
    float var = ssq * (1.f / EMBEDc) - mean * mean;
    float inv = rsqrtf(var + 1e-5f);
#pragma unroll
    for (int d0 = 0; d0 < 16; ++d0) {
        int d = j + d0 * 16;
        float y = (vals[d0] - mean) * inv * g[d] + bta[d];
        h[gtok * EMBEDc + d] = y;
        short hv = f2bf(y);
        umhi[gtok * UMDIM + d] = hv;
        umlo[gtok * UMDIM + d] = f2bf(y - bf2f(hv));
    }
}

// ---------------------------------------------------------------------------
// r = f @ o_w2^T + o_b2  (N=3). f: bf16 hi/lo [4096][256]. 64 tokens/block.
__global__ __launch_bounds__(256) void k_r(const short* __restrict__ fh,
                                           const short* __restrict__ fl,
                                           const float* __restrict__ w2,
                                           const float* __restrict__ b2,
                                           float* __restrict__ r) {
    __shared__ float w[3][EMBEDc];
    int t = threadIdx.x;
    for (int u = t; u < 3 * EMBEDc; u += 256) w[u >> 8][u & 255] = w2[u];
    __syncthreads();
    int tok = blockIdx.x * 64 + (t >> 2), o = t & 3;
    if (o < 3) {
        const short* ph = fh + (size_t)tok * EMBEDc;
        const short* pl = fl + (size_t)tok * EMBEDc;
        float s = b2[o];
        for (int c8 = 0; c8 < EMBEDc / 8; ++c8) {
            bf8 vh = *(const bf8*)(ph + c8 * 8);
            bf8 vl = *(const bf8*)(pl + c8 * 8);
#pragma unroll
            for (int j = 0; j < 8; ++j)
                s += (bf2f(vh[j]) + bf2f(vl[j])) * w[o][c8 * 8 + j];
        }
        r[(size_t)tok * 3 + o] = s;
    }
}

// ---------------------------------------------------------------------------
__global__ __launch_bounds__(256) void k_dmap(const float* __restrict__ r,
                                              float* __restrict__ d) {
    int b = blockIdx.x;
    int n = b / Lc;
    float xi = r[(size_t)b * 3], yi = r[(size_t)b * 3 + 1], zi = r[(size_t)b * 3 + 2];
    const float* rn = r + (size_t)n * Lc * 3;
    for (int j = threadIdx.x; j < Lc; j += 256) {
        float dx = xi - rn[j * 3];
        float dy = yi - rn[j * 3 + 1];
        float dz = zi - rn[j * 3 + 2];
        d[(size_t)b * Lc + j] = sqrtf(dx * dx + dy * dy + dz * dz + 1e-12f);
    }
}

// ---------------------------------------------------------------------------
extern "C" void kernel_launch(void* const* d_in, const int* in_sizes, int n_in,
                              void* d_out, int out_size, void* d_ws, size_t ws_size,
                              hipStream_t stream) {
    const float* z       = (const float*)d_in[0];
    const float* x       = (const float*)d_in[1];
    const float* pos_emb = (const float*)d_in[2];
    const float* aa_emb  = (const float*)d_in[3];
    const float* ex_w1   = (const float*)d_in[4];
    const float* ex_b1   = (const float*)d_in[5];
    const float* ex_w2   = (const float*)d_in[6];
    const float* ex_b2   = (const float*)d_in[7];
    const float* Wq      = (const float*)d_in[8];
    const float* Wk      = (const float*)d_in[9];
    const float* Wv      = (const float*)d_in[10];
    const float* Wo      = (const float*)d_in[11];
    const float* bo      = (const float*)d_in[12];
    const float* W2d     = (const float*)d_in[13];
    const float* b2d     = (const float*)d_in[14];
    const float* Wf1     = (const float*)d_in[15];
    const float* bf1     = (const float*)d_in[16];
    const float* Wf2     = (const float*)d_in[17];
    const float* bf2     = (const float*)d_in[18];
    const float* ln1_g   = (const float*)d_in[19];
    const float* ln1_b   = (const float*)d_in[20];
    const float* ln2_g   = (const float*)d_in[21];
    const float* ln2_b   = (const float*)d_in[22];
    const float* o_w1    = (const float*)d_in[23];
    const float* o_b1    = (const float*)d_in[24];
    const float* o_w2    = (const float*)d_in[25];
    const float* o_b2    = (const float*)d_in[26];

    float* h    = (float*)d_ws;                    // 4096*256
    float* s2   = h + (size_t)NTOK * EMBEDc;
    float* bbuf = s2 + (size_t)NTOK * EMBEDc;      // pad 8192
    float* r    = bbuf + 8192;                     // pad 16384
    short* qkvh = (short*)(r + 16384);             // 4096*768
    short* qkvl = qkvh + (size_t)NTOK * 768;
    short* um_hi = qkvl + (size_t)NTOK * 768;      // 4096*288
    short* um_lo = um_hi + (size_t)NTOK * UMDIM;
    short* o_hi  = um_lo + (size_t)NTOK * UMDIM;   // 4096*256
    short* o_lo  = o_hi + (size_t)NTOK * EMBEDc;
    short* f1_hi = o_lo + (size_t)NTOK * EMBEDc;   // 4096*1024
    short* f1_lo = f1_hi + (size_t)NTOK * DFFc;
    short* wqkv_hi = f1_lo + (size_t)NTOK * DFFc;  // 6*768*256
    short* wqkv_lo = wqkv_hi + (size_t)NLc * 768 * EMBEDc;
    short* wo_hi   = wqkv_lo + (size_t)NLc * 768 * EMBEDc;   // 6*256*256
    short* wo_lo   = wo_hi + (size_t)NLc * EMBEDc * DMc;
    short* wf1_hi  = wo_lo + (size_t)NLc * EMBEDc * DMc;     // 6*1024*288
    short* wf1_lo  = wf1_hi + (size_t)NLc * DFFc * UMDIM;
    short* wf2_hi  = wf1_lo + (size_t)NLc * DFFc * UMDIM;    // 6*256*1024
    short* wf2_lo  = wf2_hi + (size_t)NLc * EMBEDc * DFFc;
    short* wex1_hi = wf2_lo + (size_t)NLc * EMBEDc * DFFc;   // 256*64
    short* wex1_lo = wex1_hi + EMBEDc * NZc;
    short* wex2_hi = wex1_lo + EMBEDc * NZc;                 // 256*256
    short* wex2_lo = wex2_hi + EMBEDc * EMBEDc;
    short* wo1_hi  = wex2_lo + EMBEDc * EMBEDc;              // 256*256
    short* wo1_lo  = wo1_hi + EMBEDc * EMBEDc;
    // zt aliases the o buffer (only used in preamble, before k_attn writes o)
    short* zt_hi = o_hi;
    short* zt_lo = o_lo;

    k_cvt<<<512, 256, 0, stream>>>(Wq, wqkv_hi, wqkv_lo, DMc * EMBEDc, 768 * EMBEDc, 0, 0.0625f, NLc * DMc * EMBEDc);
    k_cvt<<<512, 256, 0, stream>>>(Wk, wqkv_hi, wqkv_lo, DMc * EMBEDc, 768 * EMBEDc, EMBEDc * EMBEDc, 1.f, NLc * DMc * EMBEDc);
    k_cvt<<<512, 256, 0, stream>>>(Wv, wqkv_hi, wqkv_lo, DMc * EMBEDc, 768 * EMBEDc, 2 * EMBEDc * EMBEDc, 1.f, NLc * DMc * EMBEDc);
    k_cvt<<<512, 256, 0, stream>>>(Wo, wo_hi, wo_lo, EMBEDc * DMc, EMBEDc * DMc, 0, 1.f, NLc * EMBEDc * DMc);
    k_cvt<<<512, 256, 0, stream>>>(Wf1, wf1_hi, wf1_lo, DFFc * UMDIM, DFFc * UMDIM, 0, 1.f, NLc * DFFc * UMDIM);
    k_cvt<<<512, 256, 0, stream>>>(Wf2, wf2_hi, wf2_lo, EMBEDc * DFFc, EMBEDc * DFFc, 0, 1.f, NLc * EMBEDc * DFFc);
    k_cvt<<<64, 256, 0, stream>>>(ex_w1, wex1_hi, wex1_lo, EMBEDc * NZc, EMBEDc * NZc, 0, 1.f, EMBEDc * NZc);
    k_cvt<<<256, 256, 0, stream>>>(ex_w2, wex2_hi, wex2_lo, EMBEDc * EMBEDc, EMBEDc * EMBEDc, 0, 1.f, EMBEDc * EMBEDc);
    k_cvt<<<256, 256, 0, stream>>>(o_w1, wo1_hi, wo1_lo, EMBEDc * EMBEDc, EMBEDc * EMBEDc, 0, 1.f, EMBEDc * EMBEDc);

    k_biasbins<<<(NLc * NHc * NBINSc + 255) / 256, 256, 0, stream>>>(pos_emb, W2d, b2d, bbuf);
    k_eaa<<<NTOK / 256, 256, 0, stream>>>(x, aa_emb, um_hi, um_lo);

    // embed: zt -> relu GEMM -> GEMM (fp32 h + bf16 um)
    k_zt<<<NTOK / 256, 256, 0, stream>>>(z, zt_hi, zt_lo);
    k_gemm2<1><<<dim3(4, 32), 256, 0, stream>>>(
        zt_hi, zt_lo, NZc, wex1_hi, wex1_lo, NZc, NZc,
        nullptr, 0, f1_hi, f1_lo, EMBEDc, ex_b1);
    k_gemm2<3><<<dim3(4, 32), 256, 0, stream>>>(
        f1_hi, f1_lo, EMBEDc, wex2_hi, wex2_lo, EMBEDc, EMBEDc,
        h, EMBEDc, um_hi, um_lo, UMDIM, ex_b2);

    for (int l = 0; l < NLc; ++l) {
        k_gemm2<2><<<dim3(12, 32), 256, 0, stream>>>(
            um_hi, um_lo, UMDIM,
            wqkv_hi + (size_t)l * 768 * EMBEDc, wqkv_lo + (size_t)l * 768 * EMBEDc, EMBEDc,
            EMBEDc, nullptr, 0, qkvh, qkvl, 768, nullptr);
        k_attn<<<NB * NHc * 4, 256, 0, stream>>>(qkvh, qkvl, bbuf + (size_t)l * NHc * NBINSc, o_hi, o_lo);
        k_gemm2<0><<<dim3(4, 32), 256, 0, stream>>>(
            o_hi, o_lo, EMBEDc,
            wo_hi + (size_t)l * EMBEDc * DMc, wo_lo + (size_t)l * EMBEDc * DMc, DMc,
            DMc, s2, EMBEDc, nullptr, nullptr, 0, nullptr);
        k_ln<<<NTOK / 16, 256, 0, stream>>>(s2, bo + (size_t)l * EMBEDc,
                                            ln1_g + (size_t)l * EMBEDc, ln1_b + (size_t)l * EMBEDc,
                                            h, um_hi, um_lo);
        k_gemm2<1><<<dim3(16, 32), 256, 0, stream>>>(
            um_hi, um_lo, UMDIM,
            wf1_hi + (size_t)l * DFFc * UMDIM, wf1_lo + (size_t)l * DFFc * UMDIM, UMDIM,
            UMDIM, nullptr, 0, f1_hi, f1_lo, DFFc, bf1 + (size_t)l * DFFc);
        k_gemm2<0><<<dim3(4, 32), 256, 0, stream>>>(
            f1_hi, f1_lo, DFFc,
            wf2_hi + (size_t)l * EMBEDc * DFFc, wf2_lo + (size_t)l * EMBEDc * DFFc, DFFc,
            DFFc, s2, EMBEDc, nullptr, nullptr, 0, nullptr);
        k_ln<<<NTOK / 16, 256, 0, stream>>>(s2, bf2 + (size_t)l * EMBEDc,
                                            ln2_g + (size_t)l * EMBEDc, ln2_b + (size_t)l * EMBEDc,
                                            h, um_hi, um_lo);
    }

    // final: f = relu(um @ o_w1^T + o_b1) (um cols 0..255 hold h in bf16)
    k_gemm2<1><<<dim3(4, 32), 256, 0, stream>>>(
        um_hi, um_lo, UMDIM, wo1_hi, wo1_lo, EMBEDc, EMBEDc,
        nullptr, 0, f1_hi, f1_lo, EMBEDc, o_b1);
    k_r<<<NTOK / 64, 256, 0, stream>>>(f1_hi, f1_lo, o_w2, o_b2, r);
    k_dmap<<<NB * Lc, 256, 0, stream>>>(r, (float*)d_out);
}

// Round 7
// 761.895 us; speedup vs baseline: 7.2459x; 1.0965x over previous
//
#include <hip/hip_runtime.h>
#include <math.h>

#define NZc     64
#define EMBEDc  256
#define DMc     256
#define NHc     16
#define HDc     16
#define DFFc    1024
#define NLc     6
#define E1Dc    32
#define PDIMc   64
#define PMAXLc  24
#define NBINSc  49
#define NB      8
#define Lc      512
#define NTOK    (NB * Lc)        // 4096
#define UMDIM   (EMBEDc + E1Dc)  // 288

typedef __attribute__((ext_vector_type(4))) float f4;
typedef __attribute__((ext_vector_type(8))) short bf8;   // 8 bf16 in 4 VGPRs

#define MFMA(a, b, c) __builtin_amdgcn_mfma_f32_16x16x32_bf16((a), (b), (c), 0, 0, 0)

__device__ __forceinline__ short f2bf(float f) {
    unsigned u = __float_as_uint(f);
    u += 0x7FFFu + ((u >> 16) & 1u);   // round-to-nearest-even
    return (short)(u >> 16);
}
__device__ __forceinline__ float bf2f(short s) {
    return __uint_as_float(((unsigned)(unsigned short)s) << 16);
}

// ---------------------------------------------------------------------------
// all weight conversions fused into one kernel (was 9 launches)
__global__ void k_cvt_all(const float* __restrict__ Wq, const float* __restrict__ Wk,
                          const float* __restrict__ Wv, const float* __restrict__ Wo,
                          const float* __restrict__ Wf1, const float* __restrict__ Wf2,
                          const float* __restrict__ exw1, const float* __restrict__ exw2,
                          const float* __restrict__ ow1,
                          short* __restrict__ wqkv_hi, short* __restrict__ wqkv_lo,
                          short* __restrict__ wo_hi, short* __restrict__ wo_lo,
                          short* __restrict__ wf1_hi, short* __restrict__ wf1_lo,
                          short* __restrict__ wf2_hi, short* __restrict__ wf2_lo,
                          short* __restrict__ wex1_hi, short* __restrict__ wex1_lo,
                          short* __restrict__ wex2_hi, short* __restrict__ wex2_lo,
                          short* __restrict__ wo1_hi, short* __restrict__ wo1_lo) {
    int stride = gridDim.x * blockDim.x;
    int tid = blockIdx.x * blockDim.x + threadIdx.x;
#define CVT(src, hi, lo, per_layer, dstride, doff, scale, total)               \
    for (int i = tid; i < (total); i += stride) {                              \
        int ll = i / (per_layer), rels = i - ll * (per_layer);                 \
        size_t di = (size_t)ll * (dstride) + (doff) + rels;                    \
        float v = src[i] * (scale);                                            \
        short hh = f2bf(v);                                                    \
        hi[di] = hh;                                                           \
        lo[di] = f2bf(v - bf2f(hh));                                           \
    }
    CVT(Wq,  wqkv_hi, wqkv_lo, 65536, 196608, 0,      0.0625f, 393216);
    CVT(Wk,  wqkv_hi, wqkv_lo, 65536, 196608, 65536,  1.f,     393216);
    CVT(Wv,  wqkv_hi, wqkv_lo, 65536, 196608, 131072, 1.f,     393216);
    CVT(Wo,  wo_hi,  wo_lo,  65536,  65536,  0, 1.f, 393216);
    CVT(Wf1, wf1_hi, wf1_lo, 294912, 294912, 0, 1.f, 1769472);
    CVT(Wf2, wf2_hi, wf2_lo, 262144, 262144, 0, 1.f, 1572864);
    CVT(exw1, wex1_hi, wex1_lo, 16384, 16384, 0, 1.f, 16384);
    CVT(exw2, wex2_hi, wex2_lo, 65536, 65536, 0, 1.f, 65536);
    CVT(ow1,  wo1_hi,  wo1_lo,  65536, 65536, 0, 1.f, 65536);
#undef CVT
}

// ---------------------------------------------------------------------------
__global__ void k_biasbins(const float* __restrict__ pos_emb,
                           const float* __restrict__ W2d,
                           const float* __restrict__ b2d,
                           float* __restrict__ bb) {
    int idx = blockIdx.x * blockDim.x + threadIdx.x;
    if (idx >= NLc * NHc * NBINSc) return;
    int bin = idx % NBINSc;
    int tmp = idx / NBINSc;
    int hh = tmp % NHc;
    int l  = tmp / NHc;
    float s = b2d[l * NHc + hh];
    const float* pe = pos_emb + bin * PDIMc;
    const float* w  = W2d + (l * NHc + hh) * PDIMc;
    for (int p = 0; p < PDIMc; ++p) s += pe[p] * w[p];
    bb[idx] = s;
}

// ---------------------------------------------------------------------------
__global__ void k_eaa(const float* __restrict__ x,
                      const float* __restrict__ aa_emb,
                      short* __restrict__ umhi, short* __restrict__ umlo) {
    int tok = blockIdx.x * blockDim.x + threadIdx.x;
    if (tok >= NTOK) return;
    int n = tok / Lc, l = tok % Lc;
    const float* xp = x + (size_t)n * 20 * Lc + l;
    float best = xp[0];
    int bi = 0;
    for (int c = 1; c < 20; ++c) {
        float v = xp[c * Lc];
        if (v > best) { best = v; bi = c; }
    }
    const float* e = aa_emb + bi * E1Dc;
    for (int c = 0; c < E1Dc; ++c) {
        float v = e[c];
        short h = f2bf(v);
        umhi[(size_t)tok * UMDIM + EMBEDc + c] = h;
        umlo[(size_t)tok * UMDIM + EMBEDc + c] = f2bf(v - bf2f(h));
    }
}

// ---------------------------------------------------------------------------
__global__ __launch_bounds__(256) void k_zt(const float* __restrict__ z,
                                            short* __restrict__ zth,
                                            short* __restrict__ ztl) {
    int tok = blockIdx.x * blockDim.x + threadIdx.x;
    int n = tok >> 9, l = tok & 511;
    for (int c = 0; c < NZc; ++c) {
        float v = z[((size_t)n * NZc + c) * Lc + l];
        short hv = f2bf(v);
        zth[(size_t)tok * NZc + c] = hv;
        ztl[(size_t)tok * NZc + c] = f2bf(v - bf2f(hv));
    }
}

// ---------------------------------------------------------------------------
// LDS-staged MFMA GEMM, XCD-swizzled 1D grid (T1). gy is always 32 M-tiles:
// xcd = bid&7 owns M-tiles [xcd*4, xcd*4+4) and iterates N-tiles within, so
// A-tiles + full B panel stay L2-resident per XCD.
template <int EPI>
__global__ __launch_bounds__(256) void k_gemm2(
    const short* __restrict__ Ahi, const short* __restrict__ Alo, int lda,
    const short* __restrict__ Bhi, const short* __restrict__ Blo, int ldb,
    int K, float* __restrict__ outf, int ldo, short* __restrict__ ohi,
    short* __restrict__ olo, int ldh, const float* __restrict__ bias, int gx) {
    __shared__ __align__(16) short Ah[128][32];
    __shared__ __align__(16) short Al[128][32];
    __shared__ __align__(16) short Bh[64][32];
    __shared__ __align__(16) short Bl[64][32];

    int bid = blockIdx.x;
    int xcd = bid & 7, j = bid >> 3;
    int bx = j % gx, by = (xcd << 2) + j / gx;

    int t = threadIdx.x;
    int w = t >> 6, l = t & 63, lr = l & 15, lk = l >> 4;
    int m0 = by * 128;
    int n0 = bx * 64;

    int srow = t >> 2, scol = (t & 3) * 8;
    const short* gah0 = Ahi + (size_t)(m0 + srow) * lda + scol;
    const short* gah1 = Ahi + (size_t)(m0 + 64 + srow) * lda + scol;
    const short* gal0 = Alo + (size_t)(m0 + srow) * lda + scol;
    const short* gal1 = Alo + (size_t)(m0 + 64 + srow) * lda + scol;
    const short* gbh  = Bhi + (size_t)(n0 + srow) * ldb + scol;
    const short* gbl  = Blo + (size_t)(n0 + srow) * ldb + scol;

    bf8 ra0 = *(const bf8*)gah0;
    bf8 ra1 = *(const bf8*)gah1;
    bf8 rla0 = *(const bf8*)gal0;
    bf8 rla1 = *(const bf8*)gal1;
    bf8 rb = *(const bf8*)gbh;
    bf8 rlb = *(const bf8*)gbl;

    f4 acc[2][4];
#pragma unroll
    for (int mf = 0; mf < 2; ++mf)
#pragma unroll
        for (int nf = 0; nf < 4; ++nf) acc[mf][nf] = (f4){0.f, 0.f, 0.f, 0.f};

    for (int ks = 0; ks < K; ks += 32) {
        __syncthreads();
        *(bf8*)&Ah[srow][scol] = ra0;
        *(bf8*)&Ah[64 + srow][scol] = ra1;
        *(bf8*)&Al[srow][scol] = rla0;
        *(bf8*)&Al[64 + srow][scol] = rla1;
        *(bf8*)&Bh[srow][scol] = rb;
        *(bf8*)&Bl[srow][scol] = rlb;
        __syncthreads();
        if (ks + 32 < K) {
            ra0 = *(const bf8*)(gah0 + ks + 32);
            ra1 = *(const bf8*)(gah1 + ks + 32);
            rla0 = *(const bf8*)(gal0 + ks + 32);
            rla1 = *(const bf8*)(gal1 + ks + 32);
            rb = *(const bf8*)(gbh + ks + 32);
            rlb = *(const bf8*)(gbl + ks + 32);
        }
        bf8 bhf[4], blf[4];
#pragma unroll
        for (int nf = 0; nf < 4; ++nf) {
            bhf[nf] = *(const bf8*)&Bh[nf * 16 + lr][lk * 8];
            blf[nf] = *(const bf8*)&Bl[nf * 16 + lr][lk * 8];
        }
#pragma unroll
        for (int mf = 0; mf < 2; ++mf) {
            bf8 ah = *(const bf8*)&Ah[w * 32 + mf * 16 + lr][lk * 8];
            bf8 al = *(const bf8*)&Al[w * 32 + mf * 16 + lr][lk * 8];
#pragma unroll
            for (int nf = 0; nf < 4; ++nf) {
                acc[mf][nf] = MFMA(ah, bhf[nf], acc[mf][nf]);
                acc[mf][nf] = MFMA(ah, blf[nf], acc[mf][nf]);
                acc[mf][nf] = MFMA(al, bhf[nf], acc[mf][nf]);
            }
        }
    }

#pragma unroll
    for (int mf = 0; mf < 2; ++mf) {
#pragma unroll
        for (int nf = 0; nf < 4; ++nf) {
            int n = n0 + nf * 16 + lr;
            int mbase = m0 + w * 32 + mf * 16 + lk * 4;
            if (EPI == 0) {
#pragma unroll
                for (int r = 0; r < 4; ++r)
                    outf[(size_t)(mbase + r) * ldo + n] = acc[mf][nf][r];
            } else if (EPI == 1) {
                float bv = bias[n];
#pragma unroll
                for (int r = 0; r < 4; ++r) {
                    float y = fmaxf(acc[mf][nf][r] + bv, 0.f);
                    short hv = f2bf(y);
                    size_t oi = (size_t)(mbase + r) * ldh + n;
                    ohi[oi] = hv;
                    olo[oi] = f2bf(y - bf2f(hv));
                }
            } else if (EPI == 2) {
#pragma unroll
                for (int r = 0; r < 4; ++r) {
                    float y = acc[mf][nf][r];
                    short hv = f2bf(y);
                    size_t oi = (size_t)(mbase + r) * ldh + n;
                    ohi[oi] = hv;
                    olo[oi] = f2bf(y - bf2f(hv));
                }
            } else {
                float bv = bias[n];
#pragma unroll
                for (int r = 0; r < 4; ++r) {
                    float y = acc[mf][nf][r] + bv;
                    outf[(size_t)(mbase + r) * ldo + n] = y;
                    short hv = f2bf(y);
                    size_t oi = (size_t)(mbase + r) * ldh + n;
                    ohi[oi] = hv;
                    olo[oi] = f2bf(y - bf2f(hv));
                }
            }
        }
    }
}

// ---------------------------------------------------------------------------
// MFMA flash attention, merged q-tiles: both 16-row q-tiles of a wave share
// each K/V LDS read (halves ds_read traffic) and run as independent chains
// (2x ILP). Joint defer-max branch; bias fast-path; trunc-split P.
__global__ __launch_bounds__(256) void k_attn(const short* __restrict__ qh,
                                              const short* __restrict__ ql,
                                              const float* __restrict__ bb,
                                              short* __restrict__ ohi,
                                              short* __restrict__ olo) {
    int bx = blockIdx.x;
    int qt = bx >> 7;            // slow: blocks sharing (n,head) are 128 apart
    int head = bx & 15;
    int n = (bx >> 4) & 7;
    int t = threadIdx.x;
    int w = t >> 6, l = t & 63;
    int lq = l & 15, lk = l >> 4;

    __shared__ __align__(16) short khl[512][40];   // [key][hi0-15|lo16-31|pad]
    __shared__ __align__(16) short vth[16][536];   // V^T hi: [d][key]
    __shared__ __align__(16) short vtl[16][536];   // V^T lo
    __shared__ float biasr[64];

    if (t < NBINSc) biasr[t] = bb[head * NBINSc + t];
    float bL = bb[head * NBINSc];
    float bR = bb[head * NBINSc + 48];

    size_t base = (size_t)n * Lc * 768 + head * 16;
    for (int u = t; u < 2048; u += 256) {
        int key = u >> 2, seg = u & 3;
        const short* src = (seg < 2 ? qh : ql) + base + 256 + (size_t)key * 768 + (seg & 1) * 8;
        *(bf8*)&khl[key][seg * 8] = *(const bf8*)src;
    }
    {
        int u = t;                       // pair index -> keys 2u, 2u+1
        const short* vsh = qh + base + 512 + (size_t)(u * 2) * 768;
        const short* vsl = ql + base + 512 + (size_t)(u * 2) * 768;
        bf8 h0  = *(const bf8*)vsh;
        bf8 h0b = *(const bf8*)(vsh + 8);
        bf8 h1  = *(const bf8*)(vsh + 768);
        bf8 h1b = *(const bf8*)(vsh + 768 + 8);
        bf8 l0  = *(const bf8*)vsl;
        bf8 l0b = *(const bf8*)(vsl + 8);
        bf8 l1  = *(const bf8*)(vsl + 768);
        bf8 l1b = *(const bf8*)(vsl + 768 + 8);
        unsigned* vthw = (unsigned*)&vth[0][0];   // row stride 268 words
        unsigned* vtlw = (unsigned*)&vtl[0][0];
#pragma unroll
        for (int i = 0; i < 8; ++i) {
            vthw[i * 268 + u]       = (unsigned)(unsigned short)h0[i]  | ((unsigned)(unsigned short)h1[i] << 16);
            vthw[(8 + i) * 268 + u] = (unsigned)(unsigned short)h0b[i] | ((unsigned)(unsigned short)h1b[i] << 16);
            vtlw[i * 268 + u]       = (unsigned)(unsigned short)l0[i]  | ((unsigned)(unsigned short)l1[i] << 16);
            vtlw[(8 + i) * 268 + u] = (unsigned)(unsigned short)l0b[i] | ((unsigned)(unsigned short)l1b[i] << 16);
        }
    }
    __syncthreads();

    int qg = qt * 128 + w * 32 + lq;             // q-tile 0 row; tile 1 = +16
    size_t qrow = ((size_t)n * Lc + qg) * 768 + head * 16;
    bf8 B1a = *(const bf8*)(qh + qrow + (lk & 1) * 8);
    bf8 B1b = *(const bf8*)(qh + qrow + 16 * 768 + (lk & 1) * 8);
    bf8 B2a, B2b;
    if (lk < 2) {
        B2a = *(const bf8*)(ql + qrow + lk * 8);
        B2b = *(const bf8*)(ql + qrow + 16 * 768 + lk * 8);
    } else {
#pragma unroll
        for (int i = 0; i < 8; ++i) { B2a[i] = 0; B2b[i] = 0; }
    }

    f4 acc0 = (f4){0.f, 0.f, 0.f, 0.f};
    f4 acc1 = (f4){0.f, 0.f, 0.f, 0.f};
    float m0 = -1e30f, m1 = -1e30f, ls0 = 0.f, ls1 = 0.f;
    int rel0 = lk * 4 - qg;      // rel of s0[0] at kt=0; s1 uses rel0-16

    for (int kt = 0; kt < 32; ++kt, rel0 += 16) {
        bf8 A1 = *(const bf8*)&khl[kt * 16 + lq][lk * 8];
        f4 s0 = (f4){0.f, 0.f, 0.f, 0.f};
        f4 s1 = (f4){0.f, 0.f, 0.f, 0.f};
        __builtin_amdgcn_s_setprio(1);
        s0 = MFMA(A1, B1a, s0);
        s0 = MFMA(A1, B2a, s0);
        s1 = MFMA(A1, B1b, s1);
        s1 = MFMA(A1, B2b, s1);
        __builtin_amdgcn_s_setprio(0);
        // bias qtile0
        if (rel0 >= PMAXLc) {
            s0[0] += bR; s0[1] += bR; s0[2] += bR; s0[3] += bR;
        } else if (rel0 + 3 <= -PMAXLc) {
            s0[0] += bL; s0[1] += bL; s0[2] += bL; s0[3] += bL;
        } else {
#pragma unroll
            for (int r = 0; r < 4; ++r) {
                int rel = rel0 + r;
                rel = rel < -PMAXLc ? -PMAXLc : (rel > PMAXLc ? PMAXLc : rel);
                s0[r] += biasr[rel + PMAXLc];
            }
        }
        // bias qtile1 (rel shifted by -16)
        int rel1 = rel0 - 16;
        if (rel1 >= PMAXLc) {
            s1[0] += bR; s1[1] += bR; s1[2] += bR; s1[3] += bR;
        } else if (rel1 + 3 <= -PMAXLc) {
            s1[0] += bL; s1[1] += bL; s1[2] += bL; s1[3] += bL;
        } else {
#pragma unroll
            for (int r = 0; r < 4; ++r) {
                int rel = rel1 + r;
                rel = rel < -PMAXLc ? -PMAXLc : (rel > PMAXLc ? PMAXLc : rel);
                s1[r] += biasr[rel + PMAXLc];
            }
        }
        float mt0 = fmaxf(fmaxf(s0[0], s0[1]), fmaxf(s0[2], s0[3]));
        float mt1 = fmaxf(fmaxf(s1[0], s1[1]), fmaxf(s1[2], s1[3]));
        mt0 = fmaxf(mt0, __shfl_xor(mt0, 16));
        mt0 = fmaxf(mt0, __shfl_xor(mt0, 32));
        mt1 = fmaxf(mt1, __shfl_xor(mt1, 16));
        mt1 = fmaxf(mt1, __shfl_xor(mt1, 32));
        if (__any((mt0 > m0 + 8.0f) || (mt1 > m1 + 8.0f))) {
            float mn0 = fmaxf(m0, mt0), a0 = __expf(m0 - mn0);
            float mn1 = fmaxf(m1, mt1), a1 = __expf(m1 - mn1);
            m0 = mn0; m1 = mn1;
            ls0 *= a0; ls1 *= a1;
#pragma unroll
            for (int r = 0; r < 4; ++r) {
                acc0[r] *= __shfl(a0, lk * 4 + r);
                acc1[r] *= __shfl(a1, lk * 4 + r);
            }
        }
        f4 p0, p1;
#pragma unroll
        for (int r = 0; r < 4; ++r) { p0[r] = __expf(s0[r] - m0); p1[r] = __expf(s1[r] - m1); }
        ls0 += p0[0] + p0[1] + p0[2] + p0[3];
        ls1 += p1[0] + p1[1] + p1[2] + p1[3];
        int src0 = (lk & 1) * 32 + lq;
        int src1 = src0 + 16;
        float g0[8], g1[8];
#pragma unroll
        for (int jj = 0; jj < 4; ++jj) {
            g0[jj]     = __shfl(p0[jj], src0);
            g0[jj + 4] = __shfl(p0[jj], src1);
            g1[jj]     = __shfl(p1[jj], src0);
            g1[jj + 4] = __shfl(p1[jj], src1);
        }
        bf8 PA0, PA1;
        if (lk < 2) {
#pragma unroll
            for (int jj = 0; jj < 8; ++jj) {
                PA0[jj] = (short)(__float_as_uint(g0[jj]) >> 16);
                PA1[jj] = (short)(__float_as_uint(g1[jj]) >> 16);
            }
        } else {
#pragma unroll
            for (int jj = 0; jj < 8; ++jj) {
                unsigned hu0 = __float_as_uint(g0[jj]) & 0xFFFF0000u;
                unsigned hu1 = __float_as_uint(g1[jj]) & 0xFFFF0000u;
                PA0[jj] = (short)(__float_as_uint(g0[jj] - __uint_as_float(hu0)) >> 16);
                PA1[jj] = (short)(__float_as_uint(g1[jj] - __uint_as_float(hu1)) >> 16);
            }
        }
        bf8 VB1 = *(const bf8*)&vth[lq][kt * 16 + (lk & 1) * 8];
        bf8 VB2;
        if (lk < 2) VB2 = *(const bf8*)&vtl[lq][kt * 16 + lk * 8];
        else {
#pragma unroll
            for (int i = 0; i < 8; ++i) VB2[i] = 0;
        }
        __builtin_amdgcn_s_setprio(1);
        acc0 = MFMA(PA0, VB1, acc0);
        acc0 = MFMA(PA0, VB2, acc0);
        acc1 = MFMA(PA1, VB1, acc1);
        acc1 = MFMA(PA1, VB2, acc1);
        __builtin_amdgcn_s_setprio(0);
    }

    float lr0 = ls0 + __shfl_xor(ls0, 16);
    lr0 += __shfl_xor(lr0, 32);
    float lr1 = ls1 + __shfl_xor(ls1, 16);
    lr1 += __shfl_xor(lr1, 32);
    float inv0 = 1.0f / lr0;
    float inv1 = 1.0f / lr1;
#pragma unroll
    for (int r = 0; r < 4; ++r) {
        float iq0 = __shfl(inv0, lk * 4 + r);
        float iq1 = __shfl(inv1, lk * 4 + r);
        float y0 = acc0[r] * iq0;
        float y1 = acc1[r] * iq1;
        int qo = qt * 128 + w * 32 + lk * 4 + r;
        size_t oi0 = ((size_t)n * Lc + qo) * DMc + head * 16 + lq;
        size_t oi1 = oi0 + (size_t)16 * DMc;
        unsigned hu0 = __float_as_uint(y0) & 0xFFFF0000u;
        unsigned hu1 = __float_as_uint(y1) & 0xFFFF0000u;
        ohi[oi0] = (short)(hu0 >> 16);
        olo[oi0] = (short)(__float_as_uint(y0 - __uint_as_float(hu0)) >> 16);
        ohi[oi1] = (short)(hu1 >> 16);
        olo[oi1] = (short)(__float_as_uint(y1 - __uint_as_float(hu1)) >> 16);
    }
}

// ---------------------------------------------------------------------------
__global__ __launch_bounds__(256) void k_ln(const float* __restrict__ s2,
                                            const float* __restrict__ sbias,
                                            const float* __restrict__ g,
                                            const float* __restrict__ bta,
                                            float* __restrict__ h,
                                            short* __restrict__ umhi,
                                            short* __restrict__ umlo) {
    int tile = blockIdx.x;
    int t = threadIdx.x;
    int tok = t >> 4, j = t & 15;
    size_t gtok = (size_t)tile * 16 + tok;
    float sum = 0.f, ssq = 0.f;
    float vals[16];
#pragma unroll
    for (int d0 = 0; d0 < 16; ++d0) {
        int d = j + d0 * 16;
        float vv = h[gtok * EMBEDc + d] + s2[gtok * EMBEDc + d] + sbias[d];
        vals[d0] = vv;
        sum += vv;
        ssq += vv * vv;
    }
#pragma unroll
    for (int off = 8; off; off >>= 1) {
        sum += __shfl_xor(sum, off, 16);
        ssq += __shfl_xor(ssq, off, 16);
    }
    float mean = sum * (1.f / EMBEDc);
    float var = ssq * (1.f / EMBEDc) - mean * mean;
    float inv = rsqrtf(var + 1e-5f);
#pragma unroll
    for (int d0 = 0; d0 < 16; ++d0) {
        int d = j + d0 * 16;
        float y = (vals[d0] - mean) * inv * g[d] + bta[d];
        h[gtok * EMBEDc + d] = y;
        short hv = f2bf(y);
        umhi[gtok * UMDIM + d] = hv;
        umlo[gtok * UMDIM + d] = f2bf(y - bf2f(hv));
    }
}

// ---------------------------------------------------------------------------
__global__ __launch_bounds__(256) void k_r(const short* __restrict__ fh,
                                           const short* __restrict__ fl,
                                           const float* __restrict__ w2,
                                           const float* __restrict__ b2,
                                           float* __restrict__ r) {
    __shared__ float w[3][EMBEDc];
    int t = threadIdx.x;
    for (int u = t; u < 3 * EMBEDc; u += 256) w[u >> 8][u & 255] = w2[u];
    __syncthreads();
    int tok = blockIdx.x * 64 + (t >> 2), o = t & 3;
    if (o < 3) {
        const short* ph = fh + (size_t)tok * EMBEDc;
        const short* pl = fl + (size_t)tok * EMBEDc;
        float s = b2[o];
        for (int c8 = 0; c8 < EMBEDc / 8; ++c8) {
            bf8 vh = *(const bf8*)(ph + c8 * 8);
            bf8 vl = *(const bf8*)(pl + c8 * 8);
#pragma unroll
            for (int j = 0; j < 8; ++j)
                s += (bf2f(vh[j]) + bf2f(vl[j])) * w[o][c8 * 8 + j];
        }
        r[(size_t)tok * 3 + o] = s;
    }
}

// ---------------------------------------------------------------------------
__global__ __launch_bounds__(256) void k_dmap(const float* __restrict__ r,
                                              float* __restrict__ d) {
    int b = blockIdx.x;
    int n = b / Lc;
    float xi = r[(size_t)b * 3], yi = r[(size_t)b * 3 + 1], zi = r[(size_t)b * 3 + 2];
    const float* rn = r + (size_t)n * Lc * 3;
    for (int j = threadIdx.x; j < Lc; j += 256) {
        float dx = xi - rn[j * 3];
        float dy = yi - rn[j * 3 + 1];
        float dz = zi - rn[j * 3 + 2];
        d[(size_t)b * Lc + j] = sqrtf(dx * dx + dy * dy + dz * dz + 1e-12f);
    }
}

// ---------------------------------------------------------------------------
extern "C" void kernel_launch(void* const* d_in, const int* in_sizes, int n_in,
                              void* d_out, int out_size, void* d_ws, size_t ws_size,
                              hipStream_t stream) {
    const float* z       = (const float*)d_in[0];
    const float* x       = (const float*)d_in[1];
    const float* pos_emb = (const float*)d_in[2];
    const float* aa_emb  = (const float*)d_in[3];
    const float* ex_w1   = (const float*)d_in[4];
    const float* ex_b1   = (const float*)d_in[5];
    const float* ex_w2   = (const float*)d_in[6];
    const float* ex_b2   = (const float*)d_in[7];
    const float* Wq      = (const float*)d_in[8];
    const float* Wk      = (const float*)d_in[9];
    const float* Wv      = (const float*)d_in[10];
    const float* Wo      = (const float*)d_in[11];
    const float* bo      = (const float*)d_in[12];
    const float* W2d     = (const float*)d_in[13];
    const float* b2d     = (const float*)d_in[14];
    const float* Wf1     = (const float*)d_in[15];
    const float* bf1     = (const float*)d_in[16];
    const float* Wf2     = (const float*)d_in[17];
    const float* bf2     = (const float*)d_in[18];
    const float* ln1_g   = (const float*)d_in[19];
    const float* ln1_b   = (const float*)d_in[20];
    const float* ln2_g   = (const float*)d_in[21];
    const float* ln2_b   = (const float*)d_in[22];
    const float* o_w1    = (const float*)d_in[23];
    const float* o_b1    = (const float*)d_in[24];
    const float* o_w2    = (const float*)d_in[25];
    const float* o_b2    = (const float*)d_in[26];

    float* h    = (float*)d_ws;                    // 4096*256
    float* s2   = h + (size_t)NTOK * EMBEDc;
    float* bbuf = s2 + (size_t)NTOK * EMBEDc;      // pad 8192
    float* r    = bbuf + 8192;                     // pad 16384
    short* qkvh = (short*)(r + 16384);             // 4096*768
    short* qkvl = qkvh + (size_t)NTOK * 768;
    short* um_hi = qkvl + (size_t)NTOK * 768;      // 4096*288
    short* um_lo = um_hi + (size_t)NTOK * UMDIM;
    short* o_hi  = um_lo + (size_t)NTOK * UMDIM;   // 4096*256
    short* o_lo  = o_hi + (size_t)NTOK * EMBEDc;
    short* f1_hi = o_lo + (size_t)NTOK * EMBEDc;   // 4096*1024
    short* f1_lo = f1_hi + (size_t)NTOK * DFFc;
    short* wqkv_hi = f1_lo + (size_t)NTOK * DFFc;  // 6*768*256
    short* wqkv_lo = wqkv_hi + (size_t)NLc * 768 * EMBEDc;
    short* wo_hi   = wqkv_lo + (size_t)NLc * 768 * EMBEDc;   // 6*256*256
    short* wo_lo   = wo_hi + (size_t)NLc * EMBEDc * DMc;
    short* wf1_hi  = wo_lo + (size_t)NLc * EMBEDc * DMc;     // 6*1024*288
    short* wf1_lo  = wf1_hi + (size_t)NLc * DFFc * UMDIM;
    short* wf2_hi  = wf1_lo + (size_t)NLc * DFFc * UMDIM;    // 6*256*1024
    short* wf2_lo  = wf2_hi + (size_t)NLc * EMBEDc * DFFc;
    short* wex1_hi = wf2_lo + (size_t)NLc * EMBEDc * DFFc;   // 256*64
    short* wex1_lo = wex1_hi + EMBEDc * NZc;
    short* wex2_hi = wex1_lo + EMBEDc * NZc;                 // 256*256
    short* wex2_lo = wex2_hi + EMBEDc * EMBEDc;
    short* wo1_hi  = wex2_lo + EMBEDc * EMBEDc;              // 256*256
    short* wo1_lo  = wo1_hi + EMBEDc * EMBEDc;
    // zt aliases the o buffer (only used in preamble, before k_attn writes o)
    short* zt_hi = o_hi;
    short* zt_lo = o_lo;

    k_cvt_all<<<1024, 256, 0, stream>>>(Wq, Wk, Wv, Wo, Wf1, Wf2, ex_w1, ex_w2, o_w1,
                                        wqkv_hi, wqkv_lo, wo_hi, wo_lo,
                                        wf1_hi, wf1_lo, wf2_hi, wf2_lo,
                                        wex1_hi, wex1_lo, wex2_hi, wex2_lo,
                                        wo1_hi, wo1_lo);

    k_biasbins<<<(NLc * NHc * NBINSc + 255) / 256, 256, 0, stream>>>(pos_emb, W2d, b2d, bbuf);
    k_eaa<<<NTOK / 256, 256, 0, stream>>>(x, aa_emb, um_hi, um_lo);

    // embed: zt -> relu GEMM -> GEMM (fp32 h + bf16 um)
    k_zt<<<NTOK / 256, 256, 0, stream>>>(z, zt_hi, zt_lo);
    k_gemm2<1><<<128, 256, 0, stream>>>(
        zt_hi, zt_lo, NZc, wex1_hi, wex1_lo, NZc, NZc,
        nullptr, 0, f1_hi, f1_lo, EMBEDc, ex_b1, 4);
    k_gemm2<3><<<128, 256, 0, stream>>>(
        f1_hi, f1_lo, EMBEDc, wex2_hi, wex2_lo, EMBEDc, EMBEDc,
        h, EMBEDc, um_hi, um_lo, UMDIM, ex_b2, 4);

    for (int l = 0; l < NLc; ++l) {
        k_gemm2<2><<<384, 256, 0, stream>>>(
            um_hi, um_lo, UMDIM,
            wqkv_hi + (size_t)l * 768 * EMBEDc, wqkv_lo + (size_t)l * 768 * EMBEDc, EMBEDc,
            EMBEDc, nullptr, 0, qkvh, qkvl, 768, nullptr, 12);
        k_attn<<<NB * NHc * 4, 256, 0, stream>>>(qkvh, qkvl, bbuf + (size_t)l * NHc * NBINSc, o_hi, o_lo);
        k_gemm2<0><<<128, 256, 0, stream>>>(
            o_hi, o_lo, EMBEDc,
            wo_hi + (size_t)l * EMBEDc * DMc, wo_lo + (size_t)l * EMBEDc * DMc, DMc,
            DMc, s2, EMBEDc, nullptr, nullptr, 0, nullptr, 4);
        k_ln<<<NTOK / 16, 256, 0, stream>>>(s2, bo + (size_t)l * EMBEDc,
                                            ln1_g + (size_t)l * EMBEDc, ln1_b + (size_t)l * EMBEDc,
                                            h, um_hi, um_lo);
        k_gemm2<1><<<512, 256, 0, stream>>>(
            um_hi, um_lo, UMDIM,
            wf1_hi + (size_t)l * DFFc * UMDIM, wf1_lo + (size_t)l * DFFc * UMDIM, UMDIM,
            UMDIM, nullptr, 0, f1_hi, f1_lo, DFFc, bf1 + (size_t)l * DFFc, 16);
        k_gemm2<0><<<128, 256, 0, stream>>>(
            f1_hi, f1_lo, DFFc,
            wf2_hi + (size_t)l * EMBEDc * DFFc, wf2_lo + (size_t)l * EMBEDc * DFFc, DFFc,
            DFFc, s2, EMBEDc, nullptr, nullptr, 0, nullptr, 4);
        k_ln<<<NTOK / 16, 256, 0, stream>>>(s2, bf2 + (size_t)l * EMBEDc,
                                            ln2_g + (size_t)l * EMBEDc, ln2_b + (size_t)l * EMBEDc,
                                            h, um_hi, um_lo);
    }

    // final: f = relu(um @ o_w1^T + o_b1) (um cols 0..255 hold h in bf16)
    k_gemm2<1><<<128, 256, 0, stream>>>(
        um_hi, um_lo, UMDIM, wo1_hi, wo1_lo, EMBEDc, EMBEDc,
        nullptr, 0, f1_hi, f1_lo, EMBEDc, o_b1, 4);
    k_r<<<NTOK / 64, 256, 0, stream>>>(f1_hi, f1_lo, o_w2, o_b2, r);
    k_dmap<<<NB * Lc, 256, 0, stream>>>(r, (float*)d_out);
}

// Round 8
// 656.466 us; speedup vs baseline: 8.4096x; 1.1606x over previous
//
#include <hip/hip_runtime.h>
#include <math.h>

#define NZc     64
#define EMBEDc  256
#define DMc     256
#define NHc     16
#define HDc     16
#define DFFc    1024
#define NLc     6
#define E1Dc    32
#define PDIMc   64
#define PMAXLc  24
#define NBINSc  49
#define NB      8
#define Lc      512
#define NTOK    (NB * Lc)        // 4096
#define UMDIM   (EMBEDc + E1Dc)  // 288

typedef __attribute__((ext_vector_type(4))) float f4;
typedef __attribute__((ext_vector_type(8))) short bf8;   // 8 bf16 in 4 VGPRs

#define MFMA(a, b, c) __builtin_amdgcn_mfma_f32_16x16x32_bf16((a), (b), (c), 0, 0, 0)

__device__ __forceinline__ short f2bf(float f) {
    unsigned u = __float_as_uint(f);
    u += 0x7FFFu + ((u >> 16) & 1u);   // round-to-nearest-even
    return (short)(u >> 16);
}
__device__ __forceinline__ float bf2f(short s) {
    return __uint_as_float(((unsigned)(unsigned short)s) << 16);
}

// ---------------------------------------------------------------------------
// all weight conversions fused into one kernel
__global__ void k_cvt_all(const float* __restrict__ Wq, const float* __restrict__ Wk,
                          const float* __restrict__ Wv, const float* __restrict__ Wo,
                          const float* __restrict__ Wf1, const float* __restrict__ Wf2,
                          const float* __restrict__ exw1, const float* __restrict__ exw2,
                          const float* __restrict__ ow1,
                          short* __restrict__ wqkv_hi, short* __restrict__ wqkv_lo,
                          short* __restrict__ wo_hi, short* __restrict__ wo_lo,
                          short* __restrict__ wf1_hi, short* __restrict__ wf1_lo,
                          short* __restrict__ wf2_hi, short* __restrict__ wf2_lo,
                          short* __restrict__ wex1_hi, short* __restrict__ wex1_lo,
                          short* __restrict__ wex2_hi, short* __restrict__ wex2_lo,
                          short* __restrict__ wo1_hi, short* __restrict__ wo1_lo) {
    int stride = gridDim.x * blockDim.x;
    int tid = blockIdx.x * blockDim.x + threadIdx.x;
#define CVT(src, hi, lo, per_layer, dstride, doff, scale, total)               \
    for (int i = tid; i < (total); i += stride) {                              \
        int ll = i / (per_layer), rels = i - ll * (per_layer);                 \
        size_t di = (size_t)ll * (dstride) + (doff) + rels;                    \
        float v = src[i] * (scale);                                            \
        short hh = f2bf(v);                                                    \
        hi[di] = hh;                                                           \
        lo[di] = f2bf(v - bf2f(hh));                                           \
    }
    CVT(Wq,  wqkv_hi, wqkv_lo, 65536, 196608, 0,      0.0625f, 393216);
    CVT(Wk,  wqkv_hi, wqkv_lo, 65536, 196608, 65536,  1.f,     393216);
    CVT(Wv,  wqkv_hi, wqkv_lo, 65536, 196608, 131072, 1.f,     393216);
    CVT(Wo,  wo_hi,  wo_lo,  65536,  65536,  0, 1.f, 393216);
    CVT(Wf1, wf1_hi, wf1_lo, 294912, 294912, 0, 1.f, 1769472);
    CVT(Wf2, wf2_hi, wf2_lo, 262144, 262144, 0, 1.f, 1572864);
    CVT(exw1, wex1_hi, wex1_lo, 16384, 16384, 0, 1.f, 16384);
    CVT(exw2, wex2_hi, wex2_lo, 65536, 65536, 0, 1.f, 65536);
    CVT(ow1,  wo1_hi,  wo1_lo,  65536, 65536, 0, 1.f, 65536);
#undef CVT
}

// ---------------------------------------------------------------------------
__global__ void k_biasbins(const float* __restrict__ pos_emb,
                           const float* __restrict__ W2d,
                           const float* __restrict__ b2d,
                           float* __restrict__ bb) {
    int idx = blockIdx.x * blockDim.x + threadIdx.x;
    if (idx >= NLc * NHc * NBINSc) return;
    int bin = idx % NBINSc;
    int tmp = idx / NBINSc;
    int hh = tmp % NHc;
    int l  = tmp / NHc;
    float s = b2d[l * NHc + hh];
    const float* pe = pos_emb + bin * PDIMc;
    const float* w  = W2d + (l * NHc + hh) * PDIMc;
    for (int p = 0; p < PDIMc; ++p) s += pe[p] * w[p];
    bb[idx] = s;
}

// ---------------------------------------------------------------------------
__global__ void k_eaa(const float* __restrict__ x,
                      const float* __restrict__ aa_emb,
                      short* __restrict__ umhi, short* __restrict__ umlo) {
    int tok = blockIdx.x * blockDim.x + threadIdx.x;
    if (tok >= NTOK) return;
    int n = tok / Lc, l = tok % Lc;
    const float* xp = x + (size_t)n * 20 * Lc + l;
    float best = xp[0];
    int bi = 0;
    for (int c = 1; c < 20; ++c) {
        float v = xp[c * Lc];
        if (v > best) { best = v; bi = c; }
    }
    const float* e = aa_emb + bi * E1Dc;
    for (int c = 0; c < E1Dc; ++c) {
        float v = e[c];
        short h = f2bf(v);
        umhi[(size_t)tok * UMDIM + EMBEDc + c] = h;
        umlo[(size_t)tok * UMDIM + EMBEDc + c] = f2bf(v - bf2f(h));
    }
}

// ---------------------------------------------------------------------------
__global__ __launch_bounds__(256) void k_zt(const float* __restrict__ z,
                                            short* __restrict__ zth,
                                            short* __restrict__ ztl) {
    int tok = blockIdx.x * blockDim.x + threadIdx.x;
    int n = tok >> 9, l = tok & 511;
    for (int c = 0; c < NZc; ++c) {
        float v = z[((size_t)n * NZc + c) * Lc + l];
        short hv = f2bf(v);
        zth[(size_t)tok * NZc + c] = hv;
        ztl[(size_t)tok * NZc + c] = f2bf(v - bf2f(hv));
    }
}

// ---------------------------------------------------------------------------
// LDS-staged MFMA GEMM, XCD-swizzled, templated tile height + optional
// split-K(2) into separate partial buffers (outf, outf + NTOK*EMBEDc).
// Tile = (MF*64)M x 64N, BK=32, 4 waves; wave = (MF*16)M x 64N (Mf=MF, Nf=4).
// EPI 0: fp32 out(ldo). EPI 1: relu(acc+bias)->hi/lo(ldh).
// EPI 2: acc->hi/lo(ldh). EPI 3: acc+bias->fp32 out AND hi/lo.
template <int EPI, int MF, int SPLITK>
__global__ __launch_bounds__(256) void k_gemm3(
    const short* __restrict__ Ahi, const short* __restrict__ Alo, int lda,
    const short* __restrict__ Bhi, const short* __restrict__ Blo, int ldb,
    int K, float* __restrict__ outf, int ldo, short* __restrict__ ohi,
    short* __restrict__ olo, int ldh, const float* __restrict__ bias,
    int gx, int gypx) {
    __shared__ __align__(16) short Ah[MF * 64][32];
    __shared__ __align__(16) short Al[MF * 64][32];
    __shared__ __align__(16) short Bh[64][32];
    __shared__ __align__(16) short Bl[64][32];

    int bid = blockIdx.x;
    int koff = 0;
    if (SPLITK) {
        int kh = bid >> 7;
        bid &= 127;
        koff = kh * K;
        outf += (size_t)kh * NTOK * EMBEDc;
    }
    int xcd = bid & 7, j = bid >> 3;
    int bx = j % gx, by = xcd * gypx + j / gx;

    int t = threadIdx.x;
    int w = t >> 6, l = t & 63, lr = l & 15, lk = l >> 4;
    int m0 = by * (MF * 64);
    int n0 = bx * 64;

    int srow = t >> 2, scol = (t & 3) * 8;
    const short* pa  = Ahi + (size_t)(m0 + srow) * lda + koff + scol;
    const short* pal = Alo + (size_t)(m0 + srow) * lda + koff + scol;
    const short* pb  = Bhi + (size_t)(n0 + srow) * ldb + koff + scol;
    const short* pbl = Blo + (size_t)(n0 + srow) * ldb + koff + scol;

    bf8 ra[MF], rla[MF], rb, rlb;
#pragma unroll
    for (int p = 0; p < MF; ++p) {
        ra[p]  = *(const bf8*)(pa  + (size_t)p * 64 * lda);
        rla[p] = *(const bf8*)(pal + (size_t)p * 64 * lda);
    }
    rb  = *(const bf8*)pb;
    rlb = *(const bf8*)pbl;

    f4 acc[MF][4];
#pragma unroll
    for (int mf = 0; mf < MF; ++mf)
#pragma unroll
        for (int nf = 0; nf < 4; ++nf) acc[mf][nf] = (f4){0.f, 0.f, 0.f, 0.f};

    for (int ks = 0; ks < K; ks += 32) {
        __syncthreads();
#pragma unroll
        for (int p = 0; p < MF; ++p) {
            *(bf8*)&Ah[p * 64 + srow][scol] = ra[p];
            *(bf8*)&Al[p * 64 + srow][scol] = rla[p];
        }
        *(bf8*)&Bh[srow][scol] = rb;
        *(bf8*)&Bl[srow][scol] = rlb;
        __syncthreads();
        if (ks + 32 < K) {
#pragma unroll
            for (int p = 0; p < MF; ++p) {
                ra[p]  = *(const bf8*)(pa  + (size_t)p * 64 * lda + ks + 32);
                rla[p] = *(const bf8*)(pal + (size_t)p * 64 * lda + ks + 32);
            }
            rb  = *(const bf8*)(pb + ks + 32);
            rlb = *(const bf8*)(pbl + ks + 32);
        }
        bf8 bhf[4], blf[4];
#pragma unroll
        for (int nf = 0; nf < 4; ++nf) {
            bhf[nf] = *(const bf8*)&Bh[nf * 16 + lr][lk * 8];
            blf[nf] = *(const bf8*)&Bl[nf * 16 + lr][lk * 8];
        }
#pragma unroll
        for (int mf = 0; mf < MF; ++mf) {
            bf8 ah = *(const bf8*)&Ah[w * MF * 16 + mf * 16 + lr][lk * 8];
            bf8 al = *(const bf8*)&Al[w * MF * 16 + mf * 16 + lr][lk * 8];
#pragma unroll
            for (int nf = 0; nf < 4; ++nf) {
                acc[mf][nf] = MFMA(ah, bhf[nf], acc[mf][nf]);
                acc[mf][nf] = MFMA(ah, blf[nf], acc[mf][nf]);
                acc[mf][nf] = MFMA(al, bhf[nf], acc[mf][nf]);
            }
        }
    }

#pragma unroll
    for (int mf = 0; mf < MF; ++mf) {
#pragma unroll
        for (int nf = 0; nf < 4; ++nf) {
            int n = n0 + nf * 16 + lr;
            int mbase = m0 + w * MF * 16 + mf * 16 + lk * 4;
            if (EPI == 0) {
#pragma unroll
                for (int r = 0; r < 4; ++r)
                    outf[(size_t)(mbase + r) * ldo + n] = acc[mf][nf][r];
            } else if (EPI == 1) {
                float bv = bias[n];
#pragma unroll
                for (int r = 0; r < 4; ++r) {
                    float y = fmaxf(acc[mf][nf][r] + bv, 0.f);
                    short hv = f2bf(y);
                    size_t oi = (size_t)(mbase + r) * ldh + n;
                    ohi[oi] = hv;
                    olo[oi] = f2bf(y - bf2f(hv));
                }
            } else if (EPI == 2) {
#pragma unroll
                for (int r = 0; r < 4; ++r) {
                    float y = acc[mf][nf][r];
                    short hv = f2bf(y);
                    size_t oi = (size_t)(mbase + r) * ldh + n;
                    ohi[oi] = hv;
                    olo[oi] = f2bf(y - bf2f(hv));
                }
            } else {
                float bv = bias[n];
#pragma unroll
                for (int r = 0; r < 4; ++r) {
                    float y = acc[mf][nf][r] + bv;
                    outf[(size_t)(mbase + r) * ldo + n] = y;
                    short hv = f2bf(y);
                    size_t oi = (size_t)(mbase + r) * ldh + n;
                    ohi[oi] = hv;
                    olo[oi] = f2bf(y - bf2f(hv));
                }
            }
        }
    }
}

// ---------------------------------------------------------------------------
// MFMA flash attention, 512 threads: 8 waves cover 256 q-rows sharing one
// K/V LDS stage (2 blocks/CU -> 16 waves/CU). Dual q-tile chains per wave.
__global__ __launch_bounds__(512, 4) void k_attn(const short* __restrict__ qh,
                                                 const short* __restrict__ ql,
                                                 const float* __restrict__ bb,
                                                 short* __restrict__ ohi,
                                                 short* __restrict__ olo) {
    int bx = blockIdx.x;
    int qt = bx >> 7;            // slow: blocks sharing (n,head) are 128 apart
    int head = bx & 15;
    int n = (bx >> 4) & 7;
    int t = threadIdx.x;
    int w = t >> 6, l = t & 63;
    int lq = l & 15, lk = l >> 4;

    __shared__ __align__(16) short khl[512][40];   // [key][hi0-15|lo16-31|pad]
    __shared__ __align__(16) short vth[16][536];   // V^T hi: [d][key]
    __shared__ __align__(16) short vtl[16][536];   // V^T lo
    __shared__ float biasr[64];

    if (t < NBINSc) biasr[t] = bb[head * NBINSc + t];
    float bL = bb[head * NBINSc];
    float bR = bb[head * NBINSc + 48];

    size_t base = (size_t)n * Lc * 768 + head * 16;
    for (int u = t; u < 2048; u += 512) {
        int key = u >> 2, seg = u & 3;
        const short* src = (seg < 2 ? qh : ql) + base + 256 + (size_t)key * 768 + (seg & 1) * 8;
        *(bf8*)&khl[key][seg * 8] = *(const bf8*)src;
    }
    {
        int u = t & 255, half2 = t >> 8;     // pair u -> keys 2u,2u+1; d-half
        const short* vsh = qh + base + 512 + (size_t)(u * 2) * 768 + half2 * 8;
        const short* vsl = ql + base + 512 + (size_t)(u * 2) * 768 + half2 * 8;
        bf8 A = *(const bf8*)vsh;
        bf8 B = *(const bf8*)(vsh + 768);
        bf8 C = *(const bf8*)vsl;
        bf8 D = *(const bf8*)(vsl + 768);
        unsigned* vthw = (unsigned*)&vth[0][0];   // row stride 268 words
        unsigned* vtlw = (unsigned*)&vtl[0][0];
#pragma unroll
        for (int i = 0; i < 8; ++i) {
            int row = half2 * 8 + i;
            vthw[row * 268 + u] = (unsigned)(unsigned short)A[i] | ((unsigned)(unsigned short)B[i] << 16);
            vtlw[row * 268 + u] = (unsigned)(unsigned short)C[i] | ((unsigned)(unsigned short)D[i] << 16);
        }
    }
    __syncthreads();

    int qg = qt * 256 + w * 32 + lq;             // q-tile 0 row; tile 1 = +16
    size_t qrow = ((size_t)n * Lc + qg) * 768 + head * 16;
    bf8 B1a = *(const bf8*)(qh + qrow + (lk & 1) * 8);
    bf8 B1b = *(const bf8*)(qh + qrow + 16 * 768 + (lk & 1) * 8);
    bf8 B2a, B2b;
    if (lk < 2) {
        B2a = *(const bf8*)(ql + qrow + lk * 8);
        B2b = *(const bf8*)(ql + qrow + 16 * 768 + lk * 8);
    } else {
#pragma unroll
        for (int i = 0; i < 8; ++i) { B2a[i] = 0; B2b[i] = 0; }
    }

    f4 acc0 = (f4){0.f, 0.f, 0.f, 0.f};
    f4 acc1 = (f4){0.f, 0.f, 0.f, 0.f};
    float m0 = -1e30f, m1 = -1e30f, ls0 = 0.f, ls1 = 0.f;
    int rel0 = lk * 4 - qg;      // rel of s0[0] at kt=0; s1 uses rel0-16

    for (int kt = 0; kt < 32; ++kt, rel0 += 16) {
        bf8 A1 = *(const bf8*)&khl[kt * 16 + lq][lk * 8];
        f4 s0 = (f4){0.f, 0.f, 0.f, 0.f};
        f4 s1 = (f4){0.f, 0.f, 0.f, 0.f};
        __builtin_amdgcn_s_setprio(1);
        s0 = MFMA(A1, B1a, s0);
        s0 = MFMA(A1, B2a, s0);
        s1 = MFMA(A1, B1b, s1);
        s1 = MFMA(A1, B2b, s1);
        __builtin_amdgcn_s_setprio(0);
        if (rel0 >= PMAXLc) {
            s0[0] += bR; s0[1] += bR; s0[2] += bR; s0[3] += bR;
        } else if (rel0 + 3 <= -PMAXLc) {
            s0[0] += bL; s0[1] += bL; s0[2] += bL; s0[3] += bL;
        } else {
#pragma unroll
            for (int r = 0; r < 4; ++r) {
                int rel = rel0 + r;
                rel = rel < -PMAXLc ? -PMAXLc : (rel > PMAXLc ? PMAXLc : rel);
                s0[r] += biasr[rel + PMAXLc];
            }
        }
        int rel1 = rel0 - 16;
        if (rel1 >= PMAXLc) {
            s1[0] += bR; s1[1] += bR; s1[2] += bR; s1[3] += bR;
        } else if (rel1 + 3 <= -PMAXLc) {
            s1[0] += bL; s1[1] += bL; s1[2] += bL; s1[3] += bL;
        } else {
#pragma unroll
            for (int r = 0; r < 4; ++r) {
                int rel = rel1 + r;
                rel = rel < -PMAXLc ? -PMAXLc : (rel > PMAXLc ? PMAXLc : rel);
                s1[r] += biasr[rel + PMAXLc];
            }
        }
        float mt0 = fmaxf(fmaxf(s0[0], s0[1]), fmaxf(s0[2], s0[3]));
        float mt1 = fmaxf(fmaxf(s1[0], s1[1]), fmaxf(s1[2], s1[3]));
        mt0 = fmaxf(mt0, __shfl_xor(mt0, 16));
        mt0 = fmaxf(mt0, __shfl_xor(mt0, 32));
        mt1 = fmaxf(mt1, __shfl_xor(mt1, 16));
        mt1 = fmaxf(mt1, __shfl_xor(mt1, 32));
        if (__any((mt0 > m0 + 8.0f) || (mt1 > m1 + 8.0f))) {
            float mn0 = fmaxf(m0, mt0), a0 = __expf(m0 - mn0);
            float mn1 = fmaxf(m1, mt1), a1 = __expf(m1 - mn1);
            m0 = mn0; m1 = mn1;
            ls0 *= a0; ls1 *= a1;
#pragma unroll
            for (int r = 0; r < 4; ++r) {
                acc0[r] *= __shfl(a0, lk * 4 + r);
                acc1[r] *= __shfl(a1, lk * 4 + r);
            }
        }
        f4 p0, p1;
#pragma unroll
        for (int r = 0; r < 4; ++r) { p0[r] = __expf(s0[r] - m0); p1[r] = __expf(s1[r] - m1); }
        ls0 += p0[0] + p0[1] + p0[2] + p0[3];
        ls1 += p1[0] + p1[1] + p1[2] + p1[3];
        int src0 = (lk & 1) * 32 + lq;
        int src1 = src0 + 16;
        float g0[8], g1[8];
#pragma unroll
        for (int jj = 0; jj < 4; ++jj) {
            g0[jj]     = __shfl(p0[jj], src0);
            g0[jj + 4] = __shfl(p0[jj], src1);
            g1[jj]     = __shfl(p1[jj], src0);
            g1[jj + 4] = __shfl(p1[jj], src1);
        }
        bf8 PA0, PA1;
        if (lk < 2) {
#pragma unroll
            for (int jj = 0; jj < 8; ++jj) {
                PA0[jj] = (short)(__float_as_uint(g0[jj]) >> 16);
                PA1[jj] = (short)(__float_as_uint(g1[jj]) >> 16);
            }
        } else {
#pragma unroll
            for (int jj = 0; jj < 8; ++jj) {
                unsigned hu0 = __float_as_uint(g0[jj]) & 0xFFFF0000u;
                unsigned hu1 = __float_as_uint(g1[jj]) & 0xFFFF0000u;
                PA0[jj] = (short)(__float_as_uint(g0[jj] - __uint_as_float(hu0)) >> 16);
                PA1[jj] = (short)(__float_as_uint(g1[jj] - __uint_as_float(hu1)) >> 16);
            }
        }
        bf8 VB1 = *(const bf8*)&vth[lq][kt * 16 + (lk & 1) * 8];
        bf8 VB2;
        if (lk < 2) VB2 = *(const bf8*)&vtl[lq][kt * 16 + lk * 8];
        else {
#pragma unroll
            for (int i = 0; i < 8; ++i) VB2[i] = 0;
        }
        __builtin_amdgcn_s_setprio(1);
        acc0 = MFMA(PA0, VB1, acc0);
        acc0 = MFMA(PA0, VB2, acc0);
        acc1 = MFMA(PA1, VB1, acc1);
        acc1 = MFMA(PA1, VB2, acc1);
        __builtin_amdgcn_s_setprio(0);
    }

    float lr0 = ls0 + __shfl_xor(ls0, 16);
    lr0 += __shfl_xor(lr0, 32);
    float lr1 = ls1 + __shfl_xor(ls1, 16);
    lr1 += __shfl_xor(lr1, 32);
    float inv0 = 1.0f / lr0;
    float inv1 = 1.0f / lr1;
#pragma unroll
    for (int r = 0; r < 4; ++r) {
        float iq0 = __shfl(inv0, lk * 4 + r);
        float iq1 = __shfl(inv1, lk * 4 + r);
        float y0 = acc0[r] * iq0;
        float y1 = acc1[r] * iq1;
        int qo = qt * 256 + w * 32 + lk * 4 + r;
        size_t oi0 = ((size_t)n * Lc + qo) * DMc + head * 16 + lq;
        size_t oi1 = oi0 + (size_t)16 * DMc;
        unsigned hu0 = __float_as_uint(y0) & 0xFFFF0000u;
        unsigned hu1 = __float_as_uint(y1) & 0xFFFF0000u;
        ohi[oi0] = (short)(hu0 >> 16);
        olo[oi0] = (short)(__float_as_uint(y0 - __uint_as_float(hu0)) >> 16);
        ohi[oi1] = (short)(hu1 >> 16);
        olo[oi1] = (short)(__float_as_uint(y1 - __uint_as_float(hu1)) >> 16);
    }
}

// ---------------------------------------------------------------------------
// LN over h + s2a + s2b + sbias (split-K partials summed here)
__global__ __launch_bounds__(256) void k_ln(const float* __restrict__ s2a,
                                            const float* __restrict__ s2b,
                                            const float* __restrict__ sbias,
                                            const float* __restrict__ g,
                                            const float* __restrict__ bta,
                                            float* __restrict__ h,
                                            short* __restrict__ umhi,
                                            short* __restrict__ umlo) {
    int tile = blockIdx.x;
    int t = threadIdx.x;
    int tok = t >> 4, j = t & 15;
    size_t gtok = (size_t)tile * 16 + tok;
    float sum = 0.f, ssq = 0.f;
    float vals[16];
#pragma unroll
    for (int d0 = 0; d0 < 16; ++d0) {
        int d = j + d0 * 16;
        float vv = h[gtok * EMBEDc + d] + s2a[gtok * EMBEDc + d]
                 + s2b[gtok * EMBEDc + d] + sbias[d];
        vals[d0] = vv;
        sum += vv;
        ssq += vv * vv;
    }
#pragma unroll
    for (int off = 8; off; off >>= 1) {
        sum += __shfl_xor(sum, off, 16);
        ssq += __shfl_xor(ssq, off, 16);
    }
    float mean = sum * (1.f / EMBEDc);
    float var = ssq * (1.f / EMBEDc) - mean * mean;
    float inv = rsqrtf(var + 1e-5f);
#pragma unroll
    for (int d0 = 0; d0 < 16; ++d0) {
        int d = j + d0 * 16;
        float y = (vals[d0] - mean) * inv * g[d] + bta[d];
        h[gtok * EMBEDc + d] = y;
        short hv = f2bf(y);
        umhi[gtok * UMDIM + d] = hv;
        umlo[gtok * UMDIM + d] = f2bf(y - bf2f(hv));
    }
}

// ---------------------------------------------------------------------------
__global__ __launch_bounds__(256) void k_r(const short* __restrict__ fh,
                                           const short* __restrict__ fl,
                                           const float* __restrict__ w2,
                                           const float* __restrict__ b2,
                                           float* __restrict__ r) {
    __shared__ float w[3][EMBEDc];
    int t = threadIdx.x;
    for (int u = t; u < 3 * EMBEDc; u += 256) w[u >> 8][u & 255] = w2[u];
    __syncthreads();
    int tok = blockIdx.x * 64 + (t >> 2), o = t & 3;
    if (o < 3) {
        const short* ph = fh + (size_t)tok * EMBEDc;
        const short* pl = fl + (size_t)tok * EMBEDc;
        float s = b2[o];
        for (int c8 = 0; c8 < EMBEDc / 8; ++c8) {
            bf8 vh = *(const bf8*)(ph + c8 * 8);
            bf8 vl = *(const bf8*)(pl + c8 * 8);
#pragma unroll
            for (int j = 0; j < 8; ++j)
                s += (bf2f(vh[j]) + bf2f(vl[j])) * w[o][c8 * 8 + j];
        }
        r[(size_t)tok * 3 + o] = s;
    }
}

// ---------------------------------------------------------------------------
__global__ __launch_bounds__(256) void k_dmap(const float* __restrict__ r,
                                              float* __restrict__ d) {
    int b = blockIdx.x;
    int n = b / Lc;
    float xi = r[(size_t)b * 3], yi = r[(size_t)b * 3 + 1], zi = r[(size_t)b * 3 + 2];
    const float* rn = r + (size_t)n * Lc * 3;
    for (int j = threadIdx.x; j < Lc; j += 256) {
        float dx = xi - rn[j * 3];
        float dy = yi - rn[j * 3 + 1];
        float dz = zi - rn[j * 3 + 2];
        d[(size_t)b * Lc + j] = sqrtf(dx * dx + dy * dy + dz * dz + 1e-12f);
    }
}

// ---------------------------------------------------------------------------
extern "C" void kernel_launch(void* const* d_in, const int* in_sizes, int n_in,
                              void* d_out, int out_size, void* d_ws, size_t ws_size,
                              hipStream_t stream) {
    const float* z       = (const float*)d_in[0];
    const float* x       = (const float*)d_in[1];
    const float* pos_emb = (const float*)d_in[2];
    const float* aa_emb  = (const float*)d_in[3];
    const float* ex_w1   = (const float*)d_in[4];
    const float* ex_b1   = (const float*)d_in[5];
    const float* ex_w2   = (const float*)d_in[6];
    const float* ex_b2   = (const float*)d_in[7];
    const float* Wq      = (const float*)d_in[8];
    const float* Wk      = (const float*)d_in[9];
    const float* Wv      = (const float*)d_in[10];
    const float* Wo      = (const float*)d_in[11];
    const float* bo      = (const float*)d_in[12];
    const float* W2d     = (const float*)d_in[13];
    const float* b2d     = (const float*)d_in[14];
    const float* Wf1     = (const float*)d_in[15];
    const float* bf1     = (const float*)d_in[16];
    const float* Wf2     = (const float*)d_in[17];
    const float* bf2     = (const float*)d_in[18];
    const float* ln1_g   = (const float*)d_in[19];
    const float* ln1_b   = (const float*)d_in[20];
    const float* ln2_g   = (const float*)d_in[21];
    const float* ln2_b   = (const float*)d_in[22];
    const float* o_w1    = (const float*)d_in[23];
    const float* o_b1    = (const float*)d_in[24];
    const float* o_w2    = (const float*)d_in[25];
    const float* o_b2    = (const float*)d_in[26];

    float* h    = (float*)d_ws;                    // 4096*256
    float* s2a  = h + (size_t)NTOK * EMBEDc;
    float* s2b  = s2a + (size_t)NTOK * EMBEDc;
    float* bbuf = s2b + (size_t)NTOK * EMBEDc;     // pad 8192
    float* r    = bbuf + 8192;                     // pad 16384
    short* qkvh = (short*)(r + 16384);             // 4096*768
    short* qkvl = qkvh + (size_t)NTOK * 768;
    short* um_hi = qkvl + (size_t)NTOK * 768;      // 4096*288
    short* um_lo = um_hi + (size_t)NTOK * UMDIM;
    short* o_hi  = um_lo + (size_t)NTOK * UMDIM;   // 4096*256
    short* o_lo  = o_hi + (size_t)NTOK * EMBEDc;
    short* f1_hi = o_lo + (size_t)NTOK * EMBEDc;   // 4096*1024
    short* f1_lo = f1_hi + (size_t)NTOK * DFFc;
    short* wqkv_hi = f1_lo + (size_t)NTOK * DFFc;  // 6*768*256
    short* wqkv_lo = wqkv_hi + (size_t)NLc * 768 * EMBEDc;
    short* wo_hi   = wqkv_lo + (size_t)NLc * 768 * EMBEDc;   // 6*256*256
    short* wo_lo   = wo_hi + (size_t)NLc * EMBEDc * DMc;
    short* wf1_hi  = wo_lo + (size_t)NLc * EMBEDc * DMc;     // 6*1024*288
    short* wf1_lo  = wf1_hi + (size_t)NLc * DFFc * UMDIM;
    short* wf2_hi  = wf1_lo + (size_t)NLc * DFFc * UMDIM;    // 6*256*1024
    short* wf2_lo  = wf2_hi + (size_t)NLc * EMBEDc * DFFc;
    short* wex1_hi = wf2_lo + (size_t)NLc * EMBEDc * DFFc;   // 256*64
    short* wex1_lo = wex1_hi + EMBEDc * NZc;
    short* wex2_hi = wex1_lo + EMBEDc * NZc;                 // 256*256
    short* wex2_lo = wex2_hi + EMBEDc * EMBEDc;
    short* wo1_hi  = wex2_lo + EMBEDc * EMBEDc;              // 256*256
    short* wo1_lo  = wo1_hi + EMBEDc * EMBEDc;
    // zt aliases the o buffer (only used in preamble, before k_attn writes o)
    short* zt_hi = o_hi;
    short* zt_lo = o_lo;

    k_cvt_all<<<1024, 256, 0, stream>>>(Wq, Wk, Wv, Wo, Wf1, Wf2, ex_w1, ex_w2, o_w1,
                                        wqkv_hi, wqkv_lo, wo_hi, wo_lo,
                                        wf1_hi, wf1_lo, wf2_hi, wf2_lo,
                                        wex1_hi, wex1_lo, wex2_hi, wex2_lo,
                                        wo1_hi, wo1_lo);

    k_biasbins<<<(NLc * NHc * NBINSc + 255) / 256, 256, 0, stream>>>(pos_emb, W2d, b2d, bbuf);
    k_eaa<<<NTOK / 256, 256, 0, stream>>>(x, aa_emb, um_hi, um_lo);

    // embed: zt -> relu GEMM -> GEMM (fp32 h + bf16 um)
    k_zt<<<NTOK / 256, 256, 0, stream>>>(z, zt_hi, zt_lo);
    k_gemm3<1, 2, 0><<<128, 256, 0, stream>>>(
        zt_hi, zt_lo, NZc, wex1_hi, wex1_lo, NZc, NZc,
        nullptr, 0, f1_hi, f1_lo, EMBEDc, ex_b1, 4, 4);
    k_gemm3<3, 2, 0><<<128, 256, 0, stream>>>(
        f1_hi, f1_lo, EMBEDc, wex2_hi, wex2_lo, EMBEDc, EMBEDc,
        h, EMBEDc, um_hi, um_lo, UMDIM, ex_b2, 4, 4);

    for (int l = 0; l < NLc; ++l) {
        k_gemm3<2, 4, 0><<<192, 256, 0, stream>>>(
            um_hi, um_lo, UMDIM,
            wqkv_hi + (size_t)l * 768 * EMBEDc, wqkv_lo + (size_t)l * 768 * EMBEDc, EMBEDc,
            EMBEDc, nullptr, 0, qkvh, qkvl, 768, nullptr, 12, 2);
        k_attn<<<NB * NHc * 2, 512, 0, stream>>>(qkvh, qkvl, bbuf + (size_t)l * NHc * NBINSc, o_hi, o_lo);
        k_gemm3<0, 2, 1><<<256, 256, 0, stream>>>(
            o_hi, o_lo, EMBEDc,
            wo_hi + (size_t)l * EMBEDc * DMc, wo_lo + (size_t)l * EMBEDc * DMc, DMc,
            128, s2a, EMBEDc, nullptr, nullptr, 0, nullptr, 4, 4);
        k_ln<<<NTOK / 16, 256, 0, stream>>>(s2a, s2b, bo + (size_t)l * EMBEDc,
                                            ln1_g + (size_t)l * EMBEDc, ln1_b + (size_t)l * EMBEDc,
                                            h, um_hi, um_lo);
        k_gemm3<1, 4, 0><<<256, 256, 0, stream>>>(
            um_hi, um_lo, UMDIM,
            wf1_hi + (size_t)l * DFFc * UMDIM, wf1_lo + (size_t)l * DFFc * UMDIM, UMDIM,
            UMDIM, nullptr, 0, f1_hi, f1_lo, DFFc, bf1 + (size_t)l * DFFc, 16, 2);
        k_gemm3<0, 2, 1><<<256, 256, 0, stream>>>(
            f1_hi, f1_lo, DFFc,
            wf2_hi + (size_t)l * EMBEDc * DFFc, wf2_lo + (size_t)l * EMBEDc * DFFc, DFFc,
            512, s2a, EMBEDc, nullptr, nullptr, 0, nullptr, 4, 4);
        k_ln<<<NTOK / 16, 256, 0, stream>>>(s2a, s2b, bf2 + (size_t)l * EMBEDc,
                                            ln2_g + (size_t)l * EMBEDc, ln2_b + (size_t)l * EMBEDc,
                                            h, um_hi, um_lo);
    }

    // final: f = relu(um @ o_w1^T + o_b1) (um cols 0..255 hold h in bf16)
    k_gemm3<1, 2, 0><<<128, 256, 0, stream>>>(
        um_hi, um_lo, UMDIM, wo1_hi, wo1_lo, EMBEDc, EMBEDc,
        nullptr, 0, f1_hi, f1_lo, EMBEDc, o_b1, 4, 4);
    k_r<<<NTOK / 64, 256, 0, stream>>>(f1_hi, f1_lo, o_w2, o_b2, r);
    k_dmap<<<NB * Lc, 256, 0, stream>>>(r, (float*)d_out);
}

// Round 10
// 605.802 us; speedup vs baseline: 9.1129x; 1.0836x over previous
//
#include <hip/hip_runtime.h>
#include <math.h>

#define NZc     64
#define EMBEDc  256
#define DMc     256
#define NHc     16
#define HDc     16
#define DFFc    1024
#define NLc     6
#define E1Dc    32
#define PDIMc   64
#define PMAXLc  24
#define NBINSc  49
#define NB      8
#define Lc      512
#define NTOK    (NB * Lc)        // 4096
#define UMDIM   (EMBEDc + E1Dc)  // 288

typedef __attribute__((ext_vector_type(4))) float f4;
typedef __attribute__((ext_vector_type(8))) short bf8;   // 8 bf16 in 4 VGPRs

#define MFMA(a, b, c) __builtin_amdgcn_mfma_f32_16x16x32_bf16((a), (b), (c), 0, 0, 0)

__device__ __forceinline__ short f2bf(float f) {
    unsigned u = __float_as_uint(f);
    u += 0x7FFFu + ((u >> 16) & 1u);   // round-to-nearest-even
    return (short)(u >> 16);
}
__device__ __forceinline__ float bf2f(short s) {
    return __uint_as_float(((unsigned)(unsigned short)s) << 16);
}

// ---------------------------------------------------------------------------
// all weight conversions fused into one kernel
__global__ void k_cvt_all(const float* __restrict__ Wq, const float* __restrict__ Wk,
                          const float* __restrict__ Wv, const float* __restrict__ Wo,
                          const float* __restrict__ Wf1, const float* __restrict__ Wf2,
                          const float* __restrict__ exw1, const float* __restrict__ exw2,
                          const float* __restrict__ ow1,
                          short* __restrict__ wqkv_hi, short* __restrict__ wqkv_lo,
                          short* __restrict__ wo_hi, short* __restrict__ wo_lo,
                          short* __restrict__ wf1_hi, short* __restrict__ wf1_lo,
                          short* __restrict__ wf2_hi, short* __restrict__ wf2_lo,
                          short* __restrict__ wex1_hi, short* __restrict__ wex1_lo,
                          short* __restrict__ wex2_hi, short* __restrict__ wex2_lo,
                          short* __restrict__ wo1_hi, short* __restrict__ wo1_lo) {
    int stride = gridDim.x * blockDim.x;
    int tid = blockIdx.x * blockDim.x + threadIdx.x;
#define CVT(src, hi, lo, per_layer, dstride, doff, scale, total)               \
    for (int i = tid; i < (total); i += stride) {                              \
        int ll = i / (per_layer), rels = i - ll * (per_layer);                 \
        size_t di = (size_t)ll * (dstride) + (doff) + rels;                    \
        float v = src[i] * (scale);                                            \
        short hh = f2bf(v);                                                    \
        hi[di] = hh;                                                           \
        lo[di] = f2bf(v - bf2f(hh));                                           \
    }
    CVT(Wq,  wqkv_hi, wqkv_lo, 65536, 196608, 0,      0.0625f, 393216);
    CVT(Wk,  wqkv_hi, wqkv_lo, 65536, 196608, 65536,  1.f,     393216);
    CVT(Wv,  wqkv_hi, wqkv_lo, 65536, 196608, 131072, 1.f,     393216);
    CVT(Wo,  wo_hi,  wo_lo,  65536,  65536,  0, 1.f, 393216);
    CVT(Wf1, wf1_hi, wf1_lo, 294912, 294912, 0, 1.f, 1769472);
    CVT(Wf2, wf2_hi, wf2_lo, 262144, 262144, 0, 1.f, 1572864);
    CVT(exw1, wex1_hi, wex1_lo, 16384, 16384, 0, 1.f, 16384);
    CVT(exw2, wex2_hi, wex2_lo, 65536, 65536, 0, 1.f, 65536);
    CVT(ow1,  wo1_hi,  wo1_lo,  65536, 65536, 0, 1.f, 65536);
#undef CVT
}

// ---------------------------------------------------------------------------
__global__ void k_biasbins(const float* __restrict__ pos_emb,
                           const float* __restrict__ W2d,
                           const float* __restrict__ b2d,
                           float* __restrict__ bb) {
    int idx = blockIdx.x * blockDim.x + threadIdx.x;
    if (idx >= NLc * NHc * NBINSc) return;
    int bin = idx % NBINSc;
    int tmp = idx / NBINSc;
    int hh = tmp % NHc;
    int l  = tmp / NHc;
    float s = b2d[l * NHc + hh];
    const float* pe = pos_emb + bin * PDIMc;
    const float* w  = W2d + (l * NHc + hh) * PDIMc;
    for (int p = 0; p < PDIMc; ++p) s += pe[p] * w[p];
    bb[idx] = s;
}

// ---------------------------------------------------------------------------
__global__ void k_eaa(const float* __restrict__ x,
                      const float* __restrict__ aa_emb,
                      short* __restrict__ umhi, short* __restrict__ umlo) {
    int tok = blockIdx.x * blockDim.x + threadIdx.x;
    if (tok >= NTOK) return;
    int n = tok / Lc, l = tok % Lc;
    const float* xp = x + (size_t)n * 20 * Lc + l;
    float best = xp[0];
    int bi = 0;
    for (int c = 1; c < 20; ++c) {
        float v = xp[c * Lc];
        if (v > best) { best = v; bi = c; }
    }
    const float* e = aa_emb + bi * E1Dc;
    for (int c = 0; c < E1Dc; ++c) {
        float v = e[c];
        short h = f2bf(v);
        umhi[(size_t)tok * UMDIM + EMBEDc + c] = h;
        umlo[(size_t)tok * UMDIM + EMBEDc + c] = f2bf(v - bf2f(h));
    }
}

// ---------------------------------------------------------------------------
__global__ __launch_bounds__(256) void k_zt(const float* __restrict__ z,
                                            short* __restrict__ zth,
                                            short* __restrict__ ztl) {
    int tok = blockIdx.x * blockDim.x + threadIdx.x;
    int n = tok >> 9, l = tok & 511;
    for (int c = 0; c < NZc; ++c) {
        float v = z[((size_t)n * NZc + c) * Lc + l];
        short hv = f2bf(v);
        zth[(size_t)tok * NZc + c] = hv;
        ztl[(size_t)tok * NZc + c] = f2bf(v - bf2f(hv));
    }
}

// ---------------------------------------------------------------------------
// LDS-staged MFMA GEMM, XCD-swizzled, templated tile height + optional
// split-K into separate partial buffers (outf + kh*NTOK*EMBEDc).
// SKSHIFT = log2(blocks per K-half); 0 = no split.
template <int EPI, int MF, int SKSHIFT>
__global__ __launch_bounds__(256) void k_gemm3(
    const short* __restrict__ Ahi, const short* __restrict__ Alo, int lda,
    const short* __restrict__ Bhi, const short* __restrict__ Blo, int ldb,
    int K, float* __restrict__ outf, int ldo, short* __restrict__ ohi,
    short* __restrict__ olo, int ldh, const float* __restrict__ bias,
    int gx, int gypx) {
    __shared__ __align__(16) short Ah[MF * 64][32];
    __shared__ __align__(16) short Al[MF * 64][32];
    __shared__ __align__(16) short Bh[64][32];
    __shared__ __align__(16) short Bl[64][32];

    int bid = blockIdx.x;
    int koff = 0;
    if (SKSHIFT) {
        int kh = bid >> SKSHIFT;
        bid &= (1 << SKSHIFT) - 1;
        koff = kh * K;
        outf += (size_t)kh * NTOK * EMBEDc;
    }
    int xcd = bid & 7, j = bid >> 3;
    int bx = j % gx, by = xcd * gypx + j / gx;

    int t = threadIdx.x;
    int w = t >> 6, l = t & 63, lr = l & 15, lk = l >> 4;
    int m0 = by * (MF * 64);
    int n0 = bx * 64;

    int srow = t >> 2, scol = (t & 3) * 8;
    const short* pa  = Ahi + (size_t)(m0 + srow) * lda + koff + scol;
    const short* pal = Alo + (size_t)(m0 + srow) * lda + koff + scol;
    const short* pb  = Bhi + (size_t)(n0 + srow) * ldb + koff + scol;
    const short* pbl = Blo + (size_t)(n0 + srow) * ldb + koff + scol;

    bf8 ra[MF], rla[MF], rb, rlb;
#pragma unroll
    for (int p = 0; p < MF; ++p) {
        ra[p]  = *(const bf8*)(pa  + (size_t)p * 64 * lda);
        rla[p] = *(const bf8*)(pal + (size_t)p * 64 * lda);
    }
    rb  = *(const bf8*)pb;
    rlb = *(const bf8*)pbl;

    f4 acc[MF][4];
#pragma unroll
    for (int mf = 0; mf < MF; ++mf)
#pragma unroll
        for (int nf = 0; nf < 4; ++nf) acc[mf][nf] = (f4){0.f, 0.f, 0.f, 0.f};

    for (int ks = 0; ks < K; ks += 32) {
        __syncthreads();
#pragma unroll
        for (int p = 0; p < MF; ++p) {
            *(bf8*)&Ah[p * 64 + srow][scol] = ra[p];
            *(bf8*)&Al[p * 64 + srow][scol] = rla[p];
        }
        *(bf8*)&Bh[srow][scol] = rb;
        *(bf8*)&Bl[srow][scol] = rlb;
        __syncthreads();
        if (ks + 32 < K) {
#pragma unroll
            for (int p = 0; p < MF; ++p) {
                ra[p]  = *(const bf8*)(pa  + (size_t)p * 64 * lda + ks + 32);
                rla[p] = *(const bf8*)(pal + (size_t)p * 64 * lda + ks + 32);
            }
            rb  = *(const bf8*)(pb + ks + 32);
            rlb = *(const bf8*)(pbl + ks + 32);
        }
        bf8 bhf[4], blf[4];
#pragma unroll
        for (int nf = 0; nf < 4; ++nf) {
            bhf[nf] = *(const bf8*)&Bh[nf * 16 + lr][lk * 8];
            blf[nf] = *(const bf8*)&Bl[nf * 16 + lr][lk * 8];
        }
#pragma unroll
        for (int mf = 0; mf < MF; ++mf) {
            bf8 ah = *(const bf8*)&Ah[w * MF * 16 + mf * 16 + lr][lk * 8];
            bf8 al = *(const bf8*)&Al[w * MF * 16 + mf * 16 + lr][lk * 8];
#pragma unroll
            for (int nf = 0; nf < 4; ++nf) {
                acc[mf][nf] = MFMA(ah, bhf[nf], acc[mf][nf]);
                acc[mf][nf] = MFMA(ah, blf[nf], acc[mf][nf]);
                acc[mf][nf] = MFMA(al, bhf[nf], acc[mf][nf]);
            }
        }
    }

#pragma unroll
    for (int mf = 0; mf < MF; ++mf) {
#pragma unroll
        for (int nf = 0; nf < 4; ++nf) {
            int n = n0 + nf * 16 + lr;
            int mbase = m0 + w * MF * 16 + mf * 16 + lk * 4;
            if (EPI == 0) {
#pragma unroll
                for (int r = 0; r < 4; ++r)
                    outf[(size_t)(mbase + r) * ldo + n] = acc[mf][nf][r];
            } else if (EPI == 1) {
                float bv = bias[n];
#pragma unroll
                for (int r = 0; r < 4; ++r) {
                    float y = fmaxf(acc[mf][nf][r] + bv, 0.f);
                    short hv = f2bf(y);
                    size_t oi = (size_t)(mbase + r) * ldh + n;
                    ohi[oi] = hv;
                    olo[oi] = f2bf(y - bf2f(hv));
                }
            } else if (EPI == 2) {
#pragma unroll
                for (int r = 0; r < 4; ++r) {
                    float y = acc[mf][nf][r];
                    short hv = f2bf(y);
                    size_t oi = (size_t)(mbase + r) * ldh + n;
                    ohi[oi] = hv;
                    olo[oi] = f2bf(y - bf2f(hv));
                }
            } else {
                float bv = bias[n];
#pragma unroll
                for (int r = 0; r < 4; ++r) {
                    float y = acc[mf][nf][r] + bv;
                    outf[(size_t)(mbase + r) * ldo + n] = y;
                    short hv = f2bf(y);
                    size_t oi = (size_t)(mbase + r) * ldh + n;
                    ohi[oi] = hv;
                    olo[oi] = f2bf(y - bf2f(hv));
                }
            }
        }
    }
}

// ---------------------------------------------------------------------------
// MFMA flash attention: 512 threads, 8 waves x 16 q-rows = 128 q/block;
// qt in 0..3 -> grid 512 -> 2 blocks/CU -> 16 waves/CU.
__global__ __launch_bounds__(512, 4) void k_attn(const short* __restrict__ qh,
                                                 const short* __restrict__ ql,
                                                 const float* __restrict__ bb,
                                                 short* __restrict__ ohi,
                                                 short* __restrict__ olo) {
    int bx = blockIdx.x;
    int qt = bx >> 7;            // 0..3; blocks sharing (n,head) same XCD
    int head = bx & 15;
    int n = (bx >> 4) & 7;
    int t = threadIdx.x;
    int w = t >> 6, l = t & 63;
    int lq = l & 15, lk = l >> 4;

    __shared__ __align__(16) short khl[512][40];   // [key][hi0-15|lo16-31|pad]
    __shared__ __align__(16) short vth[16][536];   // V^T hi: [d][key]
    __shared__ __align__(16) short vtl[16][536];   // V^T lo
    __shared__ float biasr[64];

    if (t < NBINSc) biasr[t] = bb[head * NBINSc + t];
    float bL = bb[head * NBINSc];
    float bR = bb[head * NBINSc + 48];

    size_t base = (size_t)n * Lc * 768 + head * 16;
    for (int u = t; u < 2048; u += 512) {
        int key = u >> 2, seg = u & 3;
        const short* src = (seg < 2 ? qh : ql) + base + 256 + (size_t)key * 768 + (seg & 1) * 8;
        *(bf8*)&khl[key][seg * 8] = *(const bf8*)src;
    }
    {
        int u = t & 255, half2 = t >> 8;     // pair u -> keys 2u,2u+1; d-half
        const short* vsh = qh + base + 512 + (size_t)(u * 2) * 768 + half2 * 8;
        const short* vsl = ql + base + 512 + (size_t)(u * 2) * 768 + half2 * 8;
        bf8 A = *(const bf8*)vsh;
        bf8 B = *(const bf8*)(vsh + 768);
        bf8 C = *(const bf8*)vsl;
        bf8 D = *(const bf8*)(vsl + 768);
        unsigned* vthw = (unsigned*)&vth[0][0];   // row stride 268 words
        unsigned* vtlw = (unsigned*)&vtl[0][0];
#pragma unroll
        for (int i = 0; i < 8; ++i) {
            int row = half2 * 8 + i;
            vthw[row * 268 + u] = (unsigned)(unsigned short)A[i] | ((unsigned)(unsigned short)B[i] << 16);
            vtlw[row * 268 + u] = (unsigned)(unsigned short)C[i] | ((unsigned)(unsigned short)D[i] << 16);
        }
    }
    __syncthreads();

    int qg = qt * 128 + w * 16 + lq;             // this lane's q column
    size_t qrow = ((size_t)n * Lc + qg) * 768 + head * 16;
    bf8 B1 = *(const bf8*)(qh + qrow + (lk & 1) * 8);   // [Qh|Qh]
    bf8 B2;
    if (lk < 2) B2 = *(const bf8*)(ql + qrow + lk * 8);  // [Ql|0]
    else {
#pragma unroll
        for (int i = 0; i < 8; ++i) B2[i] = 0;
    }

    f4 acc = (f4){0.f, 0.f, 0.f, 0.f};
    float m = -1e30f, lsum = 0.f;
    int rel0 = lk * 4 - qg;      // rel of s[0] at kt=0; += 16 per tile

    for (int kt = 0; kt < 32; ++kt, rel0 += 16) {
        bf8 A1 = *(const bf8*)&khl[kt * 16 + lq][lk * 8];  // [Kh|Kl]
        f4 s = (f4){0.f, 0.f, 0.f, 0.f};
        __builtin_amdgcn_s_setprio(1);
        s = MFMA(A1, B1, s);      // KhQh + KlQh
        s = MFMA(A1, B2, s);      // KhQl
        __builtin_amdgcn_s_setprio(0);
        if (rel0 >= PMAXLc) {
            s[0] += bR; s[1] += bR; s[2] += bR; s[3] += bR;
        } else if (rel0 + 3 <= -PMAXLc) {
            s[0] += bL; s[1] += bL; s[2] += bL; s[3] += bL;
        } else {
#pragma unroll
            for (int r = 0; r < 4; ++r) {
                int rel = rel0 + r;
                rel = rel < -PMAXLc ? -PMAXLc : (rel > PMAXLc ? PMAXLc : rel);
                s[r] += biasr[rel + PMAXLc];
            }
        }
        float mt = fmaxf(fmaxf(s[0], s[1]), fmaxf(s[2], s[3]));
        mt = fmaxf(mt, __shfl_xor(mt, 16));
        mt = fmaxf(mt, __shfl_xor(mt, 32));
        if (__any(mt > m + 8.0f)) {
            float mn = fmaxf(m, mt);
            float alpha = __expf(m - mn);
            m = mn;
            lsum *= alpha;
#pragma unroll
            for (int r = 0; r < 4; ++r) acc[r] *= __shfl(alpha, lk * 4 + r);
        }
        f4 p;
#pragma unroll
        for (int r = 0; r < 4; ++r) p[r] = __expf(s[r] - m);
        lsum += p[0] + p[1] + p[2] + p[3];
        int src0 = (lk & 1) * 32 + lq;
        int src1 = src0 + 16;
        float g[8];
#pragma unroll
        for (int jj = 0; jj < 4; ++jj) {
            g[jj]     = __shfl(p[jj], src0);
            g[jj + 4] = __shfl(p[jj], src1);
        }
        bf8 PA;
        if (lk < 2) {
#pragma unroll
            for (int jj = 0; jj < 8; ++jj)
                PA[jj] = (short)(__float_as_uint(g[jj]) >> 16);
        } else {
#pragma unroll
            for (int jj = 0; jj < 8; ++jj) {
                unsigned hu = __float_as_uint(g[jj]) & 0xFFFF0000u;
                PA[jj] = (short)(__float_as_uint(g[jj] - __uint_as_float(hu)) >> 16);
            }
        }
        bf8 VB1 = *(const bf8*)&vth[lq][kt * 16 + (lk & 1) * 8];  // [Vh|Vh]
        bf8 VB2;
        if (lk < 2) VB2 = *(const bf8*)&vtl[lq][kt * 16 + lk * 8];  // [Vl|0]
        else {
#pragma unroll
            for (int i = 0; i < 8; ++i) VB2[i] = 0;
        }
        __builtin_amdgcn_s_setprio(1);
        acc = MFMA(PA, VB1, acc);   // PhVh + PlVh
        acc = MFMA(PA, VB2, acc);   // PhVl
        __builtin_amdgcn_s_setprio(0);
    }

    float lred = lsum + __shfl_xor(lsum, 16);
    lred += __shfl_xor(lred, 32);
    float inv = 1.0f / lred;
#pragma unroll
    for (int r = 0; r < 4; ++r) {
        float iq = __shfl(inv, lk * 4 + r);
        float y = acc[r] * iq;
        int qo = qt * 128 + w * 16 + lk * 4 + r;
        size_t oi = ((size_t)n * Lc + qo) * DMc + head * 16 + lq;
        unsigned hu = __float_as_uint(y) & 0xFFFF0000u;
        ohi[oi] = (short)(hu >> 16);
        olo[oi] = (short)(__float_as_uint(y - __uint_as_float(hu)) >> 16);
    }
}

// ---------------------------------------------------------------------------
// LN over h + s2a + s2b + sbias (split-K partials summed here)
__global__ __launch_bounds__(256) void k_ln(const float* __restrict__ s2a,
                                            const float* __restrict__ s2b,
                                            const float* __restrict__ sbias,
                                            const float* __restrict__ g,
                                            const float* __restrict__ bta,
                                            float* __restrict__ h,
                                            short* __restrict__ umhi,
                                            short* __restrict__ umlo) {
    int tile = blockIdx.x;
    int t = threadIdx.x;
    int tok = t >> 4, j = t & 15;
    size_t gtok = (size_t)tile * 16 + tok;
    float sum = 0.f, ssq = 0.f;
    float vals[16];
#pragma unroll
    for (int d0 = 0; d0 < 16; ++d0) {
        int d = j + d0 * 16;
        float vv = h[gtok * EMBEDc + d] + s2a[gtok * EMBEDc + d]
                 + s2b[gtok * EMBEDc + d] + sbias[d];
        vals[d0] = vv;
        sum += vv;
        ssq += vv * vv;
    }
#pragma unroll
    for (int off = 8; off; off >>= 1) {
        sum += __shfl_xor(sum, off, 16);
        ssq += __shfl_xor(ssq, off, 16);
    }
    float mean = sum * (1.f / EMBEDc);
    float var = ssq * (1.f / EMBEDc) - mean * mean;
    float inv = rsqrtf(var + 1e-5f);
#pragma unroll
    for (int d0 = 0; d0 < 16; ++d0) {
        int d = j + d0 * 16;
        float y = (vals[d0] - mean) * inv * g[d] + bta[d];
        h[gtok * EMBEDc + d] = y;
        short hv = f2bf(y);
        umhi[gtok * UMDIM + d] = hv;
        umlo[gtok * UMDIM + d] = f2bf(y - bf2f(hv));
    }
}

// ---------------------------------------------------------------------------
__global__ __launch_bounds__(256) void k_r(const short* __restrict__ fh,
                                           const short* __restrict__ fl,
                                           const float* __restrict__ w2,
                                           const float* __restrict__ b2,
                                           float* __restrict__ r) {
    __shared__ float w[3][EMBEDc];
    int t = threadIdx.x;
    for (int u = t; u < 3 * EMBEDc; u += 256) w[u >> 8][u & 255] = w2[u];
    __syncthreads();
    int tok = blockIdx.x * 64 + (t >> 2), o = t & 3;
    if (o < 3) {
        const short* ph = fh + (size_t)tok * EMBEDc;
        const short* pl = fl + (size_t)tok * EMBEDc;
        float s = b2[o];
        for (int c8 = 0; c8 < EMBEDc / 8; ++c8) {
            bf8 vh = *(const bf8*)(ph + c8 * 8);
            bf8 vl = *(const bf8*)(pl + c8 * 8);
#pragma unroll
            for (int j = 0; j < 8; ++j)
                s += (bf2f(vh[j]) + bf2f(vl[j])) * w[o][c8 * 8 + j];
        }
        r[(size_t)tok * 3 + o] = s;
    }
}

// ---------------------------------------------------------------------------
__global__ __launch_bounds__(256) void k_dmap(const float* __restrict__ r,
                                              float* __restrict__ d) {
    int b = blockIdx.x;
    int n = b / Lc;
    float xi = r[(size_t)b * 3], yi = r[(size_t)b * 3 + 1], zi = r[(size_t)b * 3 + 2];
    const float* rn = r + (size_t)n * Lc * 3;
    for (int j = threadIdx.x; j < Lc; j += 256) {
        float dx = xi - rn[j * 3];
        float dy = yi - rn[j * 3 + 1];
        float dz = zi - rn[j * 3 + 2];
        d[(size_t)b * Lc + j] = sqrtf(dx * dx + dy * dy + dz * dz + 1e-12f);
    }
}

// ---------------------------------------------------------------------------
extern "C" void kernel_launch(void* const* d_in, const int* in_sizes, int n_in,
                              void* d_out, int out_size, void* d_ws, size_t ws_size,
                              hipStream_t stream) {
    const float* z       = (const float*)d_in[0];
    const float* x       = (const float*)d_in[1];
    const float* pos_emb = (const float*)d_in[2];
    const float* aa_emb  = (const float*)d_in[3];
    const float* ex_w1   = (const float*)d_in[4];
    const float* ex_b1   = (const float*)d_in[5];
    const float* ex_w2   = (const float*)d_in[6];
    const float* ex_b2   = (const float*)d_in[7];
    const float* Wq      = (const float*)d_in[8];
    const float* Wk      = (const float*)d_in[9];
    const float* Wv      = (const float*)d_in[10];
    const float* Wo      = (const float*)d_in[11];
    const float* bo      = (const float*)d_in[12];
    const float* W2d     = (const float*)d_in[13];
    const float* b2d     = (const float*)d_in[14];
    const float* Wf1     = (const float*)d_in[15];
    const float* bf1     = (const float*)d_in[16];
    const float* Wf2     = (const float*)d_in[17];
    const float* bf2     = (const float*)d_in[18];
    const float* ln1_g   = (const float*)d_in[19];
    const float* ln1_b   = (const float*)d_in[20];
    const float* ln2_g   = (const float*)d_in[21];
    const float* ln2_b   = (const float*)d_in[22];
    const float* o_w1    = (const float*)d_in[23];
    const float* o_b1    = (const float*)d_in[24];
    const float* o_w2    = (const float*)d_in[25];
    const float* o_b2    = (const float*)d_in[26];

    float* h    = (float*)d_ws;                    // 4096*256
    float* s2a  = h + (size_t)NTOK * EMBEDc;
    float* s2b  = s2a + (size_t)NTOK * EMBEDc;
    float* bbuf = s2b + (size_t)NTOK * EMBEDc;     // pad 8192
    float* r    = bbuf + 8192;                     // pad 16384
    short* qkvh = (short*)(r + 16384);             // 4096*768
    short* qkvl = qkvh + (size_t)NTOK * 768;
    short* um_hi = qkvl + (size_t)NTOK * 768;      // 4096*288
    short* um_lo = um_hi + (size_t)NTOK * UMDIM;
    short* o_hi  = um_lo + (size_t)NTOK * UMDIM;   // 4096*256
    short* o_lo  = o_hi + (size_t)NTOK * EMBEDc;
    short* f1_hi = o_lo + (size_t)NTOK * EMBEDc;   // 4096*1024
    short* f1_lo = f1_hi + (size_t)NTOK * DFFc;
    short* wqkv_hi = f1_lo + (size_t)NTOK * DFFc;  // 6*768*256
    short* wqkv_lo = wqkv_hi + (size_t)NLc * 768 * EMBEDc;
    short* wo_hi   = wqkv_lo + (size_t)NLc * 768 * EMBEDc;   // 6*256*256
    short* wo_lo   = wo_hi + (size_t)NLc * EMBEDc * DMc;
    short* wf1_hi  = wo_lo + (size_t)NLc * EMBEDc * DMc;     // 6*1024*288
    short* wf1_lo  = wf1_hi + (size_t)NLc * DFFc * UMDIM;
    short* wf2_hi  = wf1_lo + (size_t)NLc * DFFc * UMDIM;    // 6*256*1024
    short* wf2_lo  = wf2_hi + (size_t)NLc * EMBEDc * DFFc;
    short* wex1_hi = wf2_lo + (size_t)NLc * EMBEDc * DFFc;   // 256*64
    short* wex1_lo = wex1_hi + EMBEDc * NZc;
    short* wex2_hi = wex1_lo + EMBEDc * NZc;                 // 256*256
    short* wex2_lo = wex2_hi + EMBEDc * EMBEDc;
    short* wo1_hi  = wex2_lo + EMBEDc * EMBEDc;              // 256*256
    short* wo1_lo  = wo1_hi + EMBEDc * EMBEDc;
    // zt aliases the o buffer (only used in preamble, before k_attn writes o)
    short* zt_hi = o_hi;
    short* zt_lo = o_lo;

    k_cvt_all<<<1024, 256, 0, stream>>>(Wq, Wk, Wv, Wo, Wf1, Wf2, ex_w1, ex_w2, o_w1,
                                        wqkv_hi, wqkv_lo, wo_hi, wo_lo,
                                        wf1_hi, wf1_lo, wf2_hi, wf2_lo,
                                        wex1_hi, wex1_lo, wex2_hi, wex2_lo,
                                        wo1_hi, wo1_lo);

    k_biasbins<<<(NLc * NHc * NBINSc + 255) / 256, 256, 0, stream>>>(pos_emb, W2d, b2d, bbuf);
    k_eaa<<<NTOK / 256, 256, 0, stream>>>(x, aa_emb, um_hi, um_lo);

    // embed: zt -> relu GEMM -> GEMM (fp32 h + bf16 um)
    k_zt<<<NTOK / 256, 256, 0, stream>>>(z, zt_hi, zt_lo);
    k_gemm3<1, 1, 0><<<256, 256, 0, stream>>>(
        zt_hi, zt_lo, NZc, wex1_hi, wex1_lo, NZc, NZc,
        nullptr, 0, f1_hi, f1_lo, EMBEDc, ex_b1, 4, 8);
    k_gemm3<3, 1, 0><<<256, 256, 0, stream>>>(
        f1_hi, f1_lo, EMBEDc, wex2_hi, wex2_lo, EMBEDc, EMBEDc,
        h, EMBEDc, um_hi, um_lo, UMDIM, ex_b2, 4, 8);

    for (int l = 0; l < NLc; ++l) {
        k_gemm3<2, 2, 0><<<384, 256, 0, stream>>>(
            um_hi, um_lo, UMDIM,
            wqkv_hi + (size_t)l * 768 * EMBEDc, wqkv_lo + (size_t)l * 768 * EMBEDc, EMBEDc,
            EMBEDc, nullptr, 0, qkvh, qkvl, 768, nullptr, 12, 4);
        k_attn<<<NB * NHc * 4, 512, 0, stream>>>(qkvh, qkvl, bbuf + (size_t)l * NHc * NBINSc, o_hi, o_lo);
        k_gemm3<0, 1, 8><<<512, 256, 0, stream>>>(
            o_hi, o_lo, EMBEDc,
            wo_hi + (size_t)l * EMBEDc * DMc, wo_lo + (size_t)l * EMBEDc * DMc, DMc,
            128, s2a, EMBEDc, nullptr, nullptr, 0, nullptr, 4, 8);
        k_ln<<<NTOK / 16, 256, 0, stream>>>(s2a, s2b, bo + (size_t)l * EMBEDc,
                                            ln1_g + (size_t)l * EMBEDc, ln1_b + (size_t)l * EMBEDc,
                                            h, um_hi, um_lo);
        k_gemm3<1, 2, 0><<<512, 256, 0, stream>>>(
            um_hi, um_lo, UMDIM,
            wf1_hi + (size_t)l * DFFc * UMDIM, wf1_lo + (size_t)l * DFFc * UMDIM, UMDIM,
            UMDIM, nullptr, 0, f1_hi, f1_lo, DFFc, bf1 + (size_t)l * DFFc, 16, 4);
        k_gemm3<0, 1, 8><<<512, 256, 0, stream>>>(
            f1_hi, f1_lo, DFFc,
            wf2_hi + (size_t)l * EMBEDc * DFFc, wf2_lo + (size_t)l * EMBEDc * DFFc, DFFc,
            512, s2a, EMBEDc, nullptr, nullptr, 0, nullptr, 4, 8);
        k_ln<<<NTOK / 16, 256, 0, stream>>>(s2a, s2b, bf2 + (size_t)l * EMBEDc,
                                            ln2_g + (size_t)l * EMBEDc, ln2_b + (size_t)l * EMBEDc,
                                            h, um_hi, um_lo);
    }

    // final: f = relu(um @ o_w1^T + o_b1) (um cols 0..255 hold h in bf16)
    k_gemm3<1, 1, 0><<<256, 256, 0, stream>>>(
        um_hi, um_lo, UMDIM, wo1_hi, wo1_lo, EMBEDc, EMBEDc,
        nullptr, 0, f1_hi, f1_lo, EMBEDc, o_b1, 4, 8);
    k_r<<<NTOK / 64, 256, 0, stream>>>(f1_hi, f1_lo, o_w2, o_b2, r);
    k_dmap<<<NB * Lc, 256, 0, stream>>>(r, (float*)d_out);
}

// Round 11
// 593.512 us; speedup vs baseline: 9.3016x; 1.0207x over previous
//
#include <hip/hip_runtime.h>
#include <math.h>

#define NZc     64
#define EMBEDc  256
#define DMc     256
#define NHc     16
#define HDc     16
#define DFFc    1024
#define NLc     6
#define E1Dc    32
#define PDIMc   64
#define PMAXLc  24
#define NBINSc  49
#define NB      8
#define Lc      512
#define NTOK    (NB * Lc)        // 4096
#define UMDIM   (EMBEDc + E1Dc)  // 288

typedef __attribute__((ext_vector_type(4))) float f4;
typedef __attribute__((ext_vector_type(8))) short bf8;   // 8 bf16 in 4 VGPRs

#define MFMA(a, b, c) __builtin_amdgcn_mfma_f32_16x16x32_bf16((a), (b), (c), 0, 0, 0)

__device__ __forceinline__ short f2bf(float f) {
    unsigned u = __float_as_uint(f);
    u += 0x7FFFu + ((u >> 16) & 1u);   // round-to-nearest-even
    return (short)(u >> 16);
}
__device__ __forceinline__ float bf2f(short s) {
    return __uint_as_float(((unsigned)(unsigned short)s) << 16);
}

// ---------------------------------------------------------------------------
// preamble: all weight conversions + bias bins + e_aa + z transpose, fused.
__global__ void k_pre(const float* __restrict__ Wq, const float* __restrict__ Wk,
                      const float* __restrict__ Wv, const float* __restrict__ Wo,
                      const float* __restrict__ Wf1, const float* __restrict__ Wf2,
                      const float* __restrict__ exw1, const float* __restrict__ exw2,
                      const float* __restrict__ ow1,
                      const float* __restrict__ pos_emb, const float* __restrict__ W2d,
                      const float* __restrict__ b2d, const float* __restrict__ x,
                      const float* __restrict__ aa_emb, const float* __restrict__ z,
                      short* __restrict__ wqkv_hi, short* __restrict__ wqkv_lo,
                      short* __restrict__ wo_hi, short* __restrict__ wo_lo,
                      short* __restrict__ wf1_hi, short* __restrict__ wf1_lo,
                      short* __restrict__ wf2_hi, short* __restrict__ wf2_lo,
                      short* __restrict__ wex1_hi, short* __restrict__ wex1_lo,
                      short* __restrict__ wex2_hi, short* __restrict__ wex2_lo,
                      short* __restrict__ wo1_hi, short* __restrict__ wo1_lo,
                      float* __restrict__ bb,
                      short* __restrict__ umhi, short* __restrict__ umlo,
                      short* __restrict__ zth, short* __restrict__ ztl) {
    int stride = gridDim.x * blockDim.x;
    int tid = blockIdx.x * blockDim.x + threadIdx.x;
#define CVT(src, hi, lo, per_layer, dstride, doff, scale, total)               \
    for (int i = tid; i < (total); i += stride) {                              \
        int ll = i / (per_layer), rels = i - ll * (per_layer);                 \
        size_t di = (size_t)ll * (dstride) + (doff) + rels;                    \
        float v = src[i] * (scale);                                            \
        short hh = f2bf(v);                                                    \
        hi[di] = hh;                                                           \
        lo[di] = f2bf(v - bf2f(hh));                                           \
    }
    CVT(Wq,  wqkv_hi, wqkv_lo, 65536, 196608, 0,      0.0625f, 393216);
    CVT(Wk,  wqkv_hi, wqkv_lo, 65536, 196608, 65536,  1.f,     393216);
    CVT(Wv,  wqkv_hi, wqkv_lo, 65536, 196608, 131072, 1.f,     393216);
    CVT(Wo,  wo_hi,  wo_lo,  65536,  65536,  0, 1.f, 393216);
    CVT(Wf1, wf1_hi, wf1_lo, 294912, 294912, 0, 1.f, 1769472);
    CVT(Wf2, wf2_hi, wf2_lo, 262144, 262144, 0, 1.f, 1572864);
    CVT(exw1, wex1_hi, wex1_lo, 16384, 16384, 0, 1.f, 16384);
    CVT(exw2, wex2_hi, wex2_lo, 65536, 65536, 0, 1.f, 65536);
    CVT(ow1,  wo1_hi,  wo1_lo,  65536, 65536, 0, 1.f, 65536);
#undef CVT
    // bias bins
    for (int idx = tid; idx < NLc * NHc * NBINSc; idx += stride) {
        int bin = idx % NBINSc;
        int tmp = idx / NBINSc;
        int hh = tmp % NHc, l = tmp / NHc;
        float s = b2d[l * NHc + hh];
        const float* pe = pos_emb + bin * PDIMc;
        const float* w  = W2d + (l * NHc + hh) * PDIMc;
        for (int p = 0; p < PDIMc; ++p) s += pe[p] * w[p];
        bb[idx] = s;
    }
    // e_aa -> um cols 256..287
    for (int tok = tid; tok < NTOK; tok += stride) {
        int n = tok / Lc, l = tok % Lc;
        const float* xp = x + (size_t)n * 20 * Lc + l;
        float best = xp[0];
        int bi = 0;
        for (int c = 1; c < 20; ++c) {
            float v = xp[c * Lc];
            if (v > best) { best = v; bi = c; }
        }
        const float* e = aa_emb + bi * E1Dc;
        for (int c = 0; c < E1Dc; ++c) {
            float v = e[c];
            short h = f2bf(v);
            umhi[(size_t)tok * UMDIM + EMBEDc + c] = h;
            umlo[(size_t)tok * UMDIM + EMBEDc + c] = f2bf(v - bf2f(h));
        }
    }
    // z transpose
    for (int tok = tid; tok < NTOK; tok += stride) {
        int n = tok >> 9, l = tok & 511;
        for (int c = 0; c < NZc; ++c) {
            float v = z[((size_t)n * NZc + c) * Lc + l];
            short hv = f2bf(v);
            zth[(size_t)tok * NZc + c] = hv;
            ztl[(size_t)tok * NZc + c] = f2bf(v - bf2f(hv));
        }
    }
}

// ---------------------------------------------------------------------------
// LDS-staged MFMA GEMM, XCD-swizzled, templated tile height + K-step + optional
// split-K into separate partial buffers (outf + kh*NTOK*EMBEDc).
// Rows padded to BK+8 shorts: stride (BK+8)/2 words % 32 = 4 -> 2-way (free).
template <int EPI, int MF, int SKSHIFT, int BK>
__global__ __launch_bounds__(256) void k_gemm3(
    const short* __restrict__ Ahi, const short* __restrict__ Alo, int lda,
    const short* __restrict__ Bhi, const short* __restrict__ Blo, int ldb,
    int K, float* __restrict__ outf, int ldo, short* __restrict__ ohi,
    short* __restrict__ olo, int ldh, const float* __restrict__ bias,
    int gx, int gypx) {
    constexpr int PAD = BK + 8;
    __shared__ __align__(16) short Ah[MF * 64][PAD];
    __shared__ __align__(16) short Al[MF * 64][PAD];
    __shared__ __align__(16) short Bh[64][PAD];
    __shared__ __align__(16) short Bl[64][PAD];

    int bid = blockIdx.x;
    int koff = 0;
    if (SKSHIFT) {
        int kh = bid >> SKSHIFT;
        bid &= (1 << SKSHIFT) - 1;
        koff = kh * K;
        outf += (size_t)kh * NTOK * EMBEDc;
    }
    int xcd = bid & 7, j = bid >> 3;
    int bx = j % gx, by = xcd * gypx + j / gx;

    int t = threadIdx.x;
    int w = t >> 6, l = t & 63, lr = l & 15, lk = l >> 4;
    int m0 = by * (MF * 64);
    int n0 = bx * 64;

    constexpr int TPR = BK / 8;        // threads per staged row
    constexpr int RP  = 256 / TPR;     // rows per staging pass
    constexpr int AP  = MF * 64 / RP;  // passes for A
    constexpr int BP  = 64 / RP;       // passes for B
    int srow = t / TPR, scol = (t % TPR) * 8;

    const short* pa  = Ahi + (size_t)(m0 + srow) * lda + koff + scol;
    const short* pal = Alo + (size_t)(m0 + srow) * lda + koff + scol;
    const short* pb  = Bhi + (size_t)(n0 + srow) * ldb + koff + scol;
    const short* pbl = Blo + (size_t)(n0 + srow) * ldb + koff + scol;

    bf8 ra[AP], rla[AP], rb[BP], rlb[BP];
#pragma unroll
    for (int p = 0; p < AP; ++p) {
        ra[p]  = *(const bf8*)(pa  + (size_t)p * RP * lda);
        rla[p] = *(const bf8*)(pal + (size_t)p * RP * lda);
    }
#pragma unroll
    for (int p = 0; p < BP; ++p) {
        rb[p]  = *(const bf8*)(pb  + (size_t)p * RP * ldb);
        rlb[p] = *(const bf8*)(pbl + (size_t)p * RP * ldb);
    }

    f4 acc[MF][4];
#pragma unroll
    for (int mf = 0; mf < MF; ++mf)
#pragma unroll
        for (int nf = 0; nf < 4; ++nf) acc[mf][nf] = (f4){0.f, 0.f, 0.f, 0.f};

    for (int ks = 0; ks < K; ks += BK) {
        __syncthreads();
#pragma unroll
        for (int p = 0; p < AP; ++p) {
            *(bf8*)&Ah[p * RP + srow][scol] = ra[p];
            *(bf8*)&Al[p * RP + srow][scol] = rla[p];
        }
#pragma unroll
        for (int p = 0; p < BP; ++p) {
            *(bf8*)&Bh[p * RP + srow][scol] = rb[p];
            *(bf8*)&Bl[p * RP + srow][scol] = rlb[p];
        }
        __syncthreads();
        if (ks + BK < K) {
#pragma unroll
            for (int p = 0; p < AP; ++p) {
                ra[p]  = *(const bf8*)(pa  + (size_t)p * RP * lda + ks + BK);
                rla[p] = *(const bf8*)(pal + (size_t)p * RP * lda + ks + BK);
            }
#pragma unroll
            for (int p = 0; p < BP; ++p) {
                rb[p]  = *(const bf8*)(pb  + (size_t)p * RP * ldb + ks + BK);
                rlb[p] = *(const bf8*)(pbl + (size_t)p * RP * ldb + ks + BK);
            }
        }
#pragma unroll
        for (int kc = 0; kc < BK / 32; ++kc) {
            bf8 bhf[4], blf[4];
#pragma unroll
            for (int nf = 0; nf < 4; ++nf) {
                bhf[nf] = *(const bf8*)&Bh[nf * 16 + lr][kc * 32 + lk * 8];
                blf[nf] = *(const bf8*)&Bl[nf * 16 + lr][kc * 32 + lk * 8];
            }
#pragma unroll
            for (int mf = 0; mf < MF; ++mf) {
                bf8 ah = *(const bf8*)&Ah[w * MF * 16 + mf * 16 + lr][kc * 32 + lk * 8];
                bf8 al = *(const bf8*)&Al[w * MF * 16 + mf * 16 + lr][kc * 32 + lk * 8];
#pragma unroll
                for (int nf = 0; nf < 4; ++nf) {
                    acc[mf][nf] = MFMA(ah, bhf[nf], acc[mf][nf]);
                    acc[mf][nf] = MFMA(ah, blf[nf], acc[mf][nf]);
                    acc[mf][nf] = MFMA(al, bhf[nf], acc[mf][nf]);
                }
            }
        }
    }

#pragma unroll
    for (int mf = 0; mf < MF; ++mf) {
#pragma unroll
        for (int nf = 0; nf < 4; ++nf) {
            int n = n0 + nf * 16 + lr;
            int mbase = m0 + w * MF * 16 + mf * 16 + lk * 4;
            if (EPI == 0) {
#pragma unroll
                for (int r = 0; r < 4; ++r)
                    outf[(size_t)(mbase + r) * ldo + n] = acc[mf][nf][r];
            } else if (EPI == 1) {
                float bv = bias[n];
#pragma unroll
                for (int r = 0; r < 4; ++r) {
                    float y = fmaxf(acc[mf][nf][r] + bv, 0.f);
                    short hv = f2bf(y);
                    size_t oi = (size_t)(mbase + r) * ldh + n;
                    ohi[oi] = hv;
                    olo[oi] = f2bf(y - bf2f(hv));
                }
            } else if (EPI == 2) {
#pragma unroll
                for (int r = 0; r < 4; ++r) {
                    float y = acc[mf][nf][r];
                    short hv = f2bf(y);
                    size_t oi = (size_t)(mbase + r) * ldh + n;
                    ohi[oi] = hv;
                    olo[oi] = f2bf(y - bf2f(hv));
                }
            } else {
                float bv = bias[n];
#pragma unroll
                for (int r = 0; r < 4; ++r) {
                    float y = acc[mf][nf][r] + bv;
                    outf[(size_t)(mbase + r) * ldo + n] = y;
                    short hv = f2bf(y);
                    size_t oi = (size_t)(mbase + r) * ldh + n;
                    ohi[oi] = hv;
                    olo[oi] = f2bf(y - bf2f(hv));
                }
            }
        }
    }
}

// ---------------------------------------------------------------------------
// MFMA flash attention: 512 threads, K/V staged in two 256-key halves so
// LDS = 37.6 KB -> 4 blocks/CU = 32 waves/CU (was 2 blocks at 75.7 KB).
__global__ __launch_bounds__(512, 8) void k_attn(const short* __restrict__ qh,
                                                 const short* __restrict__ ql,
                                                 const float* __restrict__ bb,
                                                 short* __restrict__ ohi,
                                                 short* __restrict__ olo) {
    int bx = blockIdx.x;
    int qt = bx >> 7;            // 0..3; blocks sharing (n,head) same XCD
    int head = bx & 15;
    int n = (bx >> 4) & 7;
    int t = threadIdx.x;
    int w = t >> 6, l = t & 63;
    int lq = l & 15, lk = l >> 4;

    __shared__ __align__(16) short khl[256][40];   // [key][hi0-15|lo16-31|pad]
    __shared__ __align__(16) short vth[16][264];   // V^T hi: [d][key 0..255]
    __shared__ __align__(16) short vtl[16][264];   // V^T lo
    __shared__ float biasr[64];

    if (t < NBINSc) biasr[t] = bb[head * NBINSc + t];
    float bL = bb[head * NBINSc];
    float bR = bb[head * NBINSc + 48];

    size_t base = (size_t)n * Lc * 768 + head * 16;

    int qg = qt * 128 + w * 16 + lq;             // this lane's q column
    size_t qrow = ((size_t)n * Lc + qg) * 768 + head * 16;
    bf8 B1 = *(const bf8*)(qh + qrow + (lk & 1) * 8);   // [Qh|Qh]
    bf8 B2;
    if (lk < 2) B2 = *(const bf8*)(ql + qrow + lk * 8);  // [Ql|0]
    else {
#pragma unroll
        for (int i = 0; i < 8; ++i) B2[i] = 0;
    }

    f4 acc = (f4){0.f, 0.f, 0.f, 0.f};
    float m = -1e30f, lsum = 0.f;
    int rel0 = lk * 4 - qg;      // rel of s[0] at global kt=0; += 16 per tile

    for (int half = 0; half < 2; ++half) {
        __syncthreads();          // previous half fully consumed
        // stage K half (256 keys)
        for (int u = t; u < 1024; u += 512) {
            int key = u >> 2, seg = u & 3;
            const short* src = (seg < 2 ? qh : ql) + base + 256
                             + (size_t)(half * 256 + key) * 768 + (seg & 1) * 8;
            *(bf8*)&khl[key][seg * 8] = *(const bf8*)src;
        }
        // stage V half transposed, pair-packed b32 writes (1 item/thread)
        {
            int u = t & 127;             // key pair
            int dhalf = (t >> 7) & 1;    // d 0..7 / 8..15
            int hl = (t >> 8) & 1;       // hi / lo
            int gkey = half * 256 + u * 2;
            const short* vs = (hl ? ql : qh) + base + 512 + (size_t)gkey * 768 + dhalf * 8;
            bf8 A = *(const bf8*)vs;
            bf8 B = *(const bf8*)(vs + 768);
            unsigned* vw = (unsigned*)(hl ? &vtl[0][0] : &vth[0][0]);  // stride 132 words
#pragma unroll
            for (int i = 0; i < 8; ++i)
                vw[(dhalf * 8 + i) * 132 + u] =
                    (unsigned)(unsigned short)A[i] | ((unsigned)(unsigned short)B[i] << 16);
        }
        __syncthreads();

        for (int kt = 0; kt < 16; ++kt, rel0 += 16) {
            bf8 A1 = *(const bf8*)&khl[kt * 16 + lq][lk * 8];  // [Kh|Kl]
            f4 s = (f4){0.f, 0.f, 0.f, 0.f};
            __builtin_amdgcn_s_setprio(1);
            s = MFMA(A1, B1, s);      // KhQh + KlQh
            s = MFMA(A1, B2, s);      // KhQl
            __builtin_amdgcn_s_setprio(0);
            if (rel0 >= PMAXLc) {
                s[0] += bR; s[1] += bR; s[2] += bR; s[3] += bR;
            } else if (rel0 + 3 <= -PMAXLc) {
                s[0] += bL; s[1] += bL; s[2] += bL; s[3] += bL;
            } else {
#pragma unroll
                for (int r = 0; r < 4; ++r) {
                    int rel = rel0 + r;
                    rel = rel < -PMAXLc ? -PMAXLc : (rel > PMAXLc ? PMAXLc : rel);
                    s[r] += biasr[rel + PMAXLc];
                }
            }
            float mt = fmaxf(fmaxf(s[0], s[1]), fmaxf(s[2], s[3]));
            mt = fmaxf(mt, __shfl_xor(mt, 16));
            mt = fmaxf(mt, __shfl_xor(mt, 32));
            if (__any(mt > m + 8.0f)) {
                float mn = fmaxf(m, mt);
                float alpha = __expf(m - mn);
                m = mn;
                lsum *= alpha;
#pragma unroll
                for (int r = 0; r < 4; ++r) acc[r] *= __shfl(alpha, lk * 4 + r);
            }
            f4 p;
#pragma unroll
            for (int r = 0; r < 4; ++r) p[r] = __expf(s[r] - m);
            lsum += p[0] + p[1] + p[2] + p[3];
            int src0 = (lk & 1) * 32 + lq;
            int src1 = src0 + 16;
            float g[8];
#pragma unroll
            for (int jj = 0; jj < 4; ++jj) {
                g[jj]     = __shfl(p[jj], src0);
                g[jj + 4] = __shfl(p[jj], src1);
            }
            bf8 PA;
            if (lk < 2) {
#pragma unroll
                for (int jj = 0; jj < 8; ++jj)
                    PA[jj] = (short)(__float_as_uint(g[jj]) >> 16);
            } else {
#pragma unroll
                for (int jj = 0; jj < 8; ++jj) {
                    unsigned hu = __float_as_uint(g[jj]) & 0xFFFF0000u;
                    PA[jj] = (short)(__float_as_uint(g[jj] - __uint_as_float(hu)) >> 16);
                }
            }
            bf8 VB1 = *(const bf8*)&vth[lq][kt * 16 + (lk & 1) * 8];  // [Vh|Vh]
            bf8 VB2;
            if (lk < 2) VB2 = *(const bf8*)&vtl[lq][kt * 16 + lk * 8];  // [Vl|0]
            else {
#pragma unroll
                for (int i = 0; i < 8; ++i) VB2[i] = 0;
            }
            __builtin_amdgcn_s_setprio(1);
            acc = MFMA(PA, VB1, acc);   // PhVh + PlVh
            acc = MFMA(PA, VB2, acc);   // PhVl
            __builtin_amdgcn_s_setprio(0);
        }
    }

    float lred = lsum + __shfl_xor(lsum, 16);
    lred += __shfl_xor(lred, 32);
    float inv = 1.0f / lred;
#pragma unroll
    for (int r = 0; r < 4; ++r) {
        float iq = __shfl(inv, lk * 4 + r);
        float y = acc[r] * iq;
        int qo = qt * 128 + w * 16 + lk * 4 + r;
        size_t oi = ((size_t)n * Lc + qo) * DMc + head * 16 + lq;
        unsigned hu = __float_as_uint(y) & 0xFFFF0000u;
        ohi[oi] = (short)(hu >> 16);
        olo[oi] = (short)(__float_as_uint(y - __uint_as_float(hu)) >> 16);
    }
}

// ---------------------------------------------------------------------------
// LN over h + s2a + s2b + sbias (split-K partials summed here)
__global__ __launch_bounds__(256) void k_ln(const float* __restrict__ s2a,
                                            const float* __restrict__ s2b,
                                            const float* __restrict__ sbias,
                                            const float* __restrict__ g,
                                            const float* __restrict__ bta,
                                            float* __restrict__ h,
                                            short* __restrict__ umhi,
                                            short* __restrict__ umlo) {
    int tile = blockIdx.x;
    int t = threadIdx.x;
    int tok = t >> 4, j = t & 15;
    size_t gtok = (size_t)tile * 16 + tok;
    float sum = 0.f, ssq = 0.f;
    float vals[16];
#pragma unroll
    for (int d0 = 0; d0 < 16; ++d0) {
        int d = j + d0 * 16;
        float vv = h[gtok * EMBEDc + d] + s2a[gtok * EMBEDc + d]
                 + s2b[gtok * EMBEDc + d] + sbias[d];
        vals[d0] = vv;
        sum += vv;
        ssq += vv * vv;
    }
#pragma unroll
    for (int off = 8; off; off >>= 1) {
        sum += __shfl_xor(sum, off, 16);
        ssq += __shfl_xor(ssq, off, 16);
    }
    float mean = sum * (1.f / EMBEDc);
    float var = ssq * (1.f / EMBEDc) - mean * mean;
    float inv = rsqrtf(var + 1e-5f);
#pragma unroll
    for (int d0 = 0; d0 < 16; ++d0) {
        int d = j + d0 * 16;
        float y = (vals[d0] - mean) * inv * g[d] + bta[d];
        h[gtok * EMBEDc + d] = y;
        short hv = f2bf(y);
        umhi[gtok * UMDIM + d] = hv;
        umlo[gtok * UMDIM + d] = f2bf(y - bf2f(hv));
    }
}

// ---------------------------------------------------------------------------
__global__ __launch_bounds__(256) void k_r(const short* __restrict__ fh,
                                           const short* __restrict__ fl,
                                           const float* __restrict__ w2,
                                           const float* __restrict__ b2,
                                           float* __restrict__ r) {
    __shared__ float w[3][EMBEDc];
    int t = threadIdx.x;
    for (int u = t; u < 3 * EMBEDc; u += 256) w[u >> 8][u & 255] = w2[u];
    __syncthreads();
    int tok = blockIdx.x * 64 + (t >> 2), o = t & 3;
    if (o < 3) {
        const short* ph = fh + (size_t)tok * EMBEDc;
        const short* pl = fl + (size_t)tok * EMBEDc;
        float s = b2[o];
        for (int c8 = 0; c8 < EMBEDc / 8; ++c8) {
            bf8 vh = *(const bf8*)(ph + c8 * 8);
            bf8 vl = *(const bf8*)(pl + c8 * 8);
#pragma unroll
            for (int j = 0; j < 8; ++j)
                s += (bf2f(vh[j]) + bf2f(vl[j])) * w[o][c8 * 8 + j];
        }
        r[(size_t)tok * 3 + o] = s;
    }
}

// ---------------------------------------------------------------------------
__global__ __launch_bounds__(256) void k_dmap(const float* __restrict__ r,
                                              float* __restrict__ d) {
    int b = blockIdx.x;
    int n = b / Lc;
    float xi = r[(size_t)b * 3], yi = r[(size_t)b * 3 + 1], zi = r[(size_t)b * 3 + 2];
    const float* rn = r + (size_t)n * Lc * 3;
    for (int j = threadIdx.x; j < Lc; j += 256) {
        float dx = xi - rn[j * 3];
        float dy = yi - rn[j * 3 + 1];
        float dz = zi - rn[j * 3 + 2];
        d[(size_t)b * Lc + j] = sqrtf(dx * dx + dy * dy + dz * dz + 1e-12f);
    }
}

// ---------------------------------------------------------------------------
extern "C" void kernel_launch(void* const* d_in, const int* in_sizes, int n_in,
                              void* d_out, int out_size, void* d_ws, size_t ws_size,
                              hipStream_t stream) {
    const float* z       = (const float*)d_in[0];
    const float* x       = (const float*)d_in[1];
    const float* pos_emb = (const float*)d_in[2];
    const float* aa_emb  = (const float*)d_in[3];
    const float* ex_w1   = (const float*)d_in[4];
    const float* ex_b1   = (const float*)d_in[5];
    const float* ex_w2   = (const float*)d_in[6];
    const float* ex_b2   = (const float*)d_in[7];
    const float* Wq      = (const float*)d_in[8];
    const float* Wk      = (const float*)d_in[9];
    const float* Wv      = (const float*)d_in[10];
    const float* Wo      = (const float*)d_in[11];
    const float* bo      = (const float*)d_in[12];
    const float* W2d     = (const float*)d_in[13];
    const float* b2d     = (const float*)d_in[14];
    const float* Wf1     = (const float*)d_in[15];
    const float* bf1     = (const float*)d_in[16];
    const float* Wf2     = (const float*)d_in[17];
    const float* bf2     = (const float*)d_in[18];
    const float* ln1_g   = (const float*)d_in[19];
    const float* ln1_b   = (const float*)d_in[20];
    const float* ln2_g   = (const float*)d_in[21];
    const float* ln2_b   = (const float*)d_in[22];
    const float* o_w1    = (const float*)d_in[23];
    const float* o_b1    = (const float*)d_in[24];
    const float* o_w2    = (const float*)d_in[25];
    const float* o_b2    = (const float*)d_in[26];

    float* h    = (float*)d_ws;                    // 4096*256
    float* s2a  = h + (size_t)NTOK * EMBEDc;
    float* s2b  = s2a + (size_t)NTOK * EMBEDc;
    float* bbuf = s2b + (size_t)NTOK * EMBEDc;     // pad 8192
    float* r    = bbuf + 8192;                     // pad 16384
    short* qkvh = (short*)(r + 16384);             // 4096*768
    short* qkvl = qkvh + (size_t)NTOK * 768;
    short* um_hi = qkvl + (size_t)NTOK * 768;      // 4096*288
    short* um_lo = um_hi + (size_t)NTOK * UMDIM;
    short* o_hi  = um_lo + (size_t)NTOK * UMDIM;   // 4096*256
    short* o_lo  = o_hi + (size_t)NTOK * EMBEDc;
    short* f1_hi = o_lo + (size_t)NTOK * EMBEDc;   // 4096*1024
    short* f1_lo = f1_hi + (size_t)NTOK * DFFc;
    short* wqkv_hi = f1_lo + (size_t)NTOK * DFFc;  // 6*768*256
    short* wqkv_lo = wqkv_hi + (size_t)NLc * 768 * EMBEDc;
    short* wo_hi   = wqkv_lo + (size_t)NLc * 768 * EMBEDc;   // 6*256*256
    short* wo_lo   = wo_hi + (size_t)NLc * EMBEDc * DMc;
    short* wf1_hi  = wo_lo + (size_t)NLc * EMBEDc * DMc;     // 6*1024*288
    short* wf1_lo  = wf1_hi + (size_t)NLc * DFFc * UMDIM;
    short* wf2_hi  = wf1_lo + (size_t)NLc * DFFc * UMDIM;    // 6*256*1024
    short* wf2_lo  = wf2_hi + (size_t)NLc * EMBEDc * DFFc;
    short* wex1_hi = wf2_lo + (size_t)NLc * EMBEDc * DFFc;   // 256*64
    short* wex1_lo = wex1_hi + EMBEDc * NZc;
    short* wex2_hi = wex1_lo + EMBEDc * NZc;                 // 256*256
    short* wex2_lo = wex2_hi + EMBEDc * EMBEDc;
    short* wo1_hi  = wex2_lo + EMBEDc * EMBEDc;              // 256*256
    short* wo1_lo  = wo1_hi + EMBEDc * EMBEDc;
    // zt aliases the o buffer (only used in preamble, before k_attn writes o)
    short* zt_hi = o_hi;
    short* zt_lo = o_lo;

    k_pre<<<1024, 256, 0, stream>>>(Wq, Wk, Wv, Wo, Wf1, Wf2, ex_w1, ex_w2, o_w1,
                                    pos_emb, W2d, b2d, x, aa_emb, z,
                                    wqkv_hi, wqkv_lo, wo_hi, wo_lo,
                                    wf1_hi, wf1_lo, wf2_hi, wf2_lo,
                                    wex1_hi, wex1_lo, wex2_hi, wex2_lo,
                                    wo1_hi, wo1_lo, bbuf, um_hi, um_lo,
                                    zt_hi, zt_lo);

    // embed: relu GEMM -> GEMM (fp32 h + bf16 um)
    k_gemm3<1, 1, 0, 64><<<256, 256, 0, stream>>>(
        zt_hi, zt_lo, NZc, wex1_hi, wex1_lo, NZc, NZc,
        nullptr, 0, f1_hi, f1_lo, EMBEDc, ex_b1, 4, 8);
    k_gemm3<3, 1, 0, 64><<<256, 256, 0, stream>>>(
        f1_hi, f1_lo, EMBEDc, wex2_hi, wex2_lo, EMBEDc, EMBEDc,
        h, EMBEDc, um_hi, um_lo, UMDIM, ex_b2, 4, 8);

    for (int l = 0; l < NLc; ++l) {
        k_gemm3<2, 2, 0, 64><<<384, 256, 0, stream>>>(
            um_hi, um_lo, UMDIM,
            wqkv_hi + (size_t)l * 768 * EMBEDc, wqkv_lo + (size_t)l * 768 * EMBEDc, EMBEDc,
            EMBEDc, nullptr, 0, qkvh, qkvl, 768, nullptr, 12, 4);
        k_attn<<<NB * NHc * 4, 512, 0, stream>>>(qkvh, qkvl, bbuf + (size_t)l * NHc * NBINSc, o_hi, o_lo);
        k_gemm3<0, 1, 8, 64><<<512, 256, 0, stream>>>(
            o_hi, o_lo, EMBEDc,
            wo_hi + (size_t)l * EMBEDc * DMc, wo_lo + (size_t)l * EMBEDc * DMc, DMc,
            128, s2a, EMBEDc, nullptr, nullptr, 0, nullptr, 4, 8);
        k_ln<<<NTOK / 16, 256, 0, stream>>>(s2a, s2b, bo + (size_t)l * EMBEDc,
                                            ln1_g + (size_t)l * EMBEDc, ln1_b + (size_t)l * EMBEDc,
                                            h, um_hi, um_lo);
        k_gemm3<1, 2, 0, 32><<<512, 256, 0, stream>>>(
            um_hi, um_lo, UMDIM,
            wf1_hi + (size_t)l * DFFc * UMDIM, wf1_lo + (size_t)l * DFFc * UMDIM, UMDIM,
            UMDIM, nullptr, 0, f1_hi, f1_lo, DFFc, bf1 + (size_t)l * DFFc, 16, 4);
        k_gemm3<0, 1, 8, 64><<<512, 256, 0, stream>>>(
            f1_hi, f1_lo, DFFc,
            wf2_hi + (size_t)l * EMBEDc * DFFc, wf2_lo + (size_t)l * EMBEDc * DFFc, DFFc,
            512, s2a, EMBEDc, nullptr, nullptr, 0, nullptr, 4, 8);
        k_ln<<<NTOK / 16, 256, 0, stream>>>(s2a, s2b, bf2 + (size_t)l * EMBEDc,
                                            ln2_g + (size_t)l * EMBEDc, ln2_b + (size_t)l * EMBEDc,
                                            h, um_hi, um_lo);
    }

    // final: f = relu(um @ o_w1^T + o_b1) (um cols 0..255 hold h in bf16)
    k_gemm3<1, 1, 0, 64><<<256, 256, 0, stream>>>(
        um_hi, um_lo, UMDIM, wo1_hi, wo1_lo, EMBEDc, EMBEDc,
        nullptr, 0, f1_hi, f1_lo, EMBEDc, o_b1, 4, 8);
    k_r<<<NTOK / 64, 256, 0, stream>>>(f1_hi, f1_lo, o_w2, o_b2, r);
    k_dmap<<<NB * Lc, 256, 0, stream>>>(r, (float*)d_out);
}

// Round 12
// 579.727 us; speedup vs baseline: 9.5228x; 1.0238x over previous
//
#include <hip/hip_runtime.h>
#include <math.h>

#define NZc     64
#define EMBEDc  256
#define DMc     256
#define NHc     16
#define HDc     16
#define DFFc    1024
#define NLc     6
#define E1Dc    32
#define PDIMc   64
#define PMAXLc  24
#define NBINSc  49
#define NB      8
#define Lc      512
#define NTOK    (NB * Lc)        // 4096
#define UMDIM   (EMBEDc + E1Dc)  // 288

typedef __attribute__((ext_vector_type(4))) float f4;
typedef __attribute__((ext_vector_type(8))) short bf8;   // 8 bf16 in 4 VGPRs

#define MFMA(a, b, c) __builtin_amdgcn_mfma_f32_16x16x32_bf16((a), (b), (c), 0, 0, 0)

__device__ __forceinline__ short f2bf(float f) {
    unsigned u = __float_as_uint(f);
    u += 0x7FFFu + ((u >> 16) & 1u);   // round-to-nearest-even
    return (short)(u >> 16);
}
__device__ __forceinline__ float bf2f(short s) {
    return __uint_as_float(((unsigned)(unsigned short)s) << 16);
}

// ---------------------------------------------------------------------------
// preamble: weight conversions (x8 vectorized) + bias bins + e_aa + z^T.
__global__ void k_pre(const float* __restrict__ Wq, const float* __restrict__ Wk,
                      const float* __restrict__ Wv, const float* __restrict__ Wo,
                      const float* __restrict__ Wf1, const float* __restrict__ Wf2,
                      const float* __restrict__ exw1, const float* __restrict__ exw2,
                      const float* __restrict__ ow1,
                      const float* __restrict__ pos_emb, const float* __restrict__ W2d,
                      const float* __restrict__ b2d, const float* __restrict__ x,
                      const float* __restrict__ aa_emb, const float* __restrict__ z,
                      short* __restrict__ wqkv_hi, short* __restrict__ wqkv_lo,
                      short* __restrict__ wo_hi, short* __restrict__ wo_lo,
                      short* __restrict__ wf1_hi, short* __restrict__ wf1_lo,
                      short* __restrict__ wf2_hi, short* __restrict__ wf2_lo,
                      short* __restrict__ wex1_hi, short* __restrict__ wex1_lo,
                      short* __restrict__ wex2_hi, short* __restrict__ wex2_lo,
                      short* __restrict__ wo1_hi, short* __restrict__ wo1_lo,
                      float* __restrict__ bb,
                      short* __restrict__ umhi, short* __restrict__ umlo,
                      short* __restrict__ zth, short* __restrict__ ztl) {
    int stride = gridDim.x * blockDim.x;
    int tid = blockIdx.x * blockDim.x + threadIdx.x;
    // x8-vectorized convert: all totals/strides are multiples of 8 and layer
    // boundaries are 8-aligned, so an 8-block never straddles layers.
#define CVT(src, hi, lo, per_layer, dstride, doff, scale, total)               \
    for (int i = tid; i < (total) / 8; i += stride) {                          \
        int ib = i * 8;                                                        \
        int ll = ib / (per_layer), rels = ib - ll * (per_layer);               \
        size_t di = (size_t)ll * (dstride) + (doff) + rels;                    \
        f4 v0 = *(const f4*)(src + ib);                                        \
        f4 v1 = *(const f4*)(src + ib + 4);                                    \
        bf8 hv, lv;                                                            \
        _Pragma("unroll")                                                      \
        for (int q = 0; q < 4; ++q) {                                          \
            float v = v0[q] * (scale);                                         \
            short hh = f2bf(v);                                                \
            hv[q] = hh;                                                        \
            lv[q] = f2bf(v - bf2f(hh));                                        \
        }                                                                      \
        _Pragma("unroll")                                                      \
        for (int q = 0; q < 4; ++q) {                                          \
            float v = v1[q] * (scale);                                         \
            short hh = f2bf(v);                                                \
            hv[q + 4] = hh;                                                    \
            lv[q + 4] = f2bf(v - bf2f(hh));                                    \
        }                                                                      \
        *(bf8*)(hi + di) = hv;                                                 \
        *(bf8*)(lo + di) = lv;                                                 \
    }
    CVT(Wq,  wqkv_hi, wqkv_lo, 65536, 196608, 0,      0.0625f, 393216);
    CVT(Wk,  wqkv_hi, wqkv_lo, 65536, 196608, 65536,  1.f,     393216);
    CVT(Wv,  wqkv_hi, wqkv_lo, 65536, 196608, 131072, 1.f,     393216);
    CVT(Wo,  wo_hi,  wo_lo,  65536,  65536,  0, 1.f, 393216);
    CVT(Wf1, wf1_hi, wf1_lo, 294912, 294912, 0, 1.f, 1769472);
    CVT(Wf2, wf2_hi, wf2_lo, 262144, 262144, 0, 1.f, 1572864);
    CVT(exw1, wex1_hi, wex1_lo, 16384, 16384, 0, 1.f, 16384);
    CVT(exw2, wex2_hi, wex2_lo, 65536, 65536, 0, 1.f, 65536);
    CVT(ow1,  wo1_hi,  wo1_lo,  65536, 65536, 0, 1.f, 65536);
#undef CVT
    // bias bins
    for (int idx = tid; idx < NLc * NHc * NBINSc; idx += stride) {
        int bin = idx % NBINSc;
        int tmp = idx / NBINSc;
        int hh = tmp % NHc, l = tmp / NHc;
        float s = b2d[l * NHc + hh];
        const float* pe = pos_emb + bin * PDIMc;
        const float* w  = W2d + (l * NHc + hh) * PDIMc;
        for (int p = 0; p < PDIMc; ++p) s += pe[p] * w[p];
        bb[idx] = s;
    }
    // e_aa -> um cols 256..287
    for (int tok = tid; tok < NTOK; tok += stride) {
        int n = tok / Lc, l = tok % Lc;
        const float* xp = x + (size_t)n * 20 * Lc + l;
        float best = xp[0];
        int bi = 0;
        for (int c = 1; c < 20; ++c) {
            float v = xp[c * Lc];
            if (v > best) { best = v; bi = c; }
        }
        const float* e = aa_emb + bi * E1Dc;
        bf8 hv, lv;
        for (int c8 = 0; c8 < E1Dc / 8; ++c8) {
#pragma unroll
            for (int q = 0; q < 8; ++q) {
                float v = e[c8 * 8 + q];
                short hh = f2bf(v);
                hv[q] = hh;
                lv[q] = f2bf(v - bf2f(hh));
            }
            *(bf8*)(umhi + (size_t)tok * UMDIM + EMBEDc + c8 * 8) = hv;
            *(bf8*)(umlo + (size_t)tok * UMDIM + EMBEDc + c8 * 8) = lv;
        }
    }
    // z transpose
    for (int tok = tid; tok < NTOK; tok += stride) {
        int n = tok >> 9, l = tok & 511;
        bf8 hv, lv;
        for (int c8 = 0; c8 < NZc / 8; ++c8) {
#pragma unroll
            for (int q = 0; q < 8; ++q) {
                float v = z[((size_t)n * NZc + c8 * 8 + q) * Lc + l];
                short hh = f2bf(v);
                hv[q] = hh;
                lv[q] = f2bf(v - bf2f(hh));
            }
            *(bf8*)(zth + (size_t)tok * NZc + c8 * 8) = hv;
            *(bf8*)(ztl + (size_t)tok * NZc + c8 * 8) = lv;
        }
    }
}

// ---------------------------------------------------------------------------
// LDS-staged MFMA GEMM, XCD-swizzled, templated tile height + K-step + optional
// split-K into separate partial buffers (outf + kh*NTOK*EMBEDc).
// Rows padded to BK+8 shorts: stride (BK+8)/2 words % 32 = 4 -> 2-way (free).
template <int EPI, int MF, int SKSHIFT, int BK>
__global__ __launch_bounds__(256) void k_gemm3(
    const short* __restrict__ Ahi, const short* __restrict__ Alo, int lda,
    const short* __restrict__ Bhi, const short* __restrict__ Blo, int ldb,
    int K, float* __restrict__ outf, int ldo, short* __restrict__ ohi,
    short* __restrict__ olo, int ldh, const float* __restrict__ bias,
    int gx, int gypx) {
    constexpr int PAD = BK + 8;
    __shared__ __align__(16) short Ah[MF * 64][PAD];
    __shared__ __align__(16) short Al[MF * 64][PAD];
    __shared__ __align__(16) short Bh[64][PAD];
    __shared__ __align__(16) short Bl[64][PAD];

    int bid = blockIdx.x;
    int koff = 0;
    if (SKSHIFT) {
        int kh = bid >> SKSHIFT;
        bid &= (1 << SKSHIFT) - 1;
        koff = kh * K;
        outf += (size_t)kh * NTOK * EMBEDc;
    }
    int xcd = bid & 7, j = bid >> 3;
    int bx = j % gx, by = xcd * gypx + j / gx;

    int t = threadIdx.x;
    int w = t >> 6, l = t & 63, lr = l & 15, lk = l >> 4;
    int m0 = by * (MF * 64);
    int n0 = bx * 64;

    constexpr int TPR = BK / 8;        // threads per staged row
    constexpr int RP  = 256 / TPR;     // rows per staging pass
    constexpr int AP  = MF * 64 / RP;  // passes for A
    constexpr int BP  = 64 / RP;       // passes for B
    int srow = t / TPR, scol = (t % TPR) * 8;

    const short* pa  = Ahi + (size_t)(m0 + srow) * lda + koff + scol;
    const short* pal = Alo + (size_t)(m0 + srow) * lda + koff + scol;
    const short* pb  = Bhi + (size_t)(n0 + srow) * ldb + koff + scol;
    const short* pbl = Blo + (size_t)(n0 + srow) * ldb + koff + scol;

    bf8 ra[AP], rla[AP], rb[BP], rlb[BP];
#pragma unroll
    for (int p = 0; p < AP; ++p) {
        ra[p]  = *(const bf8*)(pa  + (size_t)p * RP * lda);
        rla[p] = *(const bf8*)(pal + (size_t)p * RP * lda);
    }
#pragma unroll
    for (int p = 0; p < BP; ++p) {
        rb[p]  = *(const bf8*)(pb  + (size_t)p * RP * ldb);
        rlb[p] = *(const bf8*)(pbl + (size_t)p * RP * ldb);
    }

    f4 acc[MF][4];
#pragma unroll
    for (int mf = 0; mf < MF; ++mf)
#pragma unroll
        for (int nf = 0; nf < 4; ++nf) acc[mf][nf] = (f4){0.f, 0.f, 0.f, 0.f};

    for (int ks = 0; ks < K; ks += BK) {
        __syncthreads();
#pragma unroll
        for (int p = 0; p < AP; ++p) {
            *(bf8*)&Ah[p * RP + srow][scol] = ra[p];
            *(bf8*)&Al[p * RP + srow][scol] = rla[p];
        }
#pragma unroll
        for (int p = 0; p < BP; ++p) {
            *(bf8*)&Bh[p * RP + srow][scol] = rb[p];
            *(bf8*)&Bl[p * RP + srow][scol] = rlb[p];
        }
        __syncthreads();
        if (ks + BK < K) {
#pragma unroll
            for (int p = 0; p < AP; ++p) {
                ra[p]  = *(const bf8*)(pa  + (size_t)p * RP * lda + ks + BK);
                rla[p] = *(const bf8*)(pal + (size_t)p * RP * lda + ks + BK);
            }
#pragma unroll
            for (int p = 0; p < BP; ++p) {
                rb[p]  = *(const bf8*)(pb  + (size_t)p * RP * ldb + ks + BK);
                rlb[p] = *(const bf8*)(pbl + (size_t)p * RP * ldb + ks + BK);
            }
        }
#pragma unroll
        for (int kc = 0; kc < BK / 32; ++kc) {
            bf8 bhf[4], blf[4];
#pragma unroll
            for (int nf = 0; nf < 4; ++nf) {
                bhf[nf] = *(const bf8*)&Bh[nf * 16 + lr][kc * 32 + lk * 8];
                blf[nf] = *(const bf8*)&Bl[nf * 16 + lr][kc * 32 + lk * 8];
            }
#pragma unroll
            for (int mf = 0; mf < MF; ++mf) {
                bf8 ah = *(const bf8*)&Ah[w * MF * 16 + mf * 16 + lr][kc * 32 + lk * 8];
                bf8 al = *(const bf8*)&Al[w * MF * 16 + mf * 16 + lr][kc * 32 + lk * 8];
#pragma unroll
                for (int nf = 0; nf < 4; ++nf) {
                    acc[mf][nf] = MFMA(ah, bhf[nf], acc[mf][nf]);
                    acc[mf][nf] = MFMA(ah, blf[nf], acc[mf][nf]);
                    acc[mf][nf] = MFMA(al, bhf[nf], acc[mf][nf]);
                }
            }
        }
    }

#pragma unroll
    for (int mf = 0; mf < MF; ++mf) {
#pragma unroll
        for (int nf = 0; nf < 4; ++nf) {
            int n = n0 + nf * 16 + lr;
            int mbase = m0 + w * MF * 16 + mf * 16 + lk * 4;
            if (EPI == 0) {
#pragma unroll
                for (int r = 0; r < 4; ++r)
                    outf[(size_t)(mbase + r) * ldo + n] = acc[mf][nf][r];
            } else if (EPI == 1) {
                float bv = bias[n];
#pragma unroll
                for (int r = 0; r < 4; ++r) {
                    float y = fmaxf(acc[mf][nf][r] + bv, 0.f);
                    short hv = f2bf(y);
                    size_t oi = (size_t)(mbase + r) * ldh + n;
                    ohi[oi] = hv;
                    olo[oi] = f2bf(y - bf2f(hv));
                }
            } else if (EPI == 2) {
#pragma unroll
                for (int r = 0; r < 4; ++r) {
                    float y = acc[mf][nf][r];
                    short hv = f2bf(y);
                    size_t oi = (size_t)(mbase + r) * ldh + n;
                    ohi[oi] = hv;
                    olo[oi] = f2bf(y - bf2f(hv));
                }
            } else {
                float bv = bias[n];
#pragma unroll
                for (int r = 0; r < 4; ++r) {
                    float y = acc[mf][nf][r] + bv;
                    outf[(size_t)(mbase + r) * ldo + n] = y;
                    short hv = f2bf(y);
                    size_t oi = (size_t)(mbase + r) * ldh + n;
                    ohi[oi] = hv;
                    olo[oi] = f2bf(y - bf2f(hv));
                }
            }
        }
    }
}

// ---------------------------------------------------------------------------
// MFMA flash attention: 512 threads, K/V staged in two 256-key halves so
// LDS = 37.6 KB -> 4 blocks/CU = 32 waves/CU.
__global__ __launch_bounds__(512, 8) void k_attn(const short* __restrict__ qh,
                                                 const short* __restrict__ ql,
                                                 const float* __restrict__ bb,
                                                 short* __restrict__ ohi,
                                                 short* __restrict__ olo) {
    int bx = blockIdx.x;
    int qt = bx >> 7;            // 0..3; blocks sharing (n,head) same XCD
    int head = bx & 15;
    int n = (bx >> 4) & 7;
    int t = threadIdx.x;
    int w = t >> 6, l = t & 63;
    int lq = l & 15, lk = l >> 4;

    __shared__ __align__(16) short khl[256][40];   // [key][hi0-15|lo16-31|pad]
    __shared__ __align__(16) short vth[16][264];   // V^T hi: [d][key 0..255]
    __shared__ __align__(16) short vtl[16][264];   // V^T lo
    __shared__ float biasr[64];

    if (t < NBINSc) biasr[t] = bb[head * NBINSc + t];
    float bL = bb[head * NBINSc];
    float bR = bb[head * NBINSc + 48];

    size_t base = (size_t)n * Lc * 768 + head * 16;

    int qg = qt * 128 + w * 16 + lq;             // this lane's q column
    size_t qrow = ((size_t)n * Lc + qg) * 768 + head * 16;
    bf8 B1 = *(const bf8*)(qh + qrow + (lk & 1) * 8);   // [Qh|Qh]
    bf8 B2;
    if (lk < 2) B2 = *(const bf8*)(ql + qrow + lk * 8);  // [Ql|0]
    else {
#pragma unroll
        for (int i = 0; i < 8; ++i) B2[i] = 0;
    }

    f4 acc = (f4){0.f, 0.f, 0.f, 0.f};
    float m = -1e30f, lsum = 0.f;
    int rel0 = lk * 4 - qg;      // rel of s[0] at global kt=0; += 16 per tile

    for (int half = 0; half < 2; ++half) {
        __syncthreads();          // previous half fully consumed
        // stage K half (256 keys)
        for (int u = t; u < 1024; u += 512) {
            int key = u >> 2, seg = u & 3;
            const short* src = (seg < 2 ? qh : ql) + base + 256
                             + (size_t)(half * 256 + key) * 768 + (seg & 1) * 8;
            *(bf8*)&khl[key][seg * 8] = *(const bf8*)src;
        }
        // stage V half transposed, pair-packed b32 writes (1 item/thread)
        {
            int u = t & 127;             // key pair
            int dhalf = (t >> 7) & 1;    // d 0..7 / 8..15
            int hl = (t >> 8) & 1;       // hi / lo
            int gkey = half * 256 + u * 2;
            const short* vs = (hl ? ql : qh) + base + 512 + (size_t)gkey * 768 + dhalf * 8;
            bf8 A = *(const bf8*)vs;
            bf8 B = *(const bf8*)(vs + 768);
            unsigned* vw = (unsigned*)(hl ? &vtl[0][0] : &vth[0][0]);  // stride 132 words
#pragma unroll
            for (int i = 0; i < 8; ++i)
                vw[(dhalf * 8 + i) * 132 + u] =
                    (unsigned)(unsigned short)A[i] | ((unsigned)(unsigned short)B[i] << 16);
        }
        __syncthreads();

        for (int kt = 0; kt < 16; ++kt, rel0 += 16) {
            bf8 A1 = *(const bf8*)&khl[kt * 16 + lq][lk * 8];  // [Kh|Kl]
            f4 s = (f4){0.f, 0.f, 0.f, 0.f};
            __builtin_amdgcn_s_setprio(1);
            s = MFMA(A1, B1, s);      // KhQh + KlQh
            s = MFMA(A1, B2, s);      // KhQl
            __builtin_amdgcn_s_setprio(0);
            if (rel0 >= PMAXLc) {
                s[0] += bR; s[1] += bR; s[2] += bR; s[3] += bR;
            } else if (rel0 + 3 <= -PMAXLc) {
                s[0] += bL; s[1] += bL; s[2] += bL; s[3] += bL;
            } else {
#pragma unroll
                for (int r = 0; r < 4; ++r) {
                    int rel = rel0 + r;
                    rel = rel < -PMAXLc ? -PMAXLc : (rel > PMAXLc ? PMAXLc : rel);
                    s[r] += biasr[rel + PMAXLc];
                }
            }
            float mt = fmaxf(fmaxf(s[0], s[1]), fmaxf(s[2], s[3]));
            mt = fmaxf(mt, __shfl_xor(mt, 16));
            mt = fmaxf(mt, __shfl_xor(mt, 32));
            if (__any(mt > m + 8.0f)) {
                float mn = fmaxf(m, mt);
                float alpha = __expf(m - mn);
                m = mn;
                lsum *= alpha;
#pragma unroll
                for (int r = 0; r < 4; ++r) acc[r] *= __shfl(alpha, lk * 4 + r);
            }
            f4 p;
#pragma unroll
            for (int r = 0; r < 4; ++r) p[r] = __expf(s[r] - m);
            lsum += p[0] + p[1] + p[2] + p[3];
            int src0 = (lk & 1) * 32 + lq;
            int src1 = src0 + 16;
            float g[8];
#pragma unroll
            for (int jj = 0; jj < 4; ++jj) {
                g[jj]     = __shfl(p[jj], src0);
                g[jj + 4] = __shfl(p[jj], src1);
            }
            bf8 PA;
            if (lk < 2) {
#pragma unroll
                for (int jj = 0; jj < 8; ++jj)
                    PA[jj] = (short)(__float_as_uint(g[jj]) >> 16);
            } else {
#pragma unroll
                for (int jj = 0; jj < 8; ++jj) {
                    unsigned hu = __float_as_uint(g[jj]) & 0xFFFF0000u;
                    PA[jj] = (short)(__float_as_uint(g[jj] - __uint_as_float(hu)) >> 16);
                }
            }
            bf8 VB1 = *(const bf8*)&vth[lq][kt * 16 + (lk & 1) * 8];  // [Vh|Vh]
            bf8 VB2;
            if (lk < 2) VB2 = *(const bf8*)&vtl[lq][kt * 16 + lk * 8];  // [Vl|0]
            else {
#pragma unroll
                for (int i = 0; i < 8; ++i) VB2[i] = 0;
            }
            __builtin_amdgcn_s_setprio(1);
            acc = MFMA(PA, VB1, acc);   // PhVh + PlVh
            acc = MFMA(PA, VB2, acc);   // PhVl
            __builtin_amdgcn_s_setprio(0);
        }
    }

    float lred = lsum + __shfl_xor(lsum, 16);
    lred += __shfl_xor(lred, 32);
    float inv = 1.0f / lred;
#pragma unroll
    for (int r = 0; r < 4; ++r) {
        float iq = __shfl(inv, lk * 4 + r);
        float y = acc[r] * iq;
        int qo = qt * 128 + w * 16 + lk * 4 + r;
        size_t oi = ((size_t)n * Lc + qo) * DMc + head * 16 + lq;
        unsigned hu = __float_as_uint(y) & 0xFFFF0000u;
        ohi[oi] = (short)(hu >> 16);
        olo[oi] = (short)(__float_as_uint(y - __uint_as_float(hu)) >> 16);
    }
}

// ---------------------------------------------------------------------------
// LN over h + s2a + s2b + sbias, fully f4-vectorized.
// 512 blocks x 256 thr: 8 tokens/block, 32 lanes/token, 8 dims/lane.
__global__ __launch_bounds__(256) void k_ln(const float* __restrict__ s2a,
                                            const float* __restrict__ s2b,
                                            const float* __restrict__ sbias,
                                            const float* __restrict__ g,
                                            const float* __restrict__ bta,
                                            float* __restrict__ h,
                                            short* __restrict__ umhi,
                                            short* __restrict__ umlo) {
    int t = threadIdx.x;
    int tl = t >> 5, j = t & 31;
    size_t gtok = (size_t)blockIdx.x * 8 + tl;
    int d0 = j * 8;
    size_t off = gtok * EMBEDc + d0;
    f4 h0 = *(const f4*)(h + off);
    f4 h1 = *(const f4*)(h + off + 4);
    f4 a0 = *(const f4*)(s2a + off);
    f4 a1 = *(const f4*)(s2a + off + 4);
    f4 b0 = *(const f4*)(s2b + off);
    f4 b1 = *(const f4*)(s2b + off + 4);
    f4 sb0 = *(const f4*)(sbias + d0);
    f4 sb1 = *(const f4*)(sbias + d0 + 4);
    f4 v0 = h0 + a0 + b0 + sb0;
    f4 v1 = h1 + a1 + b1 + sb1;
    float sum = v0[0] + v0[1] + v0[2] + v0[3] + v1[0] + v1[1] + v1[2] + v1[3];
    float ssq = v0[0]*v0[0] + v0[1]*v0[1] + v0[2]*v0[2] + v0[3]*v0[3]
              + v1[0]*v1[0] + v1[1]*v1[1] + v1[2]*v1[2] + v1[3]*v1[3];
#pragma unroll
    for (int off5 = 16; off5; off5 >>= 1) {
        sum += __shfl_xor(sum, off5, 32);
        ssq += __shfl_xor(ssq, off5, 32);
    }
    float mean = sum * (1.f / EMBEDc);
    float var = ssq * (1.f / EMBEDc) - mean * mean;
    float inv = rsqrtf(var + 1e-5f);
    f4 g0 = *(const f4*)(g + d0);
    f4 g1 = *(const f4*)(g + d0 + 4);
    f4 t0 = *(const f4*)(bta + d0);
    f4 t1 = *(const f4*)(bta + d0 + 4);
    f4 y0, y1;
    bf8 hv, lv;
#pragma unroll
    for (int q = 0; q < 4; ++q) {
        float y = (v0[q] - mean) * inv * g0[q] + t0[q];
        y0[q] = y;
        short hh = f2bf(y);
        hv[q] = hh;
        lv[q] = f2bf(y - bf2f(hh));
    }
#pragma unroll
    for (int q = 0; q < 4; ++q) {
        float y = (v1[q] - mean) * inv * g1[q] + t1[q];
        y1[q] = y;
        short hh = f2bf(y);
        hv[q + 4] = hh;
        lv[q + 4] = f2bf(y - bf2f(hh));
    }
    *(f4*)(h + off) = y0;
    *(f4*)(h + off + 4) = y1;
    *(bf8*)(umhi + gtok * UMDIM + d0) = hv;
    *(bf8*)(umlo + gtok * UMDIM + d0) = lv;
}

// ---------------------------------------------------------------------------
__global__ __launch_bounds__(256) void k_r(const short* __restrict__ fh,
                                           const short* __restrict__ fl,
                                           const float* __restrict__ w2,
                                           const float* __restrict__ b2,
                                           float* __restrict__ r) {
    __shared__ float w[3][EMBEDc];
    int t = threadIdx.x;
    for (int u = t; u < 3 * EMBEDc; u += 256) w[u >> 8][u & 255] = w2[u];
    __syncthreads();
    int tok = blockIdx.x * 64 + (t >> 2), o = t & 3;
    if (o < 3) {
        const short* ph = fh + (size_t)tok * EMBEDc;
        const short* pl = fl + (size_t)tok * EMBEDc;
        float s = b2[o];
        for (int c8 = 0; c8 < EMBEDc / 8; ++c8) {
            bf8 vh = *(const bf8*)(ph + c8 * 8);
            bf8 vl = *(const bf8*)(pl + c8 * 8);
#pragma unroll
            for (int j = 0; j < 8; ++j)
                s += (bf2f(vh[j]) + bf2f(vl[j])) * w[o][c8 * 8 + j];
        }
        r[(size_t)tok * 3 + o] = s;
    }
}

// ---------------------------------------------------------------------------
__global__ __launch_bounds__(256) void k_dmap(const float* __restrict__ r,
                                              float* __restrict__ d) {
    int b = blockIdx.x;
    int n = b / Lc;
    float xi = r[(size_t)b * 3], yi = r[(size_t)b * 3 + 1], zi = r[(size_t)b * 3 + 2];
    const float* rn = r + (size_t)n * Lc * 3;
    for (int j = threadIdx.x; j < Lc; j += 256) {
        float dx = xi - rn[j * 3];
        float dy = yi - rn[j * 3 + 1];
        float dz = zi - rn[j * 3 + 2];
        d[(size_t)b * Lc + j] = sqrtf(dx * dx + dy * dy + dz * dz + 1e-12f);
    }
}

// ---------------------------------------------------------------------------
extern "C" void kernel_launch(void* const* d_in, const int* in_sizes, int n_in,
                              void* d_out, int out_size, void* d_ws, size_t ws_size,
                              hipStream_t stream) {
    const float* z       = (const float*)d_in[0];
    const float* x       = (const float*)d_in[1];
    const float* pos_emb = (const float*)d_in[2];
    const float* aa_emb  = (const float*)d_in[3];
    const float* ex_w1   = (const float*)d_in[4];
    const float* ex_b1   = (const float*)d_in[5];
    const float* ex_w2   = (const float*)d_in[6];
    const float* ex_b2   = (const float*)d_in[7];
    const float* Wq      = (const float*)d_in[8];
    const float* Wk      = (const float*)d_in[9];
    const float* Wv      = (const float*)d_in[10];
    const float* Wo      = (const float*)d_in[11];
    const float* bo      = (const float*)d_in[12];
    const float* W2d     = (const float*)d_in[13];
    const float* b2d     = (const float*)d_in[14];
    const float* Wf1     = (const float*)d_in[15];
    const float* bf1     = (const float*)d_in[16];
    const float* Wf2     = (const float*)d_in[17];
    const float* bf2     = (const float*)d_in[18];
    const float* ln1_g   = (const float*)d_in[19];
    const float* ln1_b   = (const float*)d_in[20];
    const float* ln2_g   = (const float*)d_in[21];
    const float* ln2_b   = (const float*)d_in[22];
    const float* o_w1    = (const float*)d_in[23];
    const float* o_b1    = (const float*)d_in[24];
    const float* o_w2    = (const float*)d_in[25];
    const float* o_b2    = (const float*)d_in[26];

    float* h    = (float*)d_ws;                    // 4096*256
    float* s2a  = h + (size_t)NTOK * EMBEDc;
    float* s2b  = s2a + (size_t)NTOK * EMBEDc;
    float* bbuf = s2b + (size_t)NTOK * EMBEDc;     // pad 8192
    float* r    = bbuf + 8192;                     // pad 16384
    short* qkvh = (short*)(r + 16384);             // 4096*768
    short* qkvl = qkvh + (size_t)NTOK * 768;
    short* um_hi = qkvl + (size_t)NTOK * 768;      // 4096*288
    short* um_lo = um_hi + (size_t)NTOK * UMDIM;
    short* o_hi  = um_lo + (size_t)NTOK * UMDIM;   // 4096*256
    short* o_lo  = o_hi + (size_t)NTOK * EMBEDc;
    short* f1_hi = o_lo + (size_t)NTOK * EMBEDc;   // 4096*1024
    short* f1_lo = f1_hi + (size_t)NTOK * DFFc;
    short* wqkv_hi = f1_lo + (size_t)NTOK * DFFc;  // 6*768*256
    short* wqkv_lo = wqkv_hi + (size_t)NLc * 768 * EMBEDc;
    short* wo_hi   = wqkv_lo + (size_t)NLc * 768 * EMBEDc;   // 6*256*256
    short* wo_lo   = wo_hi + (size_t)NLc * EMBEDc * DMc;
    short* wf1_hi  = wo_lo + (size_t)NLc * EMBEDc * DMc;     // 6*1024*288
    short* wf1_lo  = wf1_hi + (size_t)NLc * DFFc * UMDIM;
    short* wf2_hi  = wf1_lo + (size_t)NLc * DFFc * UMDIM;    // 6*256*1024
    short* wf2_lo  = wf2_hi + (size_t)NLc * EMBEDc * DFFc;
    short* wex1_hi = wf2_lo + (size_t)NLc * EMBEDc * DFFc;   // 256*64
    short* wex1_lo = wex1_hi + EMBEDc * NZc;
    short* wex2_hi = wex1_lo + EMBEDc * NZc;                 // 256*256
    short* wex2_lo = wex2_hi + EMBEDc * EMBEDc;
    short* wo1_hi  = wex2_lo + EMBEDc * EMBEDc;              // 256*256
    short* wo1_lo  = wo1_hi + EMBEDc * EMBEDc;
    // zt aliases the o buffer (only used in preamble, before k_attn writes o)
    short* zt_hi = o_hi;
    short* zt_lo = o_lo;

    k_pre<<<1024, 256, 0, stream>>>(Wq, Wk, Wv, Wo, Wf1, Wf2, ex_w1, ex_w2, o_w1,
                                    pos_emb, W2d, b2d, x, aa_emb, z,
                                    wqkv_hi, wqkv_lo, wo_hi, wo_lo,
                                    wf1_hi, wf1_lo, wf2_hi, wf2_lo,
                                    wex1_hi, wex1_lo, wex2_hi, wex2_lo,
                                    wo1_hi, wo1_lo, bbuf, um_hi, um_lo,
                                    zt_hi, zt_lo);

    // embed: relu GEMM -> GEMM (fp32 h + bf16 um)
    k_gemm3<1, 1, 0, 64><<<256, 256, 0, stream>>>(
        zt_hi, zt_lo, NZc, wex1_hi, wex1_lo, NZc, NZc,
        nullptr, 0, f1_hi, f1_lo, EMBEDc, ex_b1, 4, 8);
    k_gemm3<3, 1, 0, 64><<<256, 256, 0, stream>>>(
        f1_hi, f1_lo, EMBEDc, wex2_hi, wex2_lo, EMBEDc, EMBEDc,
        h, EMBEDc, um_hi, um_lo, UMDIM, ex_b2, 4, 8);

    for (int l = 0; l < NLc; ++l) {
        k_gemm3<2, 2, 0, 64><<<384, 256, 0, stream>>>(
            um_hi, um_lo, UMDIM,
            wqkv_hi + (size_t)l * 768 * EMBEDc, wqkv_lo + (size_t)l * 768 * EMBEDc, EMBEDc,
            EMBEDc, nullptr, 0, qkvh, qkvl, 768, nullptr, 12, 4);
        k_attn<<<NB * NHc * 4, 512, 0, stream>>>(qkvh, qkvl, bbuf + (size_t)l * NHc * NBINSc, o_hi, o_lo);
        k_gemm3<0, 1, 8, 64><<<512, 256, 0, stream>>>(
            o_hi, o_lo, EMBEDc,
            wo_hi + (size_t)l * EMBEDc * DMc, wo_lo + (size_t)l * EMBEDc * DMc, DMc,
            128, s2a, EMBEDc, nullptr, nullptr, 0, nullptr, 4, 8);
        k_ln<<<NTOK / 8, 256, 0, stream>>>(s2a, s2b, bo + (size_t)l * EMBEDc,
                                           ln1_g + (size_t)l * EMBEDc, ln1_b + (size_t)l * EMBEDc,
                                           h, um_hi, um_lo);
        k_gemm3<1, 2, 0, 32><<<512, 256, 0, stream>>>(
            um_hi, um_lo, UMDIM,
            wf1_hi + (size_t)l * DFFc * UMDIM, wf1_lo + (size_t)l * DFFc * UMDIM, UMDIM,
            UMDIM, nullptr, 0, f1_hi, f1_lo, DFFc, bf1 + (size_t)l * DFFc, 16, 4);
        k_gemm3<0, 1, 8, 64><<<512, 256, 0, stream>>>(
            f1_hi, f1_lo, DFFc,
            wf2_hi + (size_t)l * EMBEDc * DFFc, wf2_lo + (size_t)l * EMBEDc * DFFc, DFFc,
            512, s2a, EMBEDc, nullptr, nullptr, 0, nullptr, 4, 8);
        k_ln<<<NTOK / 8, 256, 0, stream>>>(s2a, s2b, bf2 + (size_t)l * EMBEDc,
                                           ln2_g + (size_t)l * EMBEDc, ln2_b + (size_t)l * EMBEDc,
                                           h, um_hi, um_lo);
    }

    // final: f = relu(um @ o_w1^T + o_b1) (um cols 0..255 hold h in bf16)
    k_gemm3<1, 1, 0, 64><<<256, 256, 0, stream>>>(
        um_hi, um_lo, UMDIM, wo1_hi, wo1_lo, EMBEDc, EMBEDc,
        nullptr, 0, f1_hi, f1_lo, EMBEDc, o_b1, 4, 8);
    k_r<<<NTOK / 64, 256, 0, stream>>>(f1_hi, f1_lo, o_w2, o_b2, r);
    k_dmap<<<NB * Lc, 256, 0, stream>>>(r, (float*)d_out);
}